// Round 1
// baseline (3595.272 us; speedup 1.0000x reference)
//
#include <hip/hip_runtime.h>
#include <hip/hip_bf16.h>
#include <stdint.h>
#include <math.h>

#define N_IMG 4
#define CIN 256
#define HFD 128
#define WFD 128
#define HW (HFD*WFD)        // 16384
#define NA 3
#define NPROP (NA*HW)       // 49152
#define PRE_NMS 2000
#define POST_NMS 300

// ---------------- K1: 3x3 conv, fp64 accumulate ----------------
// tile: 32 co x 8 h x 16 w ; block 256 = (wt 8, ht 4, ct 8); thread: 4co x 2h x 2w
__global__ __launch_bounds__(256) void k_conv3(const float* __restrict__ feat,
                                               const float* __restrict__ cw,
                                               const float* __restrict__ cb,
                                               float* __restrict__ X)
{
    __shared__ float in_t[16][10][18];
    __shared__ float w_t[16][9][32];
    int b = blockIdx.x;
    int co_t = b & 7; b >>= 3;
    int w_tile = b & 7; b >>= 3;
    int h_tile = b & 15; b >>= 4;
    int n = b;
    int co0 = co_t * 32, w0 = w_tile * 16, h0 = h_tile * 8;
    int tid = threadIdx.x;
    int wt = tid & 7, ht = (tid >> 3) & 3, ct = tid >> 5;

    double acc[4][2][2];
#pragma unroll
    for (int c = 0; c < 4; c++)
#pragma unroll
        for (int ih = 0; ih < 2; ih++)
#pragma unroll
            for (int iw = 0; iw < 2; iw++) acc[c][ih][iw] = 0.0;

    for (int ci0 = 0; ci0 < CIN; ci0 += 16) {
        // stage input tile (rows h0-1..h0+8, cols w0-1..w0+16)
        for (int idx = tid; idx < 16 * 180; idx += 256) {
            int ci = idx / 180; int r2 = idx % 180; int dh = r2 / 18; int dw = r2 % 18;
            int gh = h0 - 1 + dh, gw = w0 - 1 + dw;
            float v = 0.f;
            if (gh >= 0 && gh < HFD && gw >= 0 && gw < WFD)
                v = feat[((n * CIN + ci0 + ci) * HFD + gh) * WFD + gw];
            in_t[ci][dh][dw] = v;
        }
        // stage weights as [ci][rs][co]
        for (int idx = tid; idx < 16 * 9 * 32; idx += 256) {
            int co = idx / 144; int r2 = idx % 144; int ci = r2 / 9; int rs = r2 % 9;
            w_t[ci][rs][co] = cw[(co0 + co) * 2304 + (ci0 + ci) * 9 + rs];
        }
        __syncthreads();
        for (int ci = 0; ci < 16; ci++) {
#pragma unroll
            for (int r = 0; r < 3; r++) {
#pragma unroll
                for (int s = 0; s < 3; s++) {
                    float i00 = in_t[ci][ht * 2 + 0 + r][wt * 2 + 0 + s];
                    float i01 = in_t[ci][ht * 2 + 0 + r][wt * 2 + 1 + s];
                    float i10 = in_t[ci][ht * 2 + 1 + r][wt * 2 + 0 + s];
                    float i11 = in_t[ci][ht * 2 + 1 + r][wt * 2 + 1 + s];
#pragma unroll
                    for (int c = 0; c < 4; c++) {
                        double wv = (double)w_t[ci][r * 3 + s][ct * 4 + c];
                        acc[c][0][0] += wv * (double)i00;
                        acc[c][0][1] += wv * (double)i01;
                        acc[c][1][0] += wv * (double)i10;
                        acc[c][1][1] += wv * (double)i11;
                    }
                }
            }
        }
        __syncthreads();
    }
#pragma unroll
    for (int c = 0; c < 4; c++) {
        int co = co0 + ct * 4 + c;
        double bias = (double)cb[co];
#pragma unroll
        for (int ih = 0; ih < 2; ih++)
#pragma unroll
            for (int iw = 0; iw < 2; iw++) {
                X[((size_t)(n * CIN + co) * HFD + (h0 + ht * 2 + ih)) * WFD + (w0 + wt * 2 + iw)] =
                    (float)(acc[c][ih][iw] + bias);
            }
    }
}

// ---------------- K2: 1x1 heads + sigmoid + decode + clip + sort key ----------------
__global__ __launch_bounds__(256) void k_heads(const float* __restrict__ X,
                                               const float* __restrict__ dw_, const float* __restrict__ db_,
                                               const float* __restrict__ rw_, const float* __restrict__ rb_,
                                               double* __restrict__ boxes,
                                               unsigned long long* __restrict__ keys)
{
    __shared__ float wl[15][256];
    int tid = threadIdx.x;
    for (int idx = tid; idx < 15 * 256; idx += 256) {
        int r = idx >> 8;
        wl[r][idx & 255] = (r < 3) ? dw_[idx] : rw_[idx - 768];
    }
    __syncthreads();
    int p = blockIdx.x * 256 + tid;
    int n = p >> 14, pos = p & 16383;
    const float* xp = X + (size_t)(n * CIN) * HW + pos;
    double acc[15];
#pragma unroll
    for (int c = 0; c < 15; c++) acc[c] = 0.0;
    for (int ci = 0; ci < 256; ci++) {
        double v = (double)xp[(size_t)ci * HW];
#pragma unroll
        for (int c = 0; c < 15; c++) acc[c] += v * (double)wl[c][ci];
    }
#pragma unroll
    for (int a = 0; a < 3; a++) {
        double logit = acc[a] + (double)db_[a];
        double score = 1.0 / (1.0 + exp(-logit));
        double dx  = acc[3 + a]  + (double)rb_[a];
        double dy  = acc[6 + a]  + (double)rb_[3 + a];
        double dwv = acc[9 + a]  + (double)rb_[6 + a];
        double dhv = acc[12 + a] + (double)rb_[9 + a];
        int i = a * HW + pos;
        // anchors indexed by i in (loc, anchor) order — faithful to reference mismatch
        int loc = i / 3, aa = i % 3;
        int hh = loc >> 7, wwi = loc & 127;
        double sx = (double)(wwi * 8), sy = (double)(hh * 8);
        double bx1 = (aa == 0) ? -91.0 : (aa == 1 ? -64.0 : -45.0);
        double by1 = (aa == 0) ? -45.0 : (aa == 1 ? -64.0 : -91.0);
        double bx2 = -bx1, by2 = -by1;
        double x1 = sx + bx1, y1 = sy + by1, x2 = sx + bx2, y2 = sy + by2;
        double aw = x2 - x1, ahh = y2 - y1;
        double acx = y1 + aw * 0.5;   // (sic) swap, faithful to reference
        double acy = x1 + ahh * 0.5;  // (sic)
        double px = acx + dx * aw, py = acy + dy * ahh;
        double pw = aw * exp(dwv), ph = ahh * exp(dhv);
        double c1 = px - pw * 0.5, c2 = py - ph * 0.5, c3 = px + pw * 0.5, c4 = py + ph * 0.5;
        c1 = fmin(fmax(c1, 0.0), 1024.0);
        c2 = fmin(fmax(c2, 0.0), 1024.0);
        c3 = fmin(fmax(c3, 0.0), 1024.0);
        c4 = fmin(fmax(c4, 0.0), 1024.0);
        double wb = c3 - c1, hb = c4 - c2;
        bool valid = (score > 0.3) && (wb > 0.0) && (hb > 0.0);
        unsigned long long key = valid ? ~((unsigned long long)__double_as_longlong(score)) : ~0ull;
        double* bp = boxes + ((size_t)n * NPROP + i) * 4;
        bp[0] = c1; bp[1] = c2; bp[2] = c3; bp[3] = c4;
        keys[(size_t)n * NPROP + i] = key;
    }
}

// ---------------- K3: exact top-2000 per image (radix select + bitonic) ----------------
__global__ __launch_bounds__(256) void k_select(const unsigned long long* __restrict__ keys,
                                                const double* __restrict__ boxes,
                                                unsigned long long* __restrict__ skeys,
                                                double* __restrict__ bsort,
                                                double* __restrict__ area)
{
    int n = blockIdx.x; int tid = threadIdx.x;
    const unsigned long long* K = keys + (size_t)n * NPROP;
    __shared__ uint32_t hist[2048];
    __shared__ unsigned long long selk[2048];
    __shared__ uint32_t seli[2048];
    __shared__ unsigned long long s_prefix;
    __shared__ int s_need;
    __shared__ uint32_t s_cnt;
    if (tid == 0) { s_prefix = 0ull; s_need = PRE_NMS; s_cnt = 0u; }
    for (int L = 0; L < 4; L++) {
        int sh = 53 - 11 * L;
        for (int idx = tid; idx < 2048; idx += 256) hist[idx] = 0u;
        __syncthreads();
        unsigned long long pref = s_prefix;
        for (int i = tid; i < NPROP; i += 256) {
            unsigned long long k = K[i];
            bool in = (L == 0) || ((k >> (sh + 11)) == pref);
            if (in) atomicAdd(&hist[(uint32_t)((k >> sh) & 2047ull)], 1u);
        }
        __syncthreads();
        if (tid == 0) {
            int need = s_need; uint32_t cum = 0; int bsel = 2047;
            for (int t = 0; t < 2048; t++) {
                uint32_t c = hist[t];
                if (cum + c >= (uint32_t)need) { bsel = t; break; }
                cum += c;
            }
            s_need = need - (int)cum;
            s_prefix = (pref << 11) | (unsigned long long)bsel;
        }
        __syncthreads();
    }
    unsigned long long pref44 = s_prefix;
    for (int idx = tid; idx < 2048; idx += 256) { selk[idx] = ~0ull; seli[idx] = 0xFFFFFFFFu; }
    __syncthreads();
    for (int i = tid; i < NPROP; i += 256) {
        unsigned long long k = K[i];
        if ((k >> 20) <= pref44) {
            uint32_t posn = atomicAdd(&s_cnt, 1u);
            if (posn < 2048u) { selk[posn] = k; seli[posn] = (uint32_t)i; }
        }
    }
    __syncthreads();
    // bitonic sort 2048 ascending by (key, idx)
    for (unsigned k2 = 2; k2 <= 2048; k2 <<= 1) {
        for (unsigned j = k2 >> 1; j > 0; j >>= 1) {
            for (int t = tid; t < 2048; t += 256) {
                unsigned ixj = (unsigned)t ^ j;
                if (ixj > (unsigned)t) {
                    bool up = ((t & k2) == 0);
                    unsigned long long ka = selk[t], kb2 = selk[ixj];
                    uint32_t ia = seli[t], ib = seli[ixj];
                    bool agt = (ka > kb2) || (ka == kb2 && ia > ib);
                    if (up ? agt : !agt) {
                        selk[t] = kb2; selk[ixj] = ka;
                        seli[t] = ib;  seli[ixj] = ia;
                    }
                }
            }
            __syncthreads();
        }
    }
    for (int t = tid; t < 2048; t += 256) {
        unsigned long long kk = (t < PRE_NMS) ? selk[t] : ~0ull;
        uint32_t ii = (t < PRE_NMS) ? seli[t] : 0xFFFFFFFFu;
        double b0 = 0, b1 = 0, b2 = 0, b3 = 0;
        if (ii != 0xFFFFFFFFu) {
            const double* bp = boxes + ((size_t)n * NPROP + ii) * 4;
            b0 = bp[0]; b1 = bp[1]; b2 = bp[2]; b3 = bp[3];
        }
        if (t < PRE_NMS) skeys[(size_t)n * PRE_NMS + t] = kk;
        double* bs = bsort + ((size_t)n * 2048 + t) * 4;
        bs[0] = b0; bs[1] = b1; bs[2] = b2; bs[3] = b3;
        area[(size_t)n * 2048 + t] = fmax(b2 - b0, 0.0) * fmax(b3 - b1, 0.0);
    }
}

// ---------------- K4: pairwise IoU > 0.7 bitmask ----------------
__global__ __launch_bounds__(256) void k_iou(const double* __restrict__ bsort,
                                             const double* __restrict__ area,
                                             unsigned long long* __restrict__ mat)
{
    int blk = blockIdx.x; int n = blk >> 3; int rt = blk & 7;
    int tid = threadIdx.x;
    int i = rt * 256 + tid; // 0..2047
    const double* bp = bsort + ((size_t)n * 2048 + i) * 4;
    double bx0 = bp[0], bx1_ = bp[1], bx2_ = bp[2], bx3 = bp[3];
    double ai = area[(size_t)n * 2048 + i];
    __shared__ double cbx[512][4];
    __shared__ double ca[512];
    for (int c = 0; c < 4; c++) {
        __syncthreads();
        for (int idx = tid; idx < 512; idx += 256) {
            const double* sp = bsort + ((size_t)n * 2048 + c * 512 + idx) * 4;
            cbx[idx][0] = sp[0]; cbx[idx][1] = sp[1]; cbx[idx][2] = sp[2]; cbx[idx][3] = sp[3];
            ca[idx] = area[(size_t)n * 2048 + c * 512 + idx];
        }
        __syncthreads();
        unsigned long long* mp = mat + ((size_t)n * 2048 + i) * 32 + c * 8;
        for (int w8 = 0; w8 < 8; w8++) {
            unsigned long long wd = 0ull;
            for (int jb = 0; jb < 64; jb++) {
                int jj = w8 * 64 + jb;
                double ix1 = fmax(bx0, cbx[jj][0]);
                double iy1 = fmax(bx1_, cbx[jj][1]);
                double ix2 = fmin(bx2_, cbx[jj][2]);
                double iy2 = fmin(bx3, cbx[jj][3]);
                double inter = fmax(ix2 - ix1, 0.0) * fmax(iy2 - iy1, 0.0);
                double den = fmax(ai + ca[jj] - inter, 1e-9);
                double iou = inter / den;  // division, exactly as reference
                if (iou > 0.7) wd |= (1ull << jb);
            }
            mp[w8] = wd;
        }
    }
}

// ---------------- K5: sequential NMS scan + first-300-kept emission ----------------
__global__ __launch_bounds__(64) void k_nms(const unsigned long long* __restrict__ skeys,
                                            const double* __restrict__ bsort,
                                            const unsigned long long* __restrict__ mat,
                                            float* __restrict__ out)
{
    int n = blockIdx.x; int lane = threadIdx.x;
    float* dout = out + n * (POST_NMS * 5);
    for (int t = lane; t < POST_NMS * 5; t += 64) dout[t] = 0.f;
    __shared__ unsigned long long vb[32];
    __shared__ unsigned long long kbw[32];
    for (int i0 = 0; i0 < 2048; i0 += 64) {
        int i = i0 + lane;
        unsigned long long k = (i < PRE_NMS) ? skeys[(size_t)n * PRE_NMS + i] : ~0ull;
        unsigned long long m = __ballot(k != ~0ull);
        if (lane == 0) vb[i0 >> 6] = m;
    }
    __syncthreads();
    unsigned long long sup = 0ull, keepw = 0ull;
    for (int i = 0; i < PRE_NMS; i++) {
        int wi = i >> 6, bi = i & 63;
        unsigned long long sw = __shfl(sup, wi);
        bool vi = (vb[wi] >> bi) & 1ull;
        bool kp = vi && !((sw >> bi) & 1ull);
        if (kp) {
            if (lane < 32) sup |= mat[((size_t)n * 2048 + i) * 32 + lane];
            if (lane == wi) keepw |= (1ull << bi);
        }
    }
    if (lane < 32) kbw[lane] = keepw;
    __syncthreads();
    int running = 0;
    for (int i0 = 0; i0 < 2048; i0 += 64) {
        int i = i0 + lane;
        bool kp = (i < PRE_NMS) && ((kbw[i >> 6] >> (i & 63)) & 1ull);
        unsigned long long m = __ballot(kp);
        if (kp) {
            int rk = running + __popcll(m & ((1ull << lane) - 1ull));
            if (rk < POST_NMS) {
                const double* bp = bsort + ((size_t)n * 2048 + i) * 4;
                unsigned long long k = skeys[(size_t)n * PRE_NMS + i];
                double s = __longlong_as_double((long long)~k);
                float* o = dout + rk * 5;
                o[0] = (float)bp[0]; o[1] = (float)bp[1];
                o[2] = (float)bp[2]; o[3] = (float)bp[3];
                o[4] = (float)s;
            }
        }
        running += __popcll(m);
    }
}

extern "C" void kernel_launch(void* const* d_in, const int* in_sizes, int n_in,
                              void* d_out, int out_size, void* d_ws, size_t ws_size,
                              hipStream_t stream) {
    const float* feat   = (const float*)d_in[0];
    const float* conv_w = (const float*)d_in[1];
    const float* conv_b = (const float*)d_in[2];
    const float* det_w  = (const float*)d_in[3];
    const float* det_b  = (const float*)d_in[4];
    const float* reg_w  = (const float*)d_in[5];
    const float* reg_b  = (const float*)d_in[6];
    float* out = (float*)d_out;

    char* w = (char*)d_ws;
    float* X = (float*)w;                       w += (size_t)N_IMG * CIN * HW * 4;       // 64 MB
    double* BOX = (double*)w;                   w += (size_t)N_IMG * NPROP * 4 * 8;      // 6.29 MB
    unsigned long long* KEY = (unsigned long long*)w; w += (size_t)N_IMG * NPROP * 8;    // 1.57 MB
    unsigned long long* SKEY = (unsigned long long*)w; w += (size_t)N_IMG * PRE_NMS * 8; // 64 KB
    double* BSORT = (double*)w;                 w += (size_t)N_IMG * 2048 * 4 * 8;       // 256 KB
    double* AREA = (double*)w;                  w += (size_t)N_IMG * 2048 * 8;           // 64 KB
    unsigned long long* MAT = (unsigned long long*)w; w += (size_t)N_IMG * 2048 * 32 * 8; // 2 MB

    k_conv3<<<dim3(4096), dim3(256), 0, stream>>>(feat, conv_w, conv_b, X);
    k_heads<<<dim3(256), dim3(256), 0, stream>>>(X, det_w, det_b, reg_w, reg_b, BOX, KEY);
    k_select<<<dim3(N_IMG), dim3(256), 0, stream>>>(KEY, BOX, SKEY, BSORT, AREA);
    k_iou<<<dim3(N_IMG * 8), dim3(256), 0, stream>>>(BSORT, AREA, MAT);
    k_nms<<<dim3(N_IMG), dim3(64), 0, stream>>>(SKEY, BSORT, MAT, out);
}

// Round 2
// 3499.143 us; speedup vs baseline: 1.0275x; 1.0275x over previous
//
#include <hip/hip_runtime.h>
#include <hip/hip_bf16.h>
#include <hip/hip_fp16.h>
#include <stdint.h>
#include <math.h>

#define N_IMG 4
#define CIN 256
#define HFD 128
#define WFD 128
#define HW (HFD*WFD)        // 16384
#define NA 3
#define NPROP (NA*HW)       // 49152
#define PRE_NMS 2000
#define POST_NMS 300
#define CAND_CAP 8192
#define POS_CAP 3072
#define MARGIN 2e-3f

// ---------------- K1: 3x3 conv, fp32 accumulate, f16 store ----------------
// tile: 32co x 8h x 32w ; block 256 = (wt 8 -> 4w, ht 4 -> 2h, ct 8 -> 4co)
__global__ __launch_bounds__(256) void k_conv32(const float* __restrict__ feat,
                                                const float* __restrict__ cw,
                                                const float* __restrict__ cb,
                                                __half* __restrict__ X16)
{
    __shared__ float in_t[16][10][36];
    __shared__ float w_t[16][9][32];
    int b = blockIdx.x;
    int w_tile = b & 3; int h_tile = (b >> 2) & 15; int co_t = (b >> 6) & 7; int n = b >> 9;
    int co0 = co_t * 32, w0 = w_tile * 32, h0 = h_tile * 8;
    int tid = threadIdx.x;
    int wt = tid & 7, ht = (tid >> 3) & 3, ct = tid >> 5;

    float acc[4][2][4];
#pragma unroll
    for (int c = 0; c < 4; c++)
#pragma unroll
        for (int ih = 0; ih < 2; ih++)
#pragma unroll
            for (int iw = 0; iw < 4; iw++) acc[c][ih][iw] = 0.f;

    for (int ci0 = 0; ci0 < CIN; ci0 += 16) {
        for (int idx = tid; idx < 16 * 340; idx += 256) {
            int ci = idx / 340; int r2 = idx % 340; int dh = r2 / 34; int dw = r2 % 34;
            int gh = h0 - 1 + dh, gw = w0 - 1 + dw;
            float v = 0.f;
            if (gh >= 0 && gh < HFD && gw >= 0 && gw < WFD)
                v = feat[(((n << 8) + ci0 + ci) << 14) + (gh << 7) + gw];
            in_t[ci][dh][dw] = v;
        }
        for (int idx = tid; idx < 16 * 9 * 32; idx += 256) {
            int co = idx / 144; int r2 = idx % 144; int ci = r2 / 9; int rs = r2 % 9;
            w_t[ci][rs][co] = cw[(co0 + co) * 2304 + (ci0 + ci) * 9 + rs];
        }
        __syncthreads();
        for (int ci = 0; ci < 16; ci++) {
#pragma unroll
            for (int r = 0; r < 3; r++) {
                const float* rA = &in_t[ci][ht * 2 + r][wt * 4];
                const float* rB = &in_t[ci][ht * 2 + 1 + r][wt * 4];
                float a_[6], b_[6];
                float4 t4 = *(const float4*)rA;
                a_[0] = t4.x; a_[1] = t4.y; a_[2] = t4.z; a_[3] = t4.w; a_[4] = rA[4]; a_[5] = rA[5];
                t4 = *(const float4*)rB;
                b_[0] = t4.x; b_[1] = t4.y; b_[2] = t4.z; b_[3] = t4.w; b_[4] = rB[4]; b_[5] = rB[5];
#pragma unroll
                for (int s = 0; s < 3; s++) {
                    float4 wv = *(const float4*)&w_t[ci][r * 3 + s][ct * 4];
                    float wc[4] = {wv.x, wv.y, wv.z, wv.w};
#pragma unroll
                    for (int c = 0; c < 4; c++) {
#pragma unroll
                        for (int iw = 0; iw < 4; iw++) {
                            acc[c][0][iw] += wc[c] * a_[s + iw];
                            acc[c][1][iw] += wc[c] * b_[s + iw];
                        }
                    }
                }
            }
        }
        __syncthreads();
    }
#pragma unroll
    for (int c = 0; c < 4; c++) {
        int co = co0 + ct * 4 + c;
        float bias = cb[co];
#pragma unroll
        for (int ih = 0; ih < 2; ih++) {
            int hh = h0 + ht * 2 + ih;
#pragma unroll
            for (int iw = 0; iw < 4; iw++) {
                int ww = w0 + wt * 4 + iw;
                X16[(((size_t)((n << 8) + co)) << 14) + (hh << 7) + ww] = __float2half(acc[c][ih][iw] + bias);
            }
        }
    }
}

// ---------------- K2: fp32 heads + decode -> score32, key32; init posSlot/counts ----------------
__global__ __launch_bounds__(256) void k_heads32(const __half* __restrict__ X16,
                                                 const float* __restrict__ dw_, const float* __restrict__ db_,
                                                 const float* __restrict__ rw_, const float* __restrict__ rb_,
                                                 float* __restrict__ score32, uint32_t* __restrict__ key32,
                                                 uint32_t* __restrict__ posSlot, uint32_t* __restrict__ counts)
{
    __shared__ float wl[15][256];
    int tid = threadIdx.x;
    for (int idx = tid; idx < 15 * 256; idx += 256) {
        int r = idx >> 8;
        wl[r][idx & 255] = (r < 3) ? dw_[idx] : rw_[idx - 768];
    }
    __syncthreads();
    int p = blockIdx.x * 256 + tid;
    if (p < 8) counts[p] = 0u;
    posSlot[p] = 0xFFFFFFFFu;
    int n = p >> 14, pos = p & 16383;
    const __half* xp = X16 + ((size_t)n << 22) + pos;
    float acc[15];
#pragma unroll
    for (int c = 0; c < 15; c++) acc[c] = 0.f;
    for (int ci = 0; ci < 256; ci++) {
        float v = __half2float(xp[(size_t)ci << 14]);
#pragma unroll
        for (int c = 0; c < 15; c++) acc[c] += v * wl[c][ci];
    }
#pragma unroll
    for (int a = 0; a < 3; a++) {
        float logit = acc[a] + db_[a];
        float score = 1.f / (1.f + expf(-logit));
        float dx  = acc[3 + a]  + rb_[a];
        float dy  = acc[6 + a]  + rb_[3 + a];
        float dwv = acc[9 + a]  + rb_[6 + a];
        float dhv = acc[12 + a] + rb_[9 + a];
        int i = a * HW + pos;
        int loc = i / 3, aa = i % 3;
        int hh = loc >> 7, wwi = loc & 127;
        float sx = (float)(wwi * 8), sy = (float)(hh * 8);
        float bx1 = (aa == 0) ? -91.f : (aa == 1 ? -64.f : -45.f);
        float by1 = (aa == 0) ? -45.f : (aa == 1 ? -64.f : -91.f);
        float x1 = sx + bx1, y1 = sy + by1, x2 = sx - bx1, y2 = sy - by1;
        float aw = x2 - x1, ahh = y2 - y1;
        float acx = y1 + aw * 0.5f;   // (sic)
        float acy = x1 + ahh * 0.5f;  // (sic)
        float px = acx + dx * aw, py = acy + dy * ahh;
        float pw = aw * expf(dwv), ph = ahh * expf(dhv);
        float c1 = px - pw * 0.5f, c2 = py - ph * 0.5f, c3 = px + pw * 0.5f, c4 = py + ph * 0.5f;
        c1 = fminf(fmaxf(c1, 0.f), 1024.f);
        c2 = fminf(fmaxf(c2, 0.f), 1024.f);
        c3 = fminf(fmaxf(c3, 0.f), 1024.f);
        c4 = fminf(fmaxf(c4, 0.f), 1024.f);
        bool valid = (score > 0.3f) && (c3 - c1 > 0.f) && (c4 - c2 > 0.f);
        score32[(size_t)n * NPROP + i] = score;
        key32[(size_t)n * NPROP + i] = valid ? ~__float_as_uint(score) : 0xFFFFFFFFu;
    }
}

// ---------------- K3: per-image 2000th-key radix select + candidate compaction ----------------
__global__ __launch_bounds__(1024) void k_thresh(const uint32_t* __restrict__ key32,
                                                 const float* __restrict__ score32,
                                                 uint32_t* __restrict__ counts, uint32_t* __restrict__ posSlot,
                                                 uint32_t* __restrict__ PosList, uint32_t* __restrict__ PropList)
{
    int n = blockIdx.x; int tid = threadIdx.x;
    const uint32_t* K = key32 + (size_t)n * NPROP;
    __shared__ uint32_t hist[2048];
    __shared__ uint32_t psum[256];
    __shared__ uint32_t s_prefix;
    __shared__ int s_need;
    __shared__ float s_smargin;
    if (tid == 0) { s_prefix = 0u; s_need = PRE_NMS; }
    const int shifts[3] = {21, 10, 0};
    const uint32_t hmask[3] = {0u, 0xFFE00000u, 0xFFFFFC00u};
    const uint32_t bmask[3] = {2047u, 2047u, 1023u};
    for (int ps = 0; ps < 3; ps++) {
        for (int idx = tid; idx < 2048; idx += 1024) hist[idx] = 0u;
        __syncthreads();
        uint32_t pref = s_prefix;
        for (int i = tid; i < NPROP; i += 1024) {
            uint32_t k = K[i];
            if ((k & hmask[ps]) == pref) atomicAdd(&hist[(k >> shifts[ps]) & bmask[ps]], 1u);
        }
        __syncthreads();
        if (tid < 256) { uint32_t s = 0; for (int q = 0; q < 8; q++) s += hist[tid * 8 + q]; psum[tid] = s; }
        __syncthreads();
        if (tid == 0) {
            int need = s_need; uint32_t cum = 0; int g = 255;
            for (int t = 0; t < 256; t++) { uint32_t c = psum[t]; if (cum + c >= (uint32_t)need) { g = t; break; } cum += c; }
            int bsel = g * 8 + 7;
            for (int t = g * 8; t < g * 8 + 8; t++) { uint32_t c = hist[t]; if (cum + c >= (uint32_t)need) { bsel = t; break; } cum += c; }
            s_need = need - (int)cum;
            s_prefix = pref | ((uint32_t)bsel << shifts[ps]);
        }
        __syncthreads();
    }
    if (tid == 0) {
        uint32_t kth = s_prefix;
        s_smargin = (kth == 0xFFFFFFFFu) ? (0.3f - MARGIN) : (__uint_as_float(~kth) - MARGIN);
    }
    __syncthreads();
    float sm = s_smargin;
    const float* S = score32 + (size_t)n * NPROP;
    for (int i = tid; i < NPROP; i += 1024) {
        if (S[i] >= sm) {
            uint32_t j = atomicAdd(&counts[n], 1u);
            if (j < (uint32_t)CAND_CAP) PropList[n * CAND_CAP + j] = (uint32_t)i;
            int pos = i & 16383;
            if (atomicCAS(&posSlot[n * 16384 + pos], 0xFFFFFFFFu, 0xFFFFFFFEu) == 0xFFFFFFFFu) {
                uint32_t s = atomicAdd(&counts[4 + n], 1u);
                if (s < (uint32_t)POS_CAP) { posSlot[n * 16384 + pos] = s; PosList[n * POS_CAP + s] = (uint32_t)pos; }
            }
        }
    }
}

// ---------------- K3b: weight transpose for refine GEMM ----------------
__global__ __launch_bounds__(256) void k_wtr(const float* __restrict__ cw, float* __restrict__ wT) {
    int idx = blockIdx.x * 256 + threadIdx.x;  // 2304*256
    int k = idx >> 8, co = idx & 255;
    wT[idx] = cw[co * 2304 + k];
}

// ---------------- K4: fp64 conv GEMM at candidate positions ----------------
// block: 32 slots x 256 co; thread: (ci_l = co lane 0..31) x 4 cands; acc[8 co_blk][4]
__global__ __launch_bounds__(256) void k_refineX(const float* __restrict__ feat,
                                                 const float* __restrict__ wT, const float* __restrict__ cb_,
                                                 const uint32_t* __restrict__ PosList,
                                                 const uint32_t* __restrict__ counts,
                                                 double* __restrict__ X64)
{
    int blk = blockIdx.x; int n = blk / (POS_CAP / 32); int tile = blk % (POS_CAP / 32);
    uint32_t pc = counts[4 + n]; if (pc > (uint32_t)POS_CAP) pc = POS_CAP;
    int s0 = tile * 32;
    if (s0 >= (int)pc) return;
    __shared__ float Wt[32][256];
    __shared__ float P[32][32];
    __shared__ int hp[32], wp[32];
    int tid = threadIdx.x;
    if (tid < 32) {
        int sl = s0 + tid;
        uint32_t pos = (sl < (int)pc) ? PosList[n * POS_CAP + sl] : 0u;
        hp[tid] = (int)(pos >> 7); wp[tid] = (int)(pos & 127u);
    }
    __syncthreads();
    int ci_l = tid & 31; int jq = (tid >> 5) << 2;
    double acc[8][4];
#pragma unroll
    for (int cbk = 0; cbk < 8; cbk++)
#pragma unroll
        for (int q = 0; q < 4; q++) acc[cbk][q] = 0.0;
    const float* fb = feat + ((size_t)n << 22);
    for (int kb = 0; kb < 72; kb++) {
        int k0 = kb * 32;
        for (int idx = tid; idx < 32 * 256; idx += 256) {
            int kk = idx >> 8, co = idx & 255;
            Wt[kk][co] = wT[(size_t)(k0 + kk) * 256 + co];
        }
        for (int idx = tid; idx < 1024; idx += 256) {
            int kk = idx >> 5, j = idx & 31;
            int k = k0 + kk;
            int cj = k / 9; int rs = k - cj * 9; int r = rs / 3; int s = rs - r * 3;
            int gh = hp[j] + r - 1, gw = wp[j] + s - 1;
            float v = 0.f;
            if (gh >= 0 && gh < HFD && gw >= 0 && gw < WFD) v = fb[((size_t)cj << 14) + (gh << 7) + gw];
            P[kk][j] = v;
        }
        __syncthreads();
        for (int kk = 0; kk < 32; kk++) {
            float4 pv = *(const float4*)&P[kk][jq];
            double p0 = (double)pv.x, p1 = (double)pv.y, p2 = (double)pv.z, p3 = (double)pv.w;
#pragma unroll
            for (int cbk = 0; cbk < 8; cbk++) {
                double wv = (double)Wt[kk][(cbk << 5) + ci_l];
                acc[cbk][0] += wv * p0; acc[cbk][1] += wv * p1;
                acc[cbk][2] += wv * p2; acc[cbk][3] += wv * p3;
            }
        }
        __syncthreads();
    }
#pragma unroll
    for (int cbk = 0; cbk < 8; cbk++) {
        int co = (cbk << 5) + ci_l;
        double bias = (double)cb_[co];
#pragma unroll
        for (int q = 0; q < 4; q++) {
            int sl = s0 + jq + q;
            if (sl < (int)pc) X64[(((size_t)(n * POS_CAP + sl)) << 8) + co] = acc[cbk][q] + bias;
        }
    }
}

// ---------------- K5: fp64 heads + decode for candidates ----------------
__global__ __launch_bounds__(256) void k_refineHeads(const double* __restrict__ X64,
                                                     const float* __restrict__ dw_, const float* __restrict__ db_,
                                                     const float* __restrict__ rw_, const float* __restrict__ rb_,
                                                     const uint32_t* __restrict__ PropList,
                                                     const uint32_t* __restrict__ posSlot,
                                                     const uint32_t* __restrict__ counts,
                                                     unsigned long long* __restrict__ ckey,
                                                     uint32_t* __restrict__ cpidx,
                                                     double* __restrict__ cboxJ)
{
    __shared__ float wl[15][256];
    int tid = threadIdx.x;
    for (int idx = tid; idx < 15 * 256; idx += 256) {
        int r = idx >> 8;
        wl[r][idx & 255] = (r < 3) ? dw_[idx] : rw_[idx - 768];
    }
    __syncthreads();
    int jj = blockIdx.x * 256 + tid;
    int n = jj >> 13, j = jj & 8191;
    uint32_t cnt = counts[n]; if (cnt > (uint32_t)CAND_CAP) cnt = CAND_CAP;
    bool pad = (j >= (int)cnt);
    uint32_t i = 0, slot = 0;
    if (!pad) {
        i = PropList[n * CAND_CAP + j];
        slot = posSlot[n * 16384 + (i & 16383)];
        if (slot >= (uint32_t)POS_CAP) pad = true;
    }
    if (pad) {
        ckey[n * CAND_CAP + j] = ~0ull;
        cpidx[n * CAND_CAP + j] = 0xFFFFFFFFu;
        return;
    }
    const double* xc = X64 + (((size_t)(n * POS_CAP + (int)slot)) << 8);
    double acc[15];
#pragma unroll
    for (int c = 0; c < 15; c++) acc[c] = 0.0;
    for (int ci = 0; ci < 256; ci++) {
        double v = xc[ci];
#pragma unroll
        for (int c = 0; c < 15; c++) acc[c] += v * (double)wl[c][ci];
    }
    int a = (int)(i >> 14);
    double logit = acc[a] + (double)db_[a];
    double score = 1.0 / (1.0 + exp(-logit));
    double dx  = acc[3 + a]  + (double)rb_[a];
    double dy  = acc[6 + a]  + (double)rb_[3 + a];
    double dwv = acc[9 + a]  + (double)rb_[6 + a];
    double dhv = acc[12 + a] + (double)rb_[9 + a];
    int loc = (int)i / 3, aa = (int)i % 3;
    int hh = loc >> 7, wwi = loc & 127;
    double sx = (double)(wwi * 8), sy = (double)(hh * 8);
    double bx1 = (aa == 0) ? -91.0 : (aa == 1 ? -64.0 : -45.0);
    double by1 = (aa == 0) ? -45.0 : (aa == 1 ? -64.0 : -91.0);
    double x1 = sx + bx1, y1 = sy + by1, x2 = sx - bx1, y2 = sy - by1;
    double aw = x2 - x1, ahh = y2 - y1;
    double acx = y1 + aw * 0.5;   // (sic)
    double acy = x1 + ahh * 0.5;  // (sic)
    double px = acx + dx * aw, py = acy + dy * ahh;
    double pw = aw * exp(dwv), ph = ahh * exp(dhv);
    double c1 = px - pw * 0.5, c2 = py - ph * 0.5, c3 = px + pw * 0.5, c4 = py + ph * 0.5;
    c1 = fmin(fmax(c1, 0.0), 1024.0);
    c2 = fmin(fmax(c2, 0.0), 1024.0);
    c3 = fmin(fmax(c3, 0.0), 1024.0);
    c4 = fmin(fmax(c4, 0.0), 1024.0);
    bool valid = (score > 0.3) && (c3 - c1 > 0.0) && (c4 - c2 > 0.0);
    ckey[n * CAND_CAP + j] = valid ? ~((unsigned long long)__double_as_longlong(score)) : ~0ull;
    cpidx[n * CAND_CAP + j] = i;
    double* bp = cboxJ + (((size_t)(n * CAND_CAP + j)) << 2);
    bp[0] = c1; bp[1] = c2; bp[2] = c3; bp[3] = c4;
}

// ---------------- K6: exact top-2000 (radix over candidates + bitonic, idx tiebreak) ----------------
__global__ __launch_bounds__(256) void k_sort2000(const unsigned long long* __restrict__ ckey,
                                                  const uint32_t* __restrict__ cpidx,
                                                  const double* __restrict__ cboxJ,
                                                  unsigned long long* __restrict__ skeys,
                                                  double* __restrict__ bsort,
                                                  double* __restrict__ area)
{
    int n = blockIdx.x; int tid = threadIdx.x;
    const unsigned long long* K = ckey + (size_t)n * CAND_CAP;
    __shared__ uint32_t hist[2048];
    __shared__ uint32_t psum[256];
    __shared__ unsigned long long selk[2048];
    __shared__ uint32_t selp[2048];
    __shared__ uint32_t selj[2048];
    __shared__ unsigned long long s_prefix;
    __shared__ int s_need;
    __shared__ uint32_t s_cnt;
    if (tid == 0) { s_prefix = 0ull; s_need = PRE_NMS; s_cnt = 0u; }
    for (int L = 0; L < 4; L++) {
        int sh = 53 - 11 * L;
        for (int idx = tid; idx < 2048; idx += 256) hist[idx] = 0u;
        __syncthreads();
        unsigned long long pref = s_prefix;
        for (int i = tid; i < CAND_CAP; i += 256) {
            unsigned long long k = K[i];
            bool in = (L == 0) || ((k >> (sh + 11)) == pref);
            if (in) atomicAdd(&hist[(uint32_t)((k >> sh) & 2047ull)], 1u);
        }
        __syncthreads();
        if (tid < 256) { uint32_t s = 0; for (int q = 0; q < 8; q++) s += hist[tid * 8 + q]; psum[tid] = s; }
        __syncthreads();
        if (tid == 0) {
            int need = s_need; uint32_t cum = 0; int g = 255;
            for (int t = 0; t < 256; t++) { uint32_t c = psum[t]; if (cum + c >= (uint32_t)need) { g = t; break; } cum += c; }
            int bsel = g * 8 + 7;
            for (int t = g * 8; t < g * 8 + 8; t++) { uint32_t c = hist[t]; if (cum + c >= (uint32_t)need) { bsel = t; break; } cum += c; }
            s_need = need - (int)cum;
            s_prefix = (pref << 11) | (unsigned long long)bsel;
        }
        __syncthreads();
    }
    unsigned long long pref44 = s_prefix;
    for (int idx = tid; idx < 2048; idx += 256) { selk[idx] = ~0ull; selp[idx] = 0xFFFFFFFFu; selj[idx] = 0xFFFFFFFFu; }
    __syncthreads();
    for (int i = tid; i < CAND_CAP; i += 256) {
        unsigned long long k = K[i];
        if (k != ~0ull && (k >> 20) <= pref44) {
            uint32_t p2 = atomicAdd(&s_cnt, 1u);
            if (p2 < 2048u) { selk[p2] = k; selp[p2] = cpidx[(size_t)n * CAND_CAP + i]; selj[p2] = (uint32_t)i; }
        }
    }
    __syncthreads();
    for (unsigned k2 = 2; k2 <= 2048; k2 <<= 1) {
        for (unsigned jx = k2 >> 1; jx > 0; jx >>= 1) {
            for (int t = tid; t < 2048; t += 256) {
                unsigned ixj = (unsigned)t ^ jx;
                if (ixj > (unsigned)t) {
                    bool up = ((t & k2) == 0);
                    unsigned long long ka = selk[t], kb = selk[ixj];
                    uint32_t pa = selp[t], pb = selp[ixj];
                    uint32_t ja = selj[t], jb2 = selj[ixj];
                    bool agt = (ka > kb) || (ka == kb && pa > pb);
                    if (up ? agt : !agt) {
                        selk[t] = kb; selk[ixj] = ka;
                        selp[t] = pb; selp[ixj] = pa;
                        selj[t] = jb2; selj[ixj] = ja;
                    }
                }
            }
            __syncthreads();
        }
    }
    for (int t = tid; t < 2048; t += 256) {
        bool valid = (t < PRE_NMS) && (selk[t] != ~0ull);
        if (t < PRE_NMS) skeys[(size_t)n * PRE_NMS + t] = valid ? selk[t] : ~0ull;
        double b0 = 0, b1 = 0, b2 = 0, b3 = 0;
        if (valid) {
            const double* bp = cboxJ + (((size_t)(n * CAND_CAP + (int)selj[t])) << 2);
            b0 = bp[0]; b1 = bp[1]; b2 = bp[2]; b3 = bp[3];
        }
        double* bs = bsort + (((size_t)(n * 2048 + t)) << 2);
        bs[0] = b0; bs[1] = b1; bs[2] = b2; bs[3] = b3;
        area[(size_t)n * 2048 + t] = fmax(b2 - b0, 0.0) * fmax(b3 - b1, 0.0);
    }
}

// ---------------- K7: pairwise IoU > 0.7 bitmask ----------------
__global__ __launch_bounds__(256) void k_iou(const double* __restrict__ bsort,
                                             const double* __restrict__ area,
                                             unsigned long long* __restrict__ mat)
{
    int blk = blockIdx.x; int n = blk >> 3; int rt = blk & 7;
    int tid = threadIdx.x;
    int i = rt * 256 + tid;
    const double* bp = bsort + ((size_t)n * 2048 + i) * 4;
    double bx0 = bp[0], bx1_ = bp[1], bx2_ = bp[2], bx3 = bp[3];
    double ai = area[(size_t)n * 2048 + i];
    __shared__ double cbx[512][4];
    __shared__ double ca[512];
    for (int c = 0; c < 4; c++) {
        __syncthreads();
        for (int idx = tid; idx < 512; idx += 256) {
            const double* sp = bsort + ((size_t)n * 2048 + c * 512 + idx) * 4;
            cbx[idx][0] = sp[0]; cbx[idx][1] = sp[1]; cbx[idx][2] = sp[2]; cbx[idx][3] = sp[3];
            ca[idx] = area[(size_t)n * 2048 + c * 512 + idx];
        }
        __syncthreads();
        unsigned long long* mp = mat + ((size_t)n * 2048 + i) * 32 + c * 8;
        for (int w8 = 0; w8 < 8; w8++) {
            unsigned long long wd = 0ull;
            for (int jb = 0; jb < 64; jb++) {
                int jj = w8 * 64 + jb;
                double ix1 = fmax(bx0, cbx[jj][0]);
                double iy1 = fmax(bx1_, cbx[jj][1]);
                double ix2 = fmin(bx2_, cbx[jj][2]);
                double iy2 = fmin(bx3, cbx[jj][3]);
                double inter = fmax(ix2 - ix1, 0.0) * fmax(iy2 - iy1, 0.0);
                double den = fmax(ai + ca[jj] - inter, 1e-9);
                double iou = inter / den;
                if (iou > 0.7) wd |= (1ull << jb);
            }
            mp[w8] = wd;
        }
    }
}

// ---------------- K8: sequential NMS scan + first-300-kept emission ----------------
__global__ __launch_bounds__(64) void k_nms(const unsigned long long* __restrict__ skeys,
                                            const double* __restrict__ bsort,
                                            const unsigned long long* __restrict__ mat,
                                            float* __restrict__ out)
{
    int n = blockIdx.x; int lane = threadIdx.x;
    float* dout = out + n * (POST_NMS * 5);
    for (int t = lane; t < POST_NMS * 5; t += 64) dout[t] = 0.f;
    __shared__ unsigned long long vb[32];
    __shared__ unsigned long long kbw[32];
    for (int i0 = 0; i0 < 2048; i0 += 64) {
        int i = i0 + lane;
        unsigned long long k = (i < PRE_NMS) ? skeys[(size_t)n * PRE_NMS + i] : ~0ull;
        unsigned long long m = __ballot(k != ~0ull);
        if (lane == 0) vb[i0 >> 6] = m;
    }
    __syncthreads();
    unsigned long long sup = 0ull, keepw = 0ull;
    for (int i = 0; i < PRE_NMS; i++) {
        int wi = i >> 6, bi = i & 63;
        unsigned long long sw = __shfl(sup, wi);
        bool vi = (vb[wi] >> bi) & 1ull;
        bool kp = vi && !((sw >> bi) & 1ull);
        if (kp) {
            if (lane < 32) sup |= mat[((size_t)n * 2048 + i) * 32 + lane];
            if (lane == wi) keepw |= (1ull << bi);
        }
    }
    if (lane < 32) kbw[lane] = keepw;
    __syncthreads();
    int running = 0;
    for (int i0 = 0; i0 < 2048; i0 += 64) {
        int i = i0 + lane;
        bool kp = (i < PRE_NMS) && ((kbw[i >> 6] >> (i & 63)) & 1ull);
        unsigned long long m = __ballot(kp);
        if (kp) {
            int rk = running + __popcll(m & ((1ull << lane) - 1ull));
            if (rk < POST_NMS) {
                const double* bp = bsort + ((size_t)n * 2048 + i) * 4;
                unsigned long long k = skeys[(size_t)n * PRE_NMS + i];
                double s = __longlong_as_double((long long)~k);
                float* o = dout + rk * 5;
                o[0] = (float)bp[0]; o[1] = (float)bp[1];
                o[2] = (float)bp[2]; o[3] = (float)bp[3];
                o[4] = (float)s;
            }
        }
        running += __popcll(m);
    }
}

extern "C" void kernel_launch(void* const* d_in, const int* in_sizes, int n_in,
                              void* d_out, int out_size, void* d_ws, size_t ws_size,
                              hipStream_t stream) {
    (void)in_sizes; (void)n_in; (void)out_size; (void)ws_size;
    const float* feat   = (const float*)d_in[0];
    const float* conv_w = (const float*)d_in[1];
    const float* conv_b = (const float*)d_in[2];
    const float* det_w  = (const float*)d_in[3];
    const float* det_b  = (const float*)d_in[4];
    const float* reg_w  = (const float*)d_in[5];
    const float* reg_b  = (const float*)d_in[6];
    float* out = (float*)d_out;

    char* w = (char*)d_ws;
    __half* X16 = (__half*)w;                         w += (size_t)N_IMG * CIN * HW * 2;        // 32 MB
    float* wT = (float*)w;                            w += (size_t)2304 * 256 * 4;              // 2.36 MB
    float* SCORE = (float*)w;                         w += (size_t)N_IMG * NPROP * 4;
    uint32_t* KEY32 = (uint32_t*)w;                   w += (size_t)N_IMG * NPROP * 4;
    uint32_t* POSSLOT = (uint32_t*)w;                 w += (size_t)N_IMG * 16384 * 4;
    uint32_t* POSLIST = (uint32_t*)w;                 w += (size_t)N_IMG * POS_CAP * 4;
    uint32_t* PROPLIST = (uint32_t*)w;                w += (size_t)N_IMG * CAND_CAP * 4;
    uint32_t* COUNTS = (uint32_t*)w;                  w += 256;
    double* X64 = (double*)w;                         w += (size_t)N_IMG * POS_CAP * 256 * 8;   // 24 MB
    unsigned long long* CKEY = (unsigned long long*)w; w += (size_t)N_IMG * CAND_CAP * 8;
    uint32_t* CPIDX = (uint32_t*)w;                   w += (size_t)N_IMG * CAND_CAP * 4;
    double* CBOXJ = (double*)w;                       w += (size_t)N_IMG * CAND_CAP * 4 * 8;
    unsigned long long* SKEY = (unsigned long long*)w; w += (size_t)N_IMG * PRE_NMS * 8;
    double* BSORT = (double*)w;                       w += (size_t)N_IMG * 2048 * 4 * 8;
    double* AREA = (double*)w;                        w += (size_t)N_IMG * 2048 * 8;
    unsigned long long* MAT = (unsigned long long*)w; w += (size_t)N_IMG * 2048 * 32 * 8;

    k_conv32<<<dim3(2048), dim3(256), 0, stream>>>(feat, conv_w, conv_b, X16);
    k_wtr<<<dim3(2304), dim3(256), 0, stream>>>(conv_w, wT);
    k_heads32<<<dim3(256), dim3(256), 0, stream>>>(X16, det_w, det_b, reg_w, reg_b, SCORE, KEY32, POSSLOT, COUNTS);
    k_thresh<<<dim3(N_IMG), dim3(1024), 0, stream>>>(KEY32, SCORE, COUNTS, POSSLOT, POSLIST, PROPLIST);
    k_refineX<<<dim3(N_IMG * (POS_CAP / 32)), dim3(256), 0, stream>>>(feat, wT, conv_b, POSLIST, COUNTS, X64);
    k_refineHeads<<<dim3(N_IMG * CAND_CAP / 256), dim3(256), 0, stream>>>(X64, det_w, det_b, reg_w, reg_b,
                                                                          PROPLIST, POSSLOT, COUNTS, CKEY, CPIDX, CBOXJ);
    k_sort2000<<<dim3(N_IMG), dim3(256), 0, stream>>>(CKEY, CPIDX, CBOXJ, SKEY, BSORT, AREA);
    k_iou<<<dim3(N_IMG * 8), dim3(256), 0, stream>>>(BSORT, AREA, MAT);
    k_nms<<<dim3(N_IMG), dim3(64), 0, stream>>>(SKEY, BSORT, MAT, out);
}

// Round 3
// 2074.367 us; speedup vs baseline: 1.7332x; 1.6868x over previous
//
#include <hip/hip_runtime.h>
#include <hip/hip_bf16.h>
#include <hip/hip_fp16.h>
#include <stdint.h>
#include <math.h>

#define N_IMG 4
#define CIN 256
#define HFD 128
#define WFD 128
#define HW (HFD*WFD)        // 16384
#define NA 3
#define NPROP (NA*HW)       // 49152
#define PRE_NMS 2000
#define POST_NMS 300
#define CAND_CAP 8192
#define POS_CAP 3072
#define MARGIN 2e-3f

// ---------------- K0: effective weights E[k][16] = head_w . conv_w (fp64) ----------------
// E[(ci*9+rs)*16 + c] for c in 0..14 (c=15 pad = 0); EB32[c] = head_w.cb + head_b
__global__ __launch_bounds__(256) void k_effw(const float* __restrict__ cw, const float* __restrict__ cb,
                                              const float* __restrict__ dw_, const float* __restrict__ db_,
                                              const float* __restrict__ rw_, const float* __restrict__ rb_,
                                              float* __restrict__ E, float* __restrict__ EB32)
{
    int out = blockIdx.x * 256 + threadIdx.x;
    if (out < 36864) {
        int k2 = out >> 4, c = out & 15;
        if (c == 15) { E[out] = 0.f; return; }
        const float* hw = (c < 3) ? (dw_ + c * 256) : (rw_ + (c - 3) * 256);
        double s = 0.0;
#pragma unroll 4
        for (int co = 0; co < 256; co++) s += (double)hw[co] * (double)cw[co * 2304 + k2];
        E[out] = (float)s;
    } else if (out < 36864 + 16) {
        int c = out - 36864;
        double s = 0.0; float hb = 0.f;
        if (c < 15) {
            const float* hw = (c < 3) ? (dw_ + c * 256) : (rw_ + (c - 3) * 256);
            for (int co = 0; co < 256; co++) s += (double)hw[co] * (double)cb[co];
            hb = (c < 3) ? db_[c] : rb_[c - 3];
        }
        EB32[c] = (float)(s + (double)hb);
    }
}

// ---------------- K1: direct 15-output 3x3 conv (screen), fp32, ci-chunked ----------------
// grid 512 = 4 img x 32 htiles(4h) x 4 ci-chunks(64ci); block 256: tid&63 = w-pair, tid>>6 = hl
__global__ __launch_bounds__(256) void k_screen(const float* __restrict__ feat,
                                                const float* __restrict__ E,
                                                float* __restrict__ PL)
{
    __shared__ float in_t[8][6][132];
    __shared__ float wl[8][9][16];
    int b = blockIdx.x;
    int chunk = b & 3; int htile = (b >> 2) & 31; int n = b >> 7;
    int h0 = htile * 4;
    int tid = threadIdx.x;
    int q = tid & 63, hl = tid >> 6;
    int w0 = q * 2;
    float acc[15][2];
#pragma unroll
    for (int c = 0; c < 15; c++) { acc[c][0] = 0.f; acc[c][1] = 0.f; }

    for (int sl = 0; sl < 8; sl++) {
        int ci0 = chunk * 64 + sl * 8;
        for (int idx = tid; idx < 8 * 780; idx += 256) {
            int ci = idx / 780; int r2 = idx % 780; int dh = r2 / 130; int dw = r2 % 130;
            int gh = h0 - 1 + dh, gw = dw - 1;
            float v = 0.f;
            if (gh >= 0 && gh < HFD && gw >= 0 && gw < WFD)
                v = feat[(((n << 8) + ci0 + ci) << 14) + (gh << 7) + gw];
            in_t[ci][dh][dw] = v;
        }
        for (int idx = tid; idx < 8 * 144; idx += 256) {
            int ci = idx / 144; int rem = idx % 144;
            wl[ci][rem / 16][rem & 15] = E[(ci0 + ci) * 144 + rem];
        }
        __syncthreads();
        for (int ci = 0; ci < 8; ci++) {
#pragma unroll
            for (int r = 0; r < 3; r++) {
                float2 g0 = *(const float2*)&in_t[ci][hl + r][w0];
                float2 g1 = *(const float2*)&in_t[ci][hl + r][w0 + 2];
                float f[4] = {g0.x, g0.y, g1.x, g1.y};
#pragma unroll
                for (int s = 0; s < 3; s++) {
                    const float4* wp = (const float4*)&wl[ci][r * 3 + s][0];
                    float w16[16];
                    *(float4*)&w16[0] = wp[0]; *(float4*)&w16[4] = wp[1];
                    *(float4*)&w16[8] = wp[2]; *(float4*)&w16[12] = wp[3];
                    float pa = f[s], pb = f[s + 1];
#pragma unroll
                    for (int c = 0; c < 15; c++) {
                        acc[c][0] = fmaf(w16[c], pa, acc[c][0]);
                        acc[c][1] = fmaf(w16[c], pb, acc[c][1]);
                    }
                }
            }
        }
        __syncthreads();
    }
    int gpos = (n << 14) + ((h0 + hl) << 7) + w0;
#pragma unroll
    for (int c = 0; c < 15; c++) {
        PL[((chunk * 15 + c) << 16) + gpos] = acc[c][0];
        PL[((chunk * 15 + c) << 16) + gpos + 1] = acc[c][1];
    }
}

// ---------------- K2: combine partials + fp32 decode -> score32/key32, init posSlot/counts ----------------
__global__ __launch_bounds__(256) void k_decode(const float* __restrict__ PL, const float* __restrict__ EB32,
                                                float* __restrict__ score32, uint32_t* __restrict__ key32,
                                                uint32_t* __restrict__ posSlot, uint32_t* __restrict__ counts)
{
    int p = blockIdx.x * 256 + threadIdx.x;
    if (p < 8) counts[p] = 0u;
    posSlot[p] = 0xFFFFFFFFu;
    int n = p >> 14, pos = p & 16383;
    float L[15];
#pragma unroll
    for (int c = 0; c < 15; c++)
        L[c] = ((PL[((c) << 16) + p] + PL[((15 + c) << 16) + p]) +
                (PL[((30 + c) << 16) + p] + PL[((45 + c) << 16) + p])) + EB32[c];
#pragma unroll
    for (int a = 0; a < 3; a++) {
        float logit = L[a];
        float score = 1.f / (1.f + expf(-logit));
        float dx  = L[3 + a];
        float dy  = L[6 + a];
        float dwv = L[9 + a];
        float dhv = L[12 + a];
        int i = a * HW + pos;
        int loc = i / 3, aa = i % 3;
        int hh = loc >> 7, wwi = loc & 127;
        float sx = (float)(wwi * 8), sy = (float)(hh * 8);
        float bx1 = (aa == 0) ? -91.f : (aa == 1 ? -64.f : -45.f);
        float by1 = (aa == 0) ? -45.f : (aa == 1 ? -64.f : -91.f);
        float x1 = sx + bx1, y1 = sy + by1, x2 = sx - bx1, y2 = sy - by1;
        float aw = x2 - x1, ahh = y2 - y1;
        float acx = y1 + aw * 0.5f;   // (sic)
        float acy = x1 + ahh * 0.5f;  // (sic)
        float px = acx + dx * aw, py = acy + dy * ahh;
        float pw = aw * expf(dwv), ph = ahh * expf(dhv);
        float c1 = px - pw * 0.5f, c2 = py - ph * 0.5f, c3 = px + pw * 0.5f, c4 = py + ph * 0.5f;
        c1 = fminf(fmaxf(c1, 0.f), 1024.f);
        c2 = fminf(fmaxf(c2, 0.f), 1024.f);
        c3 = fminf(fmaxf(c3, 0.f), 1024.f);
        c4 = fminf(fmaxf(c4, 0.f), 1024.f);
        // STRICT validity for the threshold key (strict subset of true-valid => safe k-th stat)
        bool valid = (score > 0.3f + 5e-4f) && (c3 - c1 > 0.1f) && (c4 - c2 > 0.1f);
        score32[(size_t)n * NPROP + i] = score;
        key32[(size_t)n * NPROP + i] = valid ? ~__float_as_uint(score) : 0xFFFFFFFFu;
    }
}

// ---------------- K3: per-image 2000th-key radix select + candidate compaction ----------------
__global__ __launch_bounds__(1024) void k_thresh(const uint32_t* __restrict__ key32,
                                                 const float* __restrict__ score32,
                                                 uint32_t* __restrict__ counts, uint32_t* __restrict__ posSlot,
                                                 uint32_t* __restrict__ PosList, uint32_t* __restrict__ PropList)
{
    int n = blockIdx.x; int tid = threadIdx.x;
    const uint32_t* K = key32 + (size_t)n * NPROP;
    __shared__ uint32_t hist[2048];
    __shared__ uint32_t psum[256];
    __shared__ uint32_t s_prefix;
    __shared__ int s_need;
    __shared__ float s_smargin;
    if (tid == 0) { s_prefix = 0u; s_need = PRE_NMS; }
    const int shifts[3] = {21, 10, 0};
    const uint32_t hmask[3] = {0u, 0xFFE00000u, 0xFFFFFC00u};
    const uint32_t bmask[3] = {2047u, 2047u, 1023u};
    for (int ps = 0; ps < 3; ps++) {
        for (int idx = tid; idx < 2048; idx += 1024) hist[idx] = 0u;
        __syncthreads();
        uint32_t pref = s_prefix;
        for (int i = tid; i < NPROP; i += 1024) {
            uint32_t k = K[i];
            if ((k & hmask[ps]) == pref) atomicAdd(&hist[(k >> shifts[ps]) & bmask[ps]], 1u);
        }
        __syncthreads();
        if (tid < 256) { uint32_t s = 0; for (int q = 0; q < 8; q++) s += hist[tid * 8 + q]; psum[tid] = s; }
        __syncthreads();
        if (tid == 0) {
            int need = s_need; uint32_t cum = 0; int g = 255;
            for (int t = 0; t < 256; t++) { uint32_t c = psum[t]; if (cum + c >= (uint32_t)need) { g = t; break; } cum += c; }
            int bsel = g * 8 + 7;
            for (int t = g * 8; t < g * 8 + 8; t++) { uint32_t c = hist[t]; if (cum + c >= (uint32_t)need) { bsel = t; break; } cum += c; }
            s_need = need - (int)cum;
            s_prefix = pref | ((uint32_t)bsel << shifts[ps]);
        }
        __syncthreads();
    }
    if (tid == 0) {
        uint32_t kth = s_prefix;
        s_smargin = (kth == 0xFFFFFFFFu) ? (0.3f - MARGIN) : (__uint_as_float(~kth) - MARGIN);
    }
    __syncthreads();
    float sm = s_smargin;
    const float* S = score32 + (size_t)n * NPROP;
    for (int i = tid; i < NPROP; i += 1024) {
        if (S[i] >= sm) {
            uint32_t j = atomicAdd(&counts[n], 1u);
            if (j < (uint32_t)CAND_CAP) PropList[n * CAND_CAP + j] = (uint32_t)i;
            int pos = i & 16383;
            if (atomicCAS(&posSlot[n * 16384 + pos], 0xFFFFFFFFu, 0xFFFFFFFEu) == 0xFFFFFFFFu) {
                uint32_t s = atomicAdd(&counts[4 + n], 1u);
                if (s < (uint32_t)POS_CAP) { posSlot[n * 16384 + pos] = s; PosList[n * POS_CAP + s] = (uint32_t)pos; }
            }
        }
    }
}

// ---------------- K3b: weight transpose for refine GEMM ----------------
__global__ __launch_bounds__(256) void k_wtr(const float* __restrict__ cw, float* __restrict__ wT) {
    int idx = blockIdx.x * 256 + threadIdx.x;  // 2304*256
    int k = idx >> 8, co = idx & 255;
    wT[idx] = cw[co * 2304 + k];
}

// ---------------- K4: fp64 conv GEMM at candidate positions ----------------
__global__ __launch_bounds__(256) void k_refineX(const float* __restrict__ feat,
                                                 const float* __restrict__ wT, const float* __restrict__ cb_,
                                                 const uint32_t* __restrict__ PosList,
                                                 const uint32_t* __restrict__ counts,
                                                 double* __restrict__ X64)
{
    int blk = blockIdx.x; int n = blk / (POS_CAP / 32); int tile = blk % (POS_CAP / 32);
    uint32_t pc = counts[4 + n]; if (pc > (uint32_t)POS_CAP) pc = POS_CAP;
    int s0 = tile * 32;
    if (s0 >= (int)pc) return;
    __shared__ float Wt[32][256];
    __shared__ float P[32][32];
    __shared__ int hp[32], wp[32];
    int tid = threadIdx.x;
    if (tid < 32) {
        int sl = s0 + tid;
        uint32_t pos = (sl < (int)pc) ? PosList[n * POS_CAP + sl] : 0u;
        hp[tid] = (int)(pos >> 7); wp[tid] = (int)(pos & 127u);
    }
    __syncthreads();
    int ci_l = tid & 31; int jq = (tid >> 5) << 2;
    double acc[8][4];
#pragma unroll
    for (int cbk = 0; cbk < 8; cbk++)
#pragma unroll
        for (int q = 0; q < 4; q++) acc[cbk][q] = 0.0;
    const float* fb = feat + ((size_t)n << 22);
    for (int kb = 0; kb < 72; kb++) {
        int k0 = kb * 32;
        for (int idx = tid; idx < 32 * 256; idx += 256) {
            int kk = idx >> 8, co = idx & 255;
            Wt[kk][co] = wT[(size_t)(k0 + kk) * 256 + co];
        }
        for (int idx = tid; idx < 1024; idx += 256) {
            int kk = idx >> 5, j = idx & 31;
            int k = k0 + kk;
            int cj = k / 9; int rs = k - cj * 9; int r = rs / 3; int s = rs - r * 3;
            int gh = hp[j] + r - 1, gw = wp[j] + s - 1;
            float v = 0.f;
            if (gh >= 0 && gh < HFD && gw >= 0 && gw < WFD) v = fb[((size_t)cj << 14) + (gh << 7) + gw];
            P[kk][j] = v;
        }
        __syncthreads();
        for (int kk = 0; kk < 32; kk++) {
            float4 pv = *(const float4*)&P[kk][jq];
            double p0 = (double)pv.x, p1 = (double)pv.y, p2 = (double)pv.z, p3 = (double)pv.w;
#pragma unroll
            for (int cbk = 0; cbk < 8; cbk++) {
                double wv = (double)Wt[kk][(cbk << 5) + ci_l];
                acc[cbk][0] += wv * p0; acc[cbk][1] += wv * p1;
                acc[cbk][2] += wv * p2; acc[cbk][3] += wv * p3;
            }
        }
        __syncthreads();
    }
#pragma unroll
    for (int cbk = 0; cbk < 8; cbk++) {
        int co = (cbk << 5) + ci_l;
        double bias = (double)cb_[co];
#pragma unroll
        for (int q = 0; q < 4; q++) {
            int sl = s0 + jq + q;
            if (sl < (int)pc) X64[(((size_t)(n * POS_CAP + sl)) << 8) + co] = acc[cbk][q] + bias;
        }
    }
}

// ---------------- K5: fp64 heads + decode for candidates ----------------
__global__ __launch_bounds__(256) void k_refineHeads(const double* __restrict__ X64,
                                                     const float* __restrict__ dw_, const float* __restrict__ db_,
                                                     const float* __restrict__ rw_, const float* __restrict__ rb_,
                                                     const uint32_t* __restrict__ PropList,
                                                     const uint32_t* __restrict__ posSlot,
                                                     const uint32_t* __restrict__ counts,
                                                     unsigned long long* __restrict__ ckey,
                                                     uint32_t* __restrict__ cpidx,
                                                     double* __restrict__ cboxJ)
{
    __shared__ float wl[15][256];
    int tid = threadIdx.x;
    for (int idx = tid; idx < 15 * 256; idx += 256) {
        int r = idx >> 8;
        wl[r][idx & 255] = (r < 3) ? dw_[idx] : rw_[idx - 768];
    }
    __syncthreads();
    int jj = blockIdx.x * 256 + tid;
    int n = jj >> 13, j = jj & 8191;
    uint32_t cnt = counts[n]; if (cnt > (uint32_t)CAND_CAP) cnt = CAND_CAP;
    bool pad = (j >= (int)cnt);
    uint32_t i = 0, slot = 0;
    if (!pad) {
        i = PropList[n * CAND_CAP + j];
        slot = posSlot[n * 16384 + (i & 16383)];
        if (slot >= (uint32_t)POS_CAP) pad = true;
    }
    if (pad) {
        ckey[n * CAND_CAP + j] = ~0ull;
        cpidx[n * CAND_CAP + j] = 0xFFFFFFFFu;
        return;
    }
    const double* xc = X64 + (((size_t)(n * POS_CAP + (int)slot)) << 8);
    double acc[15];
#pragma unroll
    for (int c = 0; c < 15; c++) acc[c] = 0.0;
    for (int ci = 0; ci < 256; ci++) {
        double v = xc[ci];
#pragma unroll
        for (int c = 0; c < 15; c++) acc[c] += v * (double)wl[c][ci];
    }
    int a = (int)(i >> 14);
    double logit = acc[a] + (double)db_[a];
    double score = 1.0 / (1.0 + exp(-logit));
    double dx  = acc[3 + a]  + (double)rb_[a];
    double dy  = acc[6 + a]  + (double)rb_[3 + a];
    double dwv = acc[9 + a]  + (double)rb_[6 + a];
    double dhv = acc[12 + a] + (double)rb_[9 + a];
    int loc = (int)i / 3, aa = (int)i % 3;
    int hh = loc >> 7, wwi = loc & 127;
    double sx = (double)(wwi * 8), sy = (double)(hh * 8);
    double bx1 = (aa == 0) ? -91.0 : (aa == 1 ? -64.0 : -45.0);
    double by1 = (aa == 0) ? -45.0 : (aa == 1 ? -64.0 : -91.0);
    double x1 = sx + bx1, y1 = sy + by1, x2 = sx - bx1, y2 = sy - by1;
    double aw = x2 - x1, ahh = y2 - y1;
    double acx = y1 + aw * 0.5;   // (sic)
    double acy = x1 + ahh * 0.5;  // (sic)
    double px = acx + dx * aw, py = acy + dy * ahh;
    double pw = aw * exp(dwv), ph = ahh * exp(dhv);
    double c1 = px - pw * 0.5, c2 = py - ph * 0.5, c3 = px + pw * 0.5, c4 = py + ph * 0.5;
    c1 = fmin(fmax(c1, 0.0), 1024.0);
    c2 = fmin(fmax(c2, 0.0), 1024.0);
    c3 = fmin(fmax(c3, 0.0), 1024.0);
    c4 = fmin(fmax(c4, 0.0), 1024.0);
    bool valid = (score > 0.3) && (c3 - c1 > 0.0) && (c4 - c2 > 0.0);
    ckey[n * CAND_CAP + j] = valid ? ~((unsigned long long)__double_as_longlong(score)) : ~0ull;
    cpidx[n * CAND_CAP + j] = i;
    double* bp = cboxJ + (((size_t)(n * CAND_CAP + j)) << 2);
    bp[0] = c1; bp[1] = c2; bp[2] = c3; bp[3] = c4;
}

// ---------------- K6: exact top-2000 (radix over candidates + bitonic, idx tiebreak) ----------------
__global__ __launch_bounds__(256) void k_sort2000(const unsigned long long* __restrict__ ckey,
                                                  const uint32_t* __restrict__ cpidx,
                                                  const double* __restrict__ cboxJ,
                                                  unsigned long long* __restrict__ skeys,
                                                  double* __restrict__ bsort,
                                                  double* __restrict__ area)
{
    int n = blockIdx.x; int tid = threadIdx.x;
    const unsigned long long* K = ckey + (size_t)n * CAND_CAP;
    __shared__ uint32_t hist[2048];
    __shared__ uint32_t psum[256];
    __shared__ unsigned long long selk[2048];
    __shared__ uint32_t selp[2048];
    __shared__ uint32_t selj[2048];
    __shared__ unsigned long long s_prefix;
    __shared__ int s_need;
    __shared__ uint32_t s_cnt;
    if (tid == 0) { s_prefix = 0ull; s_need = PRE_NMS; s_cnt = 0u; }
    for (int L = 0; L < 4; L++) {
        int sh = 53 - 11 * L;
        for (int idx = tid; idx < 2048; idx += 256) hist[idx] = 0u;
        __syncthreads();
        unsigned long long pref = s_prefix;
        for (int i = tid; i < CAND_CAP; i += 256) {
            unsigned long long k = K[i];
            bool in = (L == 0) || ((k >> (sh + 11)) == pref);
            if (in) atomicAdd(&hist[(uint32_t)((k >> sh) & 2047ull)], 1u);
        }
        __syncthreads();
        if (tid < 256) { uint32_t s = 0; for (int q = 0; q < 8; q++) s += hist[tid * 8 + q]; psum[tid] = s; }
        __syncthreads();
        if (tid == 0) {
            int need = s_need; uint32_t cum = 0; int g = 255;
            for (int t = 0; t < 256; t++) { uint32_t c = psum[t]; if (cum + c >= (uint32_t)need) { g = t; break; } cum += c; }
            int bsel = g * 8 + 7;
            for (int t = g * 8; t < g * 8 + 8; t++) { uint32_t c = hist[t]; if (cum + c >= (uint32_t)need) { bsel = t; break; } cum += c; }
            s_need = need - (int)cum;
            s_prefix = (pref << 11) | (unsigned long long)bsel;
        }
        __syncthreads();
    }
    unsigned long long pref44 = s_prefix;
    for (int idx = tid; idx < 2048; idx += 256) { selk[idx] = ~0ull; selp[idx] = 0xFFFFFFFFu; selj[idx] = 0xFFFFFFFFu; }
    __syncthreads();
    for (int i = tid; i < CAND_CAP; i += 256) {
        unsigned long long k = K[i];
        if (k != ~0ull && (k >> 20) <= pref44) {
            uint32_t p2 = atomicAdd(&s_cnt, 1u);
            if (p2 < 2048u) { selk[p2] = k; selp[p2] = cpidx[(size_t)n * CAND_CAP + i]; selj[p2] = (uint32_t)i; }
        }
    }
    __syncthreads();
    for (unsigned k2 = 2; k2 <= 2048; k2 <<= 1) {
        for (unsigned jx = k2 >> 1; jx > 0; jx >>= 1) {
            for (int t = tid; t < 2048; t += 256) {
                unsigned ixj = (unsigned)t ^ jx;
                if (ixj > (unsigned)t) {
                    bool up = ((t & k2) == 0);
                    unsigned long long ka = selk[t], kb = selk[ixj];
                    uint32_t pa = selp[t], pb = selp[ixj];
                    uint32_t ja = selj[t], jb2 = selj[ixj];
                    bool agt = (ka > kb) || (ka == kb && pa > pb);
                    if (up ? agt : !agt) {
                        selk[t] = kb; selk[ixj] = ka;
                        selp[t] = pb; selp[ixj] = pa;
                        selj[t] = jb2; selj[ixj] = ja;
                    }
                }
            }
            __syncthreads();
        }
    }
    for (int t = tid; t < 2048; t += 256) {
        bool valid = (t < PRE_NMS) && (selk[t] != ~0ull);
        if (t < PRE_NMS) skeys[(size_t)n * PRE_NMS + t] = valid ? selk[t] : ~0ull;
        double b0 = 0, b1 = 0, b2 = 0, b3 = 0;
        if (valid) {
            const double* bp = cboxJ + (((size_t)(n * CAND_CAP + (int)selj[t])) << 2);
            b0 = bp[0]; b1 = bp[1]; b2 = bp[2]; b3 = bp[3];
        }
        double* bs = bsort + (((size_t)(n * 2048 + t)) << 2);
        bs[0] = b0; bs[1] = b1; bs[2] = b2; bs[3] = b3;
        area[(size_t)n * 2048 + t] = fmax(b2 - b0, 0.0) * fmax(b3 - b1, 0.0);
    }
}

// ---------------- K7: pairwise IoU > 0.7 bitmask ----------------
__global__ __launch_bounds__(256) void k_iou(const double* __restrict__ bsort,
                                             const double* __restrict__ area,
                                             unsigned long long* __restrict__ mat)
{
    int blk = blockIdx.x; int n = blk >> 3; int rt = blk & 7;
    int tid = threadIdx.x;
    int i = rt * 256 + tid;
    const double* bp = bsort + ((size_t)n * 2048 + i) * 4;
    double bx0 = bp[0], bx1_ = bp[1], bx2_ = bp[2], bx3 = bp[3];
    double ai = area[(size_t)n * 2048 + i];
    __shared__ double cbx[512][4];
    __shared__ double ca[512];
    for (int c = 0; c < 4; c++) {
        __syncthreads();
        for (int idx = tid; idx < 512; idx += 256) {
            const double* sp = bsort + ((size_t)n * 2048 + c * 512 + idx) * 4;
            cbx[idx][0] = sp[0]; cbx[idx][1] = sp[1]; cbx[idx][2] = sp[2]; cbx[idx][3] = sp[3];
            ca[idx] = area[(size_t)n * 2048 + c * 512 + idx];
        }
        __syncthreads();
        unsigned long long* mp = mat + ((size_t)n * 2048 + i) * 32 + c * 8;
        for (int w8 = 0; w8 < 8; w8++) {
            unsigned long long wd = 0ull;
            for (int jb = 0; jb < 64; jb++) {
                int jj = w8 * 64 + jb;
                double ix1 = fmax(bx0, cbx[jj][0]);
                double iy1 = fmax(bx1_, cbx[jj][1]);
                double ix2 = fmin(bx2_, cbx[jj][2]);
                double iy2 = fmin(bx3, cbx[jj][3]);
                double inter = fmax(ix2 - ix1, 0.0) * fmax(iy2 - iy1, 0.0);
                double den = fmax(ai + ca[jj] - inter, 1e-9);
                double iou = inter / den;
                if (iou > 0.7) wd |= (1ull << jb);
            }
            mp[w8] = wd;
        }
    }
}

// ---------------- K8: sequential NMS scan + first-300-kept emission ----------------
__global__ __launch_bounds__(64) void k_nms(const unsigned long long* __restrict__ skeys,
                                            const double* __restrict__ bsort,
                                            const unsigned long long* __restrict__ mat,
                                            float* __restrict__ out)
{
    int n = blockIdx.x; int lane = threadIdx.x;
    float* dout = out + n * (POST_NMS * 5);
    for (int t = lane; t < POST_NMS * 5; t += 64) dout[t] = 0.f;
    __shared__ unsigned long long vb[32];
    __shared__ unsigned long long kbw[32];
    for (int i0 = 0; i0 < 2048; i0 += 64) {
        int i = i0 + lane;
        unsigned long long k = (i < PRE_NMS) ? skeys[(size_t)n * PRE_NMS + i] : ~0ull;
        unsigned long long m = __ballot(k != ~0ull);
        if (lane == 0) vb[i0 >> 6] = m;
    }
    __syncthreads();
    unsigned long long sup = 0ull, keepw = 0ull;
    for (int i = 0; i < PRE_NMS; i++) {
        int wi = i >> 6, bi = i & 63;
        unsigned long long sw = __shfl(sup, wi);
        bool vi = (vb[wi] >> bi) & 1ull;
        bool kp = vi && !((sw >> bi) & 1ull);
        if (kp) {
            if (lane < 32) sup |= mat[((size_t)n * 2048 + i) * 32 + lane];
            if (lane == wi) keepw |= (1ull << bi);
        }
    }
    if (lane < 32) kbw[lane] = keepw;
    __syncthreads();
    int running = 0;
    for (int i0 = 0; i0 < 2048; i0 += 64) {
        int i = i0 + lane;
        bool kp = (i < PRE_NMS) && ((kbw[i >> 6] >> (i & 63)) & 1ull);
        unsigned long long m = __ballot(kp);
        if (kp) {
            int rk = running + __popcll(m & ((1ull << lane) - 1ull));
            if (rk < POST_NMS) {
                const double* bp = bsort + ((size_t)n * 2048 + i) * 4;
                unsigned long long k = skeys[(size_t)n * PRE_NMS + i];
                double s = __longlong_as_double((long long)~k);
                float* o = dout + rk * 5;
                o[0] = (float)bp[0]; o[1] = (float)bp[1];
                o[2] = (float)bp[2]; o[3] = (float)bp[3];
                o[4] = (float)s;
            }
        }
        running += __popcll(m);
    }
}

extern "C" void kernel_launch(void* const* d_in, const int* in_sizes, int n_in,
                              void* d_out, int out_size, void* d_ws, size_t ws_size,
                              hipStream_t stream) {
    (void)in_sizes; (void)n_in; (void)out_size; (void)ws_size;
    const float* feat   = (const float*)d_in[0];
    const float* conv_w = (const float*)d_in[1];
    const float* conv_b = (const float*)d_in[2];
    const float* det_w  = (const float*)d_in[3];
    const float* det_b  = (const float*)d_in[4];
    const float* reg_w  = (const float*)d_in[5];
    const float* reg_b  = (const float*)d_in[6];
    float* out = (float*)d_out;

    char* w = (char*)d_ws;
    float* E = (float*)w;                             w += (size_t)2304 * 16 * 4;               // 147 KB
    float* EB32 = (float*)w;                          w += 64;
    float* PL = (float*)w;                            w += (size_t)60 * 65536 * 4;              // 15.7 MB
    float* SCORE = (float*)w;                         w += (size_t)N_IMG * NPROP * 4;
    uint32_t* KEY32 = (uint32_t*)w;                   w += (size_t)N_IMG * NPROP * 4;
    uint32_t* POSSLOT = (uint32_t*)w;                 w += (size_t)N_IMG * 16384 * 4;
    uint32_t* POSLIST = (uint32_t*)w;                 w += (size_t)N_IMG * POS_CAP * 4;
    uint32_t* PROPLIST = (uint32_t*)w;                w += (size_t)N_IMG * CAND_CAP * 4;
    uint32_t* COUNTS = (uint32_t*)w;                  w += 1024;
    float* wT = (float*)w;                            w += (size_t)2304 * 256 * 4;              // 2.36 MB
    double* X64 = (double*)w;                         w += (size_t)N_IMG * POS_CAP * 256 * 8;   // 25.2 MB
    unsigned long long* CKEY = (unsigned long long*)w; w += (size_t)N_IMG * CAND_CAP * 8;
    uint32_t* CPIDX = (uint32_t*)w;                   w += (size_t)N_IMG * CAND_CAP * 4;
    double* CBOXJ = (double*)w;                       w += (size_t)N_IMG * CAND_CAP * 4 * 8;
    unsigned long long* SKEY = (unsigned long long*)w; w += (size_t)N_IMG * PRE_NMS * 8;
    double* BSORT = (double*)w;                       w += (size_t)N_IMG * 2048 * 4 * 8;
    double* AREA = (double*)w;                        w += (size_t)N_IMG * 2048 * 8;
    unsigned long long* MAT = (unsigned long long*)w; w += (size_t)N_IMG * 2048 * 32 * 8;

    k_effw<<<dim3(145), dim3(256), 0, stream>>>(conv_w, conv_b, det_w, det_b, reg_w, reg_b, E, EB32);
    k_screen<<<dim3(512), dim3(256), 0, stream>>>(feat, E, PL);
    k_decode<<<dim3(256), dim3(256), 0, stream>>>(PL, EB32, SCORE, KEY32, POSSLOT, COUNTS);
    k_thresh<<<dim3(N_IMG), dim3(1024), 0, stream>>>(KEY32, SCORE, COUNTS, POSSLOT, POSLIST, PROPLIST);
    k_wtr<<<dim3(2304), dim3(256), 0, stream>>>(conv_w, wT);
    k_refineX<<<dim3(N_IMG * (POS_CAP / 32)), dim3(256), 0, stream>>>(feat, wT, conv_b, POSLIST, COUNTS, X64);
    k_refineHeads<<<dim3(N_IMG * CAND_CAP / 256), dim3(256), 0, stream>>>(X64, det_w, det_b, reg_w, reg_b,
                                                                          PROPLIST, POSSLOT, COUNTS, CKEY, CPIDX, CBOXJ);
    k_sort2000<<<dim3(N_IMG), dim3(256), 0, stream>>>(CKEY, CPIDX, CBOXJ, SKEY, BSORT, AREA);
    k_iou<<<dim3(N_IMG * 8), dim3(256), 0, stream>>>(BSORT, AREA, MAT);
    k_nms<<<dim3(N_IMG), dim3(64), 0, stream>>>(SKEY, BSORT, MAT, out);
}

// Round 4
// 1828.555 us; speedup vs baseline: 1.9662x; 1.1344x over previous
//
#include <hip/hip_runtime.h>
#include <hip/hip_bf16.h>
#include <hip/hip_fp16.h>
#include <stdint.h>
#include <math.h>

#define N_IMG 4
#define CIN 256
#define HFD 128
#define WFD 128
#define HW (HFD*WFD)        // 16384
#define NA 3
#define NPROP (NA*HW)       // 49152
#define PRE_NMS 2000
#define POST_NMS 300
#define CAND_CAP 8192
#define POS_CAP 3072
#define MARGIN 2e-3f

// ---------------- K0: effective weights (fp64 + fp32 copies) ----------------
// E64/E32[(ci*9+rs)*16 + c], c in 0..14 (c=15 pad); EB = head_w.cb + head_b
__global__ __launch_bounds__(256) void k_effw64(const float* __restrict__ cw, const float* __restrict__ cb,
                                                const float* __restrict__ dw_, const float* __restrict__ db_,
                                                const float* __restrict__ rw_, const float* __restrict__ rb_,
                                                double* __restrict__ E64, float* __restrict__ E32,
                                                double* __restrict__ EB64, float* __restrict__ EB32)
{
    int out = blockIdx.x * 256 + threadIdx.x;
    if (out < 36864) {
        int k2 = out >> 4, c = out & 15;
        if (c == 15) { E64[out] = 0.0; E32[out] = 0.f; return; }
        const float* hw = (c < 3) ? (dw_ + c * 256) : (rw_ + (c - 3) * 256);
        double s = 0.0;
#pragma unroll 4
        for (int co = 0; co < 256; co++) s += (double)hw[co] * (double)cw[co * 2304 + k2];
        E64[out] = s; E32[out] = (float)s;
    } else if (out < 36864 + 16) {
        int c = out - 36864;
        double s = 0.0; double hb = 0.0;
        if (c < 15) {
            const float* hw = (c < 3) ? (dw_ + c * 256) : (rw_ + (c - 3) * 256);
            for (int co = 0; co < 256; co++) s += (double)hw[co] * (double)cb[co];
            hb = (double)((c < 3) ? db_[c] : rb_[c - 3]);
        }
        EB64[c] = s + hb; EB32[c] = (float)(s + hb);
    }
}

// ---------------- K1: direct 15-output 3x3 conv (screen), fp32, ci-chunked ----------------
__global__ __launch_bounds__(256) void k_screen(const float* __restrict__ feat,
                                                const float* __restrict__ E,
                                                float* __restrict__ PL)
{
    __shared__ float in_t[8][6][132];
    __shared__ float wl[8][9][16];
    int b = blockIdx.x;
    int chunk = b & 3; int htile = (b >> 2) & 31; int n = b >> 7;
    int h0 = htile * 4;
    int tid = threadIdx.x;
    int q = tid & 63, hl = tid >> 6;
    int w0 = q * 2;
    float acc[15][2];
#pragma unroll
    for (int c = 0; c < 15; c++) { acc[c][0] = 0.f; acc[c][1] = 0.f; }

    for (int sl = 0; sl < 8; sl++) {
        int ci0 = chunk * 64 + sl * 8;
        for (int idx = tid; idx < 8 * 780; idx += 256) {
            int ci = idx / 780; int r2 = idx % 780; int dh = r2 / 130; int dw = r2 % 130;
            int gh = h0 - 1 + dh, gw = dw - 1;
            float v = 0.f;
            if (gh >= 0 && gh < HFD && gw >= 0 && gw < WFD)
                v = feat[(((n << 8) + ci0 + ci) << 14) + (gh << 7) + gw];
            in_t[ci][dh][dw] = v;
        }
        for (int idx = tid; idx < 8 * 144; idx += 256) {
            int ci = idx / 144; int rem = idx % 144;
            wl[ci][rem / 16][rem & 15] = E[(ci0 + ci) * 144 + rem];
        }
        __syncthreads();
        for (int ci = 0; ci < 8; ci++) {
#pragma unroll
            for (int r = 0; r < 3; r++) {
                float2 g0 = *(const float2*)&in_t[ci][hl + r][w0];
                float2 g1 = *(const float2*)&in_t[ci][hl + r][w0 + 2];
                float f[4] = {g0.x, g0.y, g1.x, g1.y};
#pragma unroll
                for (int s = 0; s < 3; s++) {
                    const float4* wp = (const float4*)&wl[ci][r * 3 + s][0];
                    float w16[16];
                    *(float4*)&w16[0] = wp[0]; *(float4*)&w16[4] = wp[1];
                    *(float4*)&w16[8] = wp[2]; *(float4*)&w16[12] = wp[3];
                    float pa = f[s], pb = f[s + 1];
#pragma unroll
                    for (int c = 0; c < 15; c++) {
                        acc[c][0] = fmaf(w16[c], pa, acc[c][0]);
                        acc[c][1] = fmaf(w16[c], pb, acc[c][1]);
                    }
                }
            }
        }
        __syncthreads();
    }
    int gpos = (n << 14) + ((h0 + hl) << 7) + w0;
#pragma unroll
    for (int c = 0; c < 15; c++) {
        PL[((chunk * 15 + c) << 16) + gpos] = acc[c][0];
        PL[((chunk * 15 + c) << 16) + gpos + 1] = acc[c][1];
    }
}

// ---------------- K2: combine partials + fp32 decode -> score32/key32 ----------------
__global__ __launch_bounds__(256) void k_decode(const float* __restrict__ PL, const float* __restrict__ EB32,
                                                float* __restrict__ score32, uint32_t* __restrict__ key32,
                                                uint32_t* __restrict__ posSlot, uint32_t* __restrict__ counts)
{
    int p = blockIdx.x * 256 + threadIdx.x;
    if (p < 8) counts[p] = 0u;
    posSlot[p] = 0xFFFFFFFFu;
    int n = p >> 14, pos = p & 16383;
    float L[15];
#pragma unroll
    for (int c = 0; c < 15; c++)
        L[c] = ((PL[((c) << 16) + p] + PL[((15 + c) << 16) + p]) +
                (PL[((30 + c) << 16) + p] + PL[((45 + c) << 16) + p])) + EB32[c];
#pragma unroll
    for (int a = 0; a < 3; a++) {
        float logit = L[a];
        float score = 1.f / (1.f + expf(-logit));
        float dx  = L[3 + a];
        float dy  = L[6 + a];
        float dwv = L[9 + a];
        float dhv = L[12 + a];
        int i = a * HW + pos;
        int loc = i / 3, aa = i % 3;
        int hh = loc >> 7, wwi = loc & 127;
        float sx = (float)(wwi * 8), sy = (float)(hh * 8);
        float bx1 = (aa == 0) ? -91.f : (aa == 1 ? -64.f : -45.f);
        float by1 = (aa == 0) ? -45.f : (aa == 1 ? -64.f : -91.f);
        float x1 = sx + bx1, y1 = sy + by1, x2 = sx - bx1, y2 = sy - by1;
        float aw = x2 - x1, ahh = y2 - y1;
        float acx = y1 + aw * 0.5f;   // (sic)
        float acy = x1 + ahh * 0.5f;  // (sic)
        float px = acx + dx * aw, py = acy + dy * ahh;
        float pw = aw * expf(dwv), ph = ahh * expf(dhv);
        float c1 = px - pw * 0.5f, c2 = py - ph * 0.5f, c3 = px + pw * 0.5f, c4 = py + ph * 0.5f;
        c1 = fminf(fmaxf(c1, 0.f), 1024.f);
        c2 = fminf(fmaxf(c2, 0.f), 1024.f);
        c3 = fminf(fmaxf(c3, 0.f), 1024.f);
        c4 = fminf(fmaxf(c4, 0.f), 1024.f);
        bool valid = (score > 0.3f + 5e-4f) && (c3 - c1 > 0.1f) && (c4 - c2 > 0.1f);
        score32[(size_t)n * NPROP + i] = score;
        key32[(size_t)n * NPROP + i] = valid ? ~__float_as_uint(score) : 0xFFFFFFFFu;
    }
}

// ---------------- K3: per-image 2000th-key radix select + candidate compaction ----------------
__global__ __launch_bounds__(1024) void k_thresh(const uint32_t* __restrict__ key32,
                                                 const float* __restrict__ score32,
                                                 uint32_t* __restrict__ counts, uint32_t* __restrict__ posSlot,
                                                 uint32_t* __restrict__ PosList, uint32_t* __restrict__ PropList)
{
    int n = blockIdx.x; int tid = threadIdx.x;
    const uint32_t* K = key32 + (size_t)n * NPROP;
    __shared__ uint32_t hist[2048];
    __shared__ uint32_t psum[256];
    __shared__ uint32_t s_prefix;
    __shared__ int s_need;
    __shared__ float s_smargin;
    if (tid == 0) { s_prefix = 0u; s_need = PRE_NMS; }
    const int shifts[3] = {21, 10, 0};
    const uint32_t hmask[3] = {0u, 0xFFE00000u, 0xFFFFFC00u};
    const uint32_t bmask[3] = {2047u, 2047u, 1023u};
    for (int ps = 0; ps < 3; ps++) {
        for (int idx = tid; idx < 2048; idx += 1024) hist[idx] = 0u;
        __syncthreads();
        uint32_t pref = s_prefix;
        for (int i = tid; i < NPROP; i += 1024) {
            uint32_t k = K[i];
            if ((k & hmask[ps]) == pref) atomicAdd(&hist[(k >> shifts[ps]) & bmask[ps]], 1u);
        }
        __syncthreads();
        if (tid < 256) { uint32_t s = 0; for (int q = 0; q < 8; q++) s += hist[tid * 8 + q]; psum[tid] = s; }
        __syncthreads();
        if (tid == 0) {
            int need = s_need; uint32_t cum = 0; int g = 255;
            for (int t = 0; t < 256; t++) { uint32_t c = psum[t]; if (cum + c >= (uint32_t)need) { g = t; break; } cum += c; }
            int bsel = g * 8 + 7;
            for (int t = g * 8; t < g * 8 + 8; t++) { uint32_t c = hist[t]; if (cum + c >= (uint32_t)need) { bsel = t; break; } cum += c; }
            s_need = need - (int)cum;
            s_prefix = pref | ((uint32_t)bsel << shifts[ps]);
        }
        __syncthreads();
    }
    if (tid == 0) {
        uint32_t kth = s_prefix;
        s_smargin = (kth == 0xFFFFFFFFu) ? (0.3f - MARGIN) : (__uint_as_float(~kth) - MARGIN);
    }
    __syncthreads();
    float sm = s_smargin;
    const float* S = score32 + (size_t)n * NPROP;
    for (int i = tid; i < NPROP; i += 1024) {
        if (S[i] >= sm) {
            uint32_t j = atomicAdd(&counts[n], 1u);
            if (j < (uint32_t)CAND_CAP) PropList[n * CAND_CAP + j] = (uint32_t)i;
            int pos = i & 16383;
            if (atomicCAS(&posSlot[n * 16384 + pos], 0xFFFFFFFFu, 0xFFFFFFFEu) == 0xFFFFFFFFu) {
                uint32_t s = atomicAdd(&counts[4 + n], 1u);
                if (s < (uint32_t)POS_CAP) { posSlot[n * 16384 + pos] = s; PosList[n * POS_CAP + s] = (uint32_t)pos; }
            }
        }
    }
}

// ---------------- K4: fp64 fused logits at candidate positions ----------------
// block 256 = 16 positions x 16 lanes (lane c computes logit c; c=15 idle)
__global__ __launch_bounds__(256) void k_refineL(const float* __restrict__ feat,
                                                 const double* __restrict__ E64, const double* __restrict__ EB64,
                                                 const uint32_t* __restrict__ PosList,
                                                 const uint32_t* __restrict__ counts,
                                                 double* __restrict__ L64)
{
    int blk = blockIdx.x;
    int n = blk / (POS_CAP / 16); int t = blk % (POS_CAP / 16);
    uint32_t pc = counts[4 + n]; if (pc > (uint32_t)POS_CAP) pc = POS_CAP;
    int tid = threadIdx.x;
    int g = tid >> 4, c = tid & 15;
    int slot = t * 16 + g;
    if (slot >= (int)pc || c >= 15) return;
    uint32_t pos = PosList[n * POS_CAP + slot];
    int h = (int)(pos >> 7), w = (int)(pos & 127u);
    const float* fb = feat + ((size_t)n << 22) + (h << 7) + w;
    bool hv0 = (h - 1 >= 0), hv2 = (h + 1 < HFD);
    bool wv0 = (w - 1 >= 0), wv2 = (w + 1 < WFD);
    double acc = 0.0;
    for (int cj = 0; cj < 256; cj++) {
        const float* base = fb + ((size_t)cj << 14);
        const double* Ek = E64 + (size_t)(cj * 9) * 16 + c;
        float v0 = (hv0 && wv0) ? base[-129] : 0.f;
        float v1 = hv0 ? base[-128] : 0.f;
        float v2 = (hv0 && wv2) ? base[-127] : 0.f;
        float v3 = wv0 ? base[-1] : 0.f;
        float v4 = base[0];
        float v5 = wv2 ? base[1] : 0.f;
        float v6 = (hv2 && wv0) ? base[127] : 0.f;
        float v7 = hv2 ? base[128] : 0.f;
        float v8 = (hv2 && wv2) ? base[129] : 0.f;
        acc += Ek[0 * 16] * (double)v0;
        acc += Ek[1 * 16] * (double)v1;
        acc += Ek[2 * 16] * (double)v2;
        acc += Ek[3 * 16] * (double)v3;
        acc += Ek[4 * 16] * (double)v4;
        acc += Ek[5 * 16] * (double)v5;
        acc += Ek[6 * 16] * (double)v6;
        acc += Ek[7 * 16] * (double)v7;
        acc += Ek[8 * 16] * (double)v8;
    }
    L64[(((size_t)(n * POS_CAP + slot)) << 4) + c] = acc + EB64[c];
}

// ---------------- K5: fp64 decode for candidates (reads fused logits) ----------------
__global__ __launch_bounds__(256) void k_refineDecode(const double* __restrict__ L64,
                                                      const uint32_t* __restrict__ PropList,
                                                      const uint32_t* __restrict__ posSlot,
                                                      const uint32_t* __restrict__ counts,
                                                      unsigned long long* __restrict__ ckey,
                                                      uint32_t* __restrict__ cpidx,
                                                      double* __restrict__ cboxJ)
{
    int jj = blockIdx.x * 256 + threadIdx.x;
    int n = jj >> 13, j = jj & 8191;
    uint32_t cnt = counts[n]; if (cnt > (uint32_t)CAND_CAP) cnt = CAND_CAP;
    bool pad = (j >= (int)cnt);
    uint32_t i = 0, slot = 0;
    if (!pad) {
        i = PropList[n * CAND_CAP + j];
        slot = posSlot[n * 16384 + (i & 16383)];
        if (slot >= (uint32_t)POS_CAP) pad = true;
    }
    if (pad) {
        ckey[n * CAND_CAP + j] = ~0ull;
        cpidx[n * CAND_CAP + j] = 0xFFFFFFFFu;
        return;
    }
    const double* Lp = L64 + (((size_t)(n * POS_CAP + (int)slot)) << 4);
    int a = (int)(i >> 14);
    double logit = Lp[a];
    double score = 1.0 / (1.0 + exp(-logit));
    double dx  = Lp[3 + a];
    double dy  = Lp[6 + a];
    double dwv = Lp[9 + a];
    double dhv = Lp[12 + a];
    int loc = (int)i / 3, aa = (int)i % 3;
    int hh = loc >> 7, wwi = loc & 127;
    double sx = (double)(wwi * 8), sy = (double)(hh * 8);
    double bx1 = (aa == 0) ? -91.0 : (aa == 1 ? -64.0 : -45.0);
    double by1 = (aa == 0) ? -45.0 : (aa == 1 ? -64.0 : -91.0);
    double x1 = sx + bx1, y1 = sy + by1, x2 = sx - bx1, y2 = sy - by1;
    double aw = x2 - x1, ahh = y2 - y1;
    double acx = y1 + aw * 0.5;   // (sic)
    double acy = x1 + ahh * 0.5;  // (sic)
    double px = acx + dx * aw, py = acy + dy * ahh;
    double pw = aw * exp(dwv), ph = ahh * exp(dhv);
    double c1 = px - pw * 0.5, c2 = py - ph * 0.5, c3 = px + pw * 0.5, c4 = py + ph * 0.5;
    c1 = fmin(fmax(c1, 0.0), 1024.0);
    c2 = fmin(fmax(c2, 0.0), 1024.0);
    c3 = fmin(fmax(c3, 0.0), 1024.0);
    c4 = fmin(fmax(c4, 0.0), 1024.0);
    bool valid = (score > 0.3) && (c3 - c1 > 0.0) && (c4 - c2 > 0.0);
    ckey[n * CAND_CAP + j] = valid ? ~((unsigned long long)__double_as_longlong(score)) : ~0ull;
    cpidx[n * CAND_CAP + j] = i;
    double* bp = cboxJ + (((size_t)(n * CAND_CAP + j)) << 2);
    bp[0] = c1; bp[1] = c2; bp[2] = c3; bp[3] = c4;
}

// ---------------- K6: exact top-2000 (radix over candidates + bitonic, idx tiebreak) ----------------
__global__ __launch_bounds__(256) void k_sort2000(const unsigned long long* __restrict__ ckey,
                                                  const uint32_t* __restrict__ cpidx,
                                                  const double* __restrict__ cboxJ,
                                                  unsigned long long* __restrict__ skeys,
                                                  double* __restrict__ bsort,
                                                  double* __restrict__ area)
{
    int n = blockIdx.x; int tid = threadIdx.x;
    const unsigned long long* K = ckey + (size_t)n * CAND_CAP;
    __shared__ uint32_t hist[2048];
    __shared__ uint32_t psum[256];
    __shared__ unsigned long long selk[2048];
    __shared__ uint32_t selp[2048];
    __shared__ uint32_t selj[2048];
    __shared__ unsigned long long s_prefix;
    __shared__ int s_need;
    __shared__ uint32_t s_cnt;
    if (tid == 0) { s_prefix = 0ull; s_need = PRE_NMS; s_cnt = 0u; }
    for (int L = 0; L < 4; L++) {
        int sh = 53 - 11 * L;
        for (int idx = tid; idx < 2048; idx += 256) hist[idx] = 0u;
        __syncthreads();
        unsigned long long pref = s_prefix;
        for (int i = tid; i < CAND_CAP; i += 256) {
            unsigned long long k = K[i];
            bool in = (L == 0) || ((k >> (sh + 11)) == pref);
            if (in) atomicAdd(&hist[(uint32_t)((k >> sh) & 2047ull)], 1u);
        }
        __syncthreads();
        if (tid < 256) { uint32_t s = 0; for (int q = 0; q < 8; q++) s += hist[tid * 8 + q]; psum[tid] = s; }
        __syncthreads();
        if (tid == 0) {
            int need = s_need; uint32_t cum = 0; int g = 255;
            for (int t = 0; t < 256; t++) { uint32_t c = psum[t]; if (cum + c >= (uint32_t)need) { g = t; break; } cum += c; }
            int bsel = g * 8 + 7;
            for (int t = g * 8; t < g * 8 + 8; t++) { uint32_t c = hist[t]; if (cum + c >= (uint32_t)need) { bsel = t; break; } cum += c; }
            s_need = need - (int)cum;
            s_prefix = (pref << 11) | (unsigned long long)bsel;
        }
        __syncthreads();
    }
    unsigned long long pref44 = s_prefix;
    for (int idx = tid; idx < 2048; idx += 256) { selk[idx] = ~0ull; selp[idx] = 0xFFFFFFFFu; selj[idx] = 0xFFFFFFFFu; }
    __syncthreads();
    for (int i = tid; i < CAND_CAP; i += 256) {
        unsigned long long k = K[i];
        if (k != ~0ull && (k >> 20) <= pref44) {
            uint32_t p2 = atomicAdd(&s_cnt, 1u);
            if (p2 < 2048u) { selk[p2] = k; selp[p2] = cpidx[(size_t)n * CAND_CAP + i]; selj[p2] = (uint32_t)i; }
        }
    }
    __syncthreads();
    for (unsigned k2 = 2; k2 <= 2048; k2 <<= 1) {
        for (unsigned jx = k2 >> 1; jx > 0; jx >>= 1) {
            for (int t = tid; t < 2048; t += 256) {
                unsigned ixj = (unsigned)t ^ jx;
                if (ixj > (unsigned)t) {
                    bool up = ((t & k2) == 0);
                    unsigned long long ka = selk[t], kb = selk[ixj];
                    uint32_t pa = selp[t], pb = selp[ixj];
                    uint32_t ja = selj[t], jb2 = selj[ixj];
                    bool agt = (ka > kb) || (ka == kb && pa > pb);
                    if (up ? agt : !agt) {
                        selk[t] = kb; selk[ixj] = ka;
                        selp[t] = pb; selp[ixj] = pa;
                        selj[t] = jb2; selj[ixj] = ja;
                    }
                }
            }
            __syncthreads();
        }
    }
    for (int t = tid; t < 2048; t += 256) {
        bool valid = (t < PRE_NMS) && (selk[t] != ~0ull);
        if (t < PRE_NMS) skeys[(size_t)n * PRE_NMS + t] = valid ? selk[t] : ~0ull;
        double b0 = 0, b1 = 0, b2 = 0, b3 = 0;
        if (valid) {
            const double* bp = cboxJ + (((size_t)(n * CAND_CAP + (int)selj[t])) << 2);
            b0 = bp[0]; b1 = bp[1]; b2 = bp[2]; b3 = bp[3];
        }
        double* bs = bsort + (((size_t)(n * 2048 + t)) << 2);
        bs[0] = b0; bs[1] = b1; bs[2] = b2; bs[3] = b3;
        area[(size_t)n * 2048 + t] = fmax(b2 - b0, 0.0) * fmax(b3 - b1, 0.0);
    }
}

// ---------------- K7: pairwise IoU > 0.7 bitmask ----------------
__global__ __launch_bounds__(256) void k_iou(const double* __restrict__ bsort,
                                             const double* __restrict__ area,
                                             unsigned long long* __restrict__ mat)
{
    int blk = blockIdx.x; int n = blk >> 3; int rt = blk & 7;
    int tid = threadIdx.x;
    int i = rt * 256 + tid;
    const double* bp = bsort + ((size_t)n * 2048 + i) * 4;
    double bx0 = bp[0], bx1_ = bp[1], bx2_ = bp[2], bx3 = bp[3];
    double ai = area[(size_t)n * 2048 + i];
    __shared__ double cbx[512][4];
    __shared__ double ca[512];
    for (int c = 0; c < 4; c++) {
        __syncthreads();
        for (int idx = tid; idx < 512; idx += 256) {
            const double* sp = bsort + ((size_t)n * 2048 + c * 512 + idx) * 4;
            cbx[idx][0] = sp[0]; cbx[idx][1] = sp[1]; cbx[idx][2] = sp[2]; cbx[idx][3] = sp[3];
            ca[idx] = area[(size_t)n * 2048 + c * 512 + idx];
        }
        __syncthreads();
        unsigned long long* mp = mat + ((size_t)n * 2048 + i) * 32 + c * 8;
        for (int w8 = 0; w8 < 8; w8++) {
            unsigned long long wd = 0ull;
            for (int jb = 0; jb < 64; jb++) {
                int jj = w8 * 64 + jb;
                double ix1 = fmax(bx0, cbx[jj][0]);
                double iy1 = fmax(bx1_, cbx[jj][1]);
                double ix2 = fmin(bx2_, cbx[jj][2]);
                double iy2 = fmin(bx3, cbx[jj][3]);
                double inter = fmax(ix2 - ix1, 0.0) * fmax(iy2 - iy1, 0.0);
                double den = fmax(ai + ca[jj] - inter, 1e-9);
                double iou = inter / den;
                if (iou > 0.7) wd |= (1ull << jb);
            }
            mp[w8] = wd;
        }
    }
}

// ---------------- K8: sequential NMS scan + first-300-kept emission ----------------
__global__ __launch_bounds__(64) void k_nms(const unsigned long long* __restrict__ skeys,
                                            const double* __restrict__ bsort,
                                            const unsigned long long* __restrict__ mat,
                                            float* __restrict__ out)
{
    int n = blockIdx.x; int lane = threadIdx.x;
    float* dout = out + n * (POST_NMS * 5);
    for (int t = lane; t < POST_NMS * 5; t += 64) dout[t] = 0.f;
    __shared__ unsigned long long vb[32];
    __shared__ unsigned long long kbw[32];
    for (int i0 = 0; i0 < 2048; i0 += 64) {
        int i = i0 + lane;
        unsigned long long k = (i < PRE_NMS) ? skeys[(size_t)n * PRE_NMS + i] : ~0ull;
        unsigned long long m = __ballot(k != ~0ull);
        if (lane == 0) vb[i0 >> 6] = m;
    }
    __syncthreads();
    unsigned long long sup = 0ull, keepw = 0ull;
    for (int i = 0; i < PRE_NMS; i++) {
        int wi = i >> 6, bi = i & 63;
        unsigned long long sw = __shfl(sup, wi);
        bool vi = (vb[wi] >> bi) & 1ull;
        bool kp = vi && !((sw >> bi) & 1ull);
        if (kp) {
            if (lane < 32) sup |= mat[((size_t)n * 2048 + i) * 32 + lane];
            if (lane == wi) keepw |= (1ull << bi);
        }
    }
    if (lane < 32) kbw[lane] = keepw;
    __syncthreads();
    int running = 0;
    for (int i0 = 0; i0 < 2048; i0 += 64) {
        int i = i0 + lane;
        bool kp = (i < PRE_NMS) && ((kbw[i >> 6] >> (i & 63)) & 1ull);
        unsigned long long m = __ballot(kp);
        if (kp) {
            int rk = running + __popcll(m & ((1ull << lane) - 1ull));
            if (rk < POST_NMS) {
                const double* bp = bsort + ((size_t)n * 2048 + i) * 4;
                unsigned long long k = skeys[(size_t)n * PRE_NMS + i];
                double s = __longlong_as_double((long long)~k);
                float* o = dout + rk * 5;
                o[0] = (float)bp[0]; o[1] = (float)bp[1];
                o[2] = (float)bp[2]; o[3] = (float)bp[3];
                o[4] = (float)s;
            }
        }
        running += __popcll(m);
    }
}

extern "C" void kernel_launch(void* const* d_in, const int* in_sizes, int n_in,
                              void* d_out, int out_size, void* d_ws, size_t ws_size,
                              hipStream_t stream) {
    (void)in_sizes; (void)n_in; (void)out_size; (void)ws_size;
    const float* feat   = (const float*)d_in[0];
    const float* conv_w = (const float*)d_in[1];
    const float* conv_b = (const float*)d_in[2];
    const float* det_w  = (const float*)d_in[3];
    const float* det_b  = (const float*)d_in[4];
    const float* reg_w  = (const float*)d_in[5];
    const float* reg_b  = (const float*)d_in[6];
    float* out = (float*)d_out;

    char* w = (char*)d_ws;
    double* E64 = (double*)w;                         w += (size_t)2304 * 16 * 8;               // 295 KB
    double* EB64 = (double*)w;                        w += 128;
    float* E32 = (float*)w;                           w += (size_t)2304 * 16 * 4;               // 147 KB
    float* EB32 = (float*)w;                          w += 64;
    float* PL = (float*)w;                            w += (size_t)60 * 65536 * 4;              // 15.7 MB
    float* SCORE = (float*)w;                         w += (size_t)N_IMG * NPROP * 4;
    uint32_t* KEY32 = (uint32_t*)w;                   w += (size_t)N_IMG * NPROP * 4;
    uint32_t* POSSLOT = (uint32_t*)w;                 w += (size_t)N_IMG * 16384 * 4;
    uint32_t* POSLIST = (uint32_t*)w;                 w += (size_t)N_IMG * POS_CAP * 4;
    uint32_t* PROPLIST = (uint32_t*)w;                w += (size_t)N_IMG * CAND_CAP * 4;
    uint32_t* COUNTS = (uint32_t*)w;                  w += 1024;
    double* L64 = (double*)w;                         w += (size_t)N_IMG * POS_CAP * 16 * 8;    // 1.57 MB
    unsigned long long* CKEY = (unsigned long long*)w; w += (size_t)N_IMG * CAND_CAP * 8;
    uint32_t* CPIDX = (uint32_t*)w;                   w += (size_t)N_IMG * CAND_CAP * 4;
    double* CBOXJ = (double*)w;                       w += (size_t)N_IMG * CAND_CAP * 4 * 8;
    unsigned long long* SKEY = (unsigned long long*)w; w += (size_t)N_IMG * PRE_NMS * 8;
    double* BSORT = (double*)w;                       w += (size_t)N_IMG * 2048 * 4 * 8;
    double* AREA = (double*)w;                        w += (size_t)N_IMG * 2048 * 8;
    unsigned long long* MAT = (unsigned long long*)w; w += (size_t)N_IMG * 2048 * 32 * 8;

    k_effw64<<<dim3(145), dim3(256), 0, stream>>>(conv_w, conv_b, det_w, det_b, reg_w, reg_b, E64, E32, EB64, EB32);
    k_screen<<<dim3(512), dim3(256), 0, stream>>>(feat, E32, PL);
    k_decode<<<dim3(256), dim3(256), 0, stream>>>(PL, EB32, SCORE, KEY32, POSSLOT, COUNTS);
    k_thresh<<<dim3(N_IMG), dim3(1024), 0, stream>>>(KEY32, SCORE, COUNTS, POSSLOT, POSLIST, PROPLIST);
    k_refineL<<<dim3(N_IMG * (POS_CAP / 16)), dim3(256), 0, stream>>>(feat, E64, EB64, POSLIST, COUNTS, L64);
    k_refineDecode<<<dim3(N_IMG * CAND_CAP / 256), dim3(256), 0, stream>>>(L64, PROPLIST, POSSLOT, COUNTS, CKEY, CPIDX, CBOXJ);
    k_sort2000<<<dim3(N_IMG), dim3(256), 0, stream>>>(CKEY, CPIDX, CBOXJ, SKEY, BSORT, AREA);
    k_iou<<<dim3(N_IMG * 8), dim3(256), 0, stream>>>(BSORT, AREA, MAT);
    k_nms<<<dim3(N_IMG), dim3(64), 0, stream>>>(SKEY, BSORT, MAT, out);
}

// Round 5
// 1217.426 us; speedup vs baseline: 2.9532x; 1.5020x over previous
//
#include <hip/hip_runtime.h>
#include <hip/hip_bf16.h>
#include <hip/hip_fp16.h>
#include <stdint.h>
#include <math.h>

#define N_IMG 4
#define CIN 256
#define HFD 128
#define WFD 128
#define HW (HFD*WFD)        // 16384
#define NA 3
#define NPROP (NA*HW)       // 49152
#define PRE_NMS 2000
#define POST_NMS 300
#define CAND_CAP 8192
#define POS_CAP 3072
#define MARGIN 2e-3f

__device__ __forceinline__ unsigned long long rl64(unsigned long long v, int i) {
    unsigned int lo = (unsigned int)__builtin_amdgcn_readlane((int)(unsigned int)v, i);
    unsigned int hi = (unsigned int)__builtin_amdgcn_readlane((int)(unsigned int)(v >> 32), i);
    return ((unsigned long long)hi << 32) | (unsigned long long)lo;
}

// ---------------- K0: effective weights (fp64 + fp32 copies) ----------------
__global__ __launch_bounds__(256) void k_effw64(const float* __restrict__ cw, const float* __restrict__ cb,
                                                const float* __restrict__ dw_, const float* __restrict__ db_,
                                                const float* __restrict__ rw_, const float* __restrict__ rb_,
                                                double* __restrict__ E64, float* __restrict__ E32,
                                                double* __restrict__ EB64, float* __restrict__ EB32)
{
    int out = blockIdx.x * 256 + threadIdx.x;
    if (out < 36864) {
        int k2 = out >> 4, c = out & 15;
        if (c == 15) { E64[out] = 0.0; E32[out] = 0.f; return; }
        const float* hw = (c < 3) ? (dw_ + c * 256) : (rw_ + (c - 3) * 256);
        double s = 0.0;
#pragma unroll 4
        for (int co = 0; co < 256; co++) s += (double)hw[co] * (double)cw[co * 2304 + k2];
        E64[out] = s; E32[out] = (float)s;
    } else if (out < 36864 + 16) {
        int c = out - 36864;
        double s = 0.0; double hb = 0.0;
        if (c < 15) {
            const float* hw = (c < 3) ? (dw_ + c * 256) : (rw_ + (c - 3) * 256);
            for (int co = 0; co < 256; co++) s += (double)hw[co] * (double)cb[co];
            hb = (double)((c < 3) ? db_[c] : rb_[c - 3]);
        }
        EB64[c] = s + hb; EB32[c] = (float)(s + hb);
    }
}

// ---------------- K1: direct 15-output 3x3 conv (screen), fp32, ci-chunked ----------------
__global__ __launch_bounds__(256) void k_screen(const float* __restrict__ feat,
                                                const float* __restrict__ E,
                                                float* __restrict__ PL)
{
    __shared__ float in_t[8][6][132];
    __shared__ float wl[8][9][16];
    int b = blockIdx.x;
    int chunk = b & 3; int htile = (b >> 2) & 31; int n = b >> 7;
    int h0 = htile * 4;
    int tid = threadIdx.x;
    int q = tid & 63, hl = tid >> 6;
    int w0 = q * 2;
    float acc[15][2];
#pragma unroll
    for (int c = 0; c < 15; c++) { acc[c][0] = 0.f; acc[c][1] = 0.f; }

    for (int sl = 0; sl < 8; sl++) {
        int ci0 = chunk * 64 + sl * 8;
        for (int idx = tid; idx < 8 * 780; idx += 256) {
            int ci = idx / 780; int r2 = idx % 780; int dh = r2 / 130; int dw = r2 % 130;
            int gh = h0 - 1 + dh, gw = dw - 1;
            float v = 0.f;
            if (gh >= 0 && gh < HFD && gw >= 0 && gw < WFD)
                v = feat[(((n << 8) + ci0 + ci) << 14) + (gh << 7) + gw];
            in_t[ci][dh][dw] = v;
        }
        for (int idx = tid; idx < 8 * 144; idx += 256) {
            int ci = idx / 144; int rem = idx % 144;
            wl[ci][rem / 16][rem & 15] = E[(ci0 + ci) * 144 + rem];
        }
        __syncthreads();
        for (int ci = 0; ci < 8; ci++) {
#pragma unroll
            for (int r = 0; r < 3; r++) {
                float2 g0 = *(const float2*)&in_t[ci][hl + r][w0];
                float2 g1 = *(const float2*)&in_t[ci][hl + r][w0 + 2];
                float f[4] = {g0.x, g0.y, g1.x, g1.y};
#pragma unroll
                for (int s = 0; s < 3; s++) {
                    const float4* wp = (const float4*)&wl[ci][r * 3 + s][0];
                    float w16[16];
                    *(float4*)&w16[0] = wp[0]; *(float4*)&w16[4] = wp[1];
                    *(float4*)&w16[8] = wp[2]; *(float4*)&w16[12] = wp[3];
                    float pa = f[s], pb = f[s + 1];
#pragma unroll
                    for (int c = 0; c < 15; c++) {
                        acc[c][0] = fmaf(w16[c], pa, acc[c][0]);
                        acc[c][1] = fmaf(w16[c], pb, acc[c][1]);
                    }
                }
            }
        }
        __syncthreads();
    }
    int gpos = (n << 14) + ((h0 + hl) << 7) + w0;
#pragma unroll
    for (int c = 0; c < 15; c++) {
        PL[((chunk * 15 + c) << 16) + gpos] = acc[c][0];
        PL[((chunk * 15 + c) << 16) + gpos + 1] = acc[c][1];
    }
}

// ---------------- K2: combine partials + fp32 decode -> score32/key32 ----------------
__global__ __launch_bounds__(256) void k_decode(const float* __restrict__ PL, const float* __restrict__ EB32,
                                                float* __restrict__ score32, uint32_t* __restrict__ key32,
                                                uint32_t* __restrict__ posSlot, uint32_t* __restrict__ counts)
{
    int p = blockIdx.x * 256 + threadIdx.x;
    if (p < 8) counts[p] = 0u;
    posSlot[p] = 0xFFFFFFFFu;
    int n = p >> 14, pos = p & 16383;
    float L[15];
#pragma unroll
    for (int c = 0; c < 15; c++)
        L[c] = ((PL[((c) << 16) + p] + PL[((15 + c) << 16) + p]) +
                (PL[((30 + c) << 16) + p] + PL[((45 + c) << 16) + p])) + EB32[c];
#pragma unroll
    for (int a = 0; a < 3; a++) {
        float logit = L[a];
        float score = 1.f / (1.f + expf(-logit));
        float dx  = L[3 + a];
        float dy  = L[6 + a];
        float dwv = L[9 + a];
        float dhv = L[12 + a];
        int i = a * HW + pos;
        int loc = i / 3, aa = i % 3;
        int hh = loc >> 7, wwi = loc & 127;
        float sx = (float)(wwi * 8), sy = (float)(hh * 8);
        float bx1 = (aa == 0) ? -91.f : (aa == 1 ? -64.f : -45.f);
        float by1 = (aa == 0) ? -45.f : (aa == 1 ? -64.f : -91.f);
        float x1 = sx + bx1, y1 = sy + by1, x2 = sx - bx1, y2 = sy - by1;
        float aw = x2 - x1, ahh = y2 - y1;
        float acx = y1 + aw * 0.5f;   // (sic)
        float acy = x1 + ahh * 0.5f;  // (sic)
        float px = acx + dx * aw, py = acy + dy * ahh;
        float pw = aw * expf(dwv), ph = ahh * expf(dhv);
        float c1 = px - pw * 0.5f, c2 = py - ph * 0.5f, c3 = px + pw * 0.5f, c4 = py + ph * 0.5f;
        c1 = fminf(fmaxf(c1, 0.f), 1024.f);
        c2 = fminf(fmaxf(c2, 0.f), 1024.f);
        c3 = fminf(fmaxf(c3, 0.f), 1024.f);
        c4 = fminf(fmaxf(c4, 0.f), 1024.f);
        bool valid = (score > 0.3f + 5e-4f) && (c3 - c1 > 0.1f) && (c4 - c2 > 0.1f);
        score32[(size_t)n * NPROP + i] = score;
        key32[(size_t)n * NPROP + i] = valid ? ~__float_as_uint(score) : 0xFFFFFFFFu;
    }
}

// ---------------- K3: per-image 2000th-key radix select + candidate compaction ----------------
__global__ __launch_bounds__(1024) void k_thresh(const uint32_t* __restrict__ key32,
                                                 const float* __restrict__ score32,
                                                 uint32_t* __restrict__ counts, uint32_t* __restrict__ posSlot,
                                                 uint32_t* __restrict__ PosList, uint32_t* __restrict__ PropList)
{
    int n = blockIdx.x; int tid = threadIdx.x;
    const uint32_t* K = key32 + (size_t)n * NPROP;
    __shared__ uint32_t hist[2048];
    __shared__ uint32_t psum[256];
    __shared__ uint32_t s_prefix;
    __shared__ int s_need;
    __shared__ float s_smargin;
    if (tid == 0) { s_prefix = 0u; s_need = PRE_NMS; }
    const int shifts[3] = {21, 10, 0};
    const uint32_t hmask[3] = {0u, 0xFFE00000u, 0xFFFFFC00u};
    const uint32_t bmask[3] = {2047u, 2047u, 1023u};
    for (int ps = 0; ps < 3; ps++) {
        for (int idx = tid; idx < 2048; idx += 1024) hist[idx] = 0u;
        __syncthreads();
        uint32_t pref = s_prefix;
        for (int i = tid; i < NPROP; i += 1024) {
            uint32_t k = K[i];
            if ((k & hmask[ps]) == pref) atomicAdd(&hist[(k >> shifts[ps]) & bmask[ps]], 1u);
        }
        __syncthreads();
        if (tid < 256) { uint32_t s = 0; for (int q = 0; q < 8; q++) s += hist[tid * 8 + q]; psum[tid] = s; }
        __syncthreads();
        if (tid == 0) {
            int need = s_need; uint32_t cum = 0; int g = 255;
            for (int t = 0; t < 256; t++) { uint32_t c = psum[t]; if (cum + c >= (uint32_t)need) { g = t; break; } cum += c; }
            int bsel = g * 8 + 7;
            for (int t = g * 8; t < g * 8 + 8; t++) { uint32_t c = hist[t]; if (cum + c >= (uint32_t)need) { bsel = t; break; } cum += c; }
            s_need = need - (int)cum;
            s_prefix = pref | ((uint32_t)bsel << shifts[ps]);
        }
        __syncthreads();
    }
    if (tid == 0) {
        uint32_t kth = s_prefix;
        s_smargin = (kth == 0xFFFFFFFFu) ? (0.3f - MARGIN) : (__uint_as_float(~kth) - MARGIN);
    }
    __syncthreads();
    float sm = s_smargin;
    const float* S = score32 + (size_t)n * NPROP;
    for (int i = tid; i < NPROP; i += 1024) {
        if (S[i] >= sm) {
            uint32_t j = atomicAdd(&counts[n], 1u);
            if (j < (uint32_t)CAND_CAP) PropList[n * CAND_CAP + j] = (uint32_t)i;
            int pos = i & 16383;
            if (atomicCAS(&posSlot[n * 16384 + pos], 0xFFFFFFFFu, 0xFFFFFFFEu) == 0xFFFFFFFFu) {
                uint32_t s = atomicAdd(&counts[4 + n], 1u);
                if (s < (uint32_t)POS_CAP) { posSlot[n * 16384 + pos] = s; PosList[n * POS_CAP + s] = (uint32_t)pos; }
            }
        }
    }
}

// ---------------- K4: fp64 fused logits at candidate positions ----------------
__global__ __launch_bounds__(256) void k_refineL(const float* __restrict__ feat,
                                                 const double* __restrict__ E64, const double* __restrict__ EB64,
                                                 const uint32_t* __restrict__ PosList,
                                                 const uint32_t* __restrict__ counts,
                                                 double* __restrict__ L64)
{
    int blk = blockIdx.x;
    int n = blk / (POS_CAP / 16); int t = blk % (POS_CAP / 16);
    uint32_t pc = counts[4 + n]; if (pc > (uint32_t)POS_CAP) pc = POS_CAP;
    int tid = threadIdx.x;
    int g = tid >> 4, c = tid & 15;
    int slot = t * 16 + g;
    if (slot >= (int)pc || c >= 15) return;
    uint32_t pos = PosList[n * POS_CAP + slot];
    int h = (int)(pos >> 7), w = (int)(pos & 127u);
    const float* fb = feat + ((size_t)n << 22) + (h << 7) + w;
    bool hv0 = (h - 1 >= 0), hv2 = (h + 1 < HFD);
    bool wv0 = (w - 1 >= 0), wv2 = (w + 1 < WFD);
    double acc = 0.0;
    for (int cj = 0; cj < 256; cj++) {
        const float* base = fb + ((size_t)cj << 14);
        const double* Ek = E64 + (size_t)(cj * 9) * 16 + c;
        float v0 = (hv0 && wv0) ? base[-129] : 0.f;
        float v1 = hv0 ? base[-128] : 0.f;
        float v2 = (hv0 && wv2) ? base[-127] : 0.f;
        float v3 = wv0 ? base[-1] : 0.f;
        float v4 = base[0];
        float v5 = wv2 ? base[1] : 0.f;
        float v6 = (hv2 && wv0) ? base[127] : 0.f;
        float v7 = hv2 ? base[128] : 0.f;
        float v8 = (hv2 && wv2) ? base[129] : 0.f;
        acc += Ek[0 * 16] * (double)v0;
        acc += Ek[1 * 16] * (double)v1;
        acc += Ek[2 * 16] * (double)v2;
        acc += Ek[3 * 16] * (double)v3;
        acc += Ek[4 * 16] * (double)v4;
        acc += Ek[5 * 16] * (double)v5;
        acc += Ek[6 * 16] * (double)v6;
        acc += Ek[7 * 16] * (double)v7;
        acc += Ek[8 * 16] * (double)v8;
    }
    L64[(((size_t)(n * POS_CAP + slot)) << 4) + c] = acc + EB64[c];
}

// ---------------- K5: fp64 decode for candidates ----------------
__global__ __launch_bounds__(256) void k_refineDecode(const double* __restrict__ L64,
                                                      const uint32_t* __restrict__ PropList,
                                                      const uint32_t* __restrict__ posSlot,
                                                      const uint32_t* __restrict__ counts,
                                                      unsigned long long* __restrict__ ckey,
                                                      uint32_t* __restrict__ cpidx,
                                                      double* __restrict__ cboxJ)
{
    int jj = blockIdx.x * 256 + threadIdx.x;
    int n = jj >> 13, j = jj & 8191;
    uint32_t cnt = counts[n]; if (cnt > (uint32_t)CAND_CAP) cnt = CAND_CAP;
    bool pad = (j >= (int)cnt);
    uint32_t i = 0, slot = 0;
    if (!pad) {
        i = PropList[n * CAND_CAP + j];
        slot = posSlot[n * 16384 + (i & 16383)];
        if (slot >= (uint32_t)POS_CAP) pad = true;
    }
    if (pad) {
        ckey[n * CAND_CAP + j] = ~0ull;
        cpidx[n * CAND_CAP + j] = 0xFFFFFFFFu;
        return;
    }
    const double* Lp = L64 + (((size_t)(n * POS_CAP + (int)slot)) << 4);
    int a = (int)(i >> 14);
    double logit = Lp[a];
    double score = 1.0 / (1.0 + exp(-logit));
    double dx  = Lp[3 + a];
    double dy  = Lp[6 + a];
    double dwv = Lp[9 + a];
    double dhv = Lp[12 + a];
    int loc = (int)i / 3, aa = (int)i % 3;
    int hh = loc >> 7, wwi = loc & 127;
    double sx = (double)(wwi * 8), sy = (double)(hh * 8);
    double bx1 = (aa == 0) ? -91.0 : (aa == 1 ? -64.0 : -45.0);
    double by1 = (aa == 0) ? -45.0 : (aa == 1 ? -64.0 : -91.0);
    double x1 = sx + bx1, y1 = sy + by1, x2 = sx - bx1, y2 = sy - by1;
    double aw = x2 - x1, ahh = y2 - y1;
    double acx = y1 + aw * 0.5;   // (sic)
    double acy = x1 + ahh * 0.5;  // (sic)
    double px = acx + dx * aw, py = acy + dy * ahh;
    double pw = aw * exp(dwv), ph = ahh * exp(dhv);
    double c1 = px - pw * 0.5, c2 = py - ph * 0.5, c3 = px + pw * 0.5, c4 = py + ph * 0.5;
    c1 = fmin(fmax(c1, 0.0), 1024.0);
    c2 = fmin(fmax(c2, 0.0), 1024.0);
    c3 = fmin(fmax(c3, 0.0), 1024.0);
    c4 = fmin(fmax(c4, 0.0), 1024.0);
    bool valid = (score > 0.3) && (c3 - c1 > 0.0) && (c4 - c2 > 0.0);
    ckey[n * CAND_CAP + j] = valid ? ~((unsigned long long)__double_as_longlong(score)) : ~0ull;
    cpidx[n * CAND_CAP + j] = i;
    double* bp = cboxJ + (((size_t)(n * CAND_CAP + j)) << 2);
    bp[0] = c1; bp[1] = c2; bp[2] = c3; bp[3] = c4;
}

// ---------------- K6: exact top-2000 (radix over candidates + bitonic, idx tiebreak) ----------------
__global__ __launch_bounds__(256) void k_sort2000(const unsigned long long* __restrict__ ckey,
                                                  const uint32_t* __restrict__ cpidx,
                                                  const double* __restrict__ cboxJ,
                                                  unsigned long long* __restrict__ skeys,
                                                  double* __restrict__ bsort,
                                                  double* __restrict__ area)
{
    int n = blockIdx.x; int tid = threadIdx.x;
    const unsigned long long* K = ckey + (size_t)n * CAND_CAP;
    __shared__ uint32_t hist[2048];
    __shared__ uint32_t psum[256];
    __shared__ unsigned long long selk[2048];
    __shared__ uint32_t selp[2048];
    __shared__ uint32_t selj[2048];
    __shared__ unsigned long long s_prefix;
    __shared__ int s_need;
    __shared__ uint32_t s_cnt;
    if (tid == 0) { s_prefix = 0ull; s_need = PRE_NMS; s_cnt = 0u; }
    for (int L = 0; L < 4; L++) {
        int sh = 53 - 11 * L;
        for (int idx = tid; idx < 2048; idx += 256) hist[idx] = 0u;
        __syncthreads();
        unsigned long long pref = s_prefix;
        for (int i = tid; i < CAND_CAP; i += 256) {
            unsigned long long k = K[i];
            bool in = (L == 0) || ((k >> (sh + 11)) == pref);
            if (in) atomicAdd(&hist[(uint32_t)((k >> sh) & 2047ull)], 1u);
        }
        __syncthreads();
        if (tid < 256) { uint32_t s = 0; for (int q = 0; q < 8; q++) s += hist[tid * 8 + q]; psum[tid] = s; }
        __syncthreads();
        if (tid == 0) {
            int need = s_need; uint32_t cum = 0; int g = 255;
            for (int t = 0; t < 256; t++) { uint32_t c = psum[t]; if (cum + c >= (uint32_t)need) { g = t; break; } cum += c; }
            int bsel = g * 8 + 7;
            for (int t = g * 8; t < g * 8 + 8; t++) { uint32_t c = hist[t]; if (cum + c >= (uint32_t)need) { bsel = t; break; } cum += c; }
            s_need = need - (int)cum;
            s_prefix = (pref << 11) | (unsigned long long)bsel;
        }
        __syncthreads();
    }
    unsigned long long pref44 = s_prefix;
    for (int idx = tid; idx < 2048; idx += 256) { selk[idx] = ~0ull; selp[idx] = 0xFFFFFFFFu; selj[idx] = 0xFFFFFFFFu; }
    __syncthreads();
    for (int i = tid; i < CAND_CAP; i += 256) {
        unsigned long long k = K[i];
        if (k != ~0ull && (k >> 20) <= pref44) {
            uint32_t p2 = atomicAdd(&s_cnt, 1u);
            if (p2 < 2048u) { selk[p2] = k; selp[p2] = cpidx[(size_t)n * CAND_CAP + i]; selj[p2] = (uint32_t)i; }
        }
    }
    __syncthreads();
    for (unsigned k2 = 2; k2 <= 2048; k2 <<= 1) {
        for (unsigned jx = k2 >> 1; jx > 0; jx >>= 1) {
            for (int t = tid; t < 2048; t += 256) {
                unsigned ixj = (unsigned)t ^ jx;
                if (ixj > (unsigned)t) {
                    bool up = ((t & k2) == 0);
                    unsigned long long ka = selk[t], kb = selk[ixj];
                    uint32_t pa = selp[t], pb = selp[ixj];
                    uint32_t ja = selj[t], jb2 = selj[ixj];
                    bool agt = (ka > kb) || (ka == kb && pa > pb);
                    if (up ? agt : !agt) {
                        selk[t] = kb; selk[ixj] = ka;
                        selp[t] = pb; selp[ixj] = pa;
                        selj[t] = jb2; selj[ixj] = ja;
                    }
                }
            }
            __syncthreads();
        }
    }
    for (int t = tid; t < 2048; t += 256) {
        bool valid = (t < PRE_NMS) && (selk[t] != ~0ull);
        if (t < PRE_NMS) skeys[(size_t)n * PRE_NMS + t] = valid ? selk[t] : ~0ull;
        double b0 = 0, b1 = 0, b2 = 0, b3 = 0;
        if (valid) {
            const double* bp = cboxJ + (((size_t)(n * CAND_CAP + (int)selj[t])) << 2);
            b0 = bp[0]; b1 = bp[1]; b2 = bp[2]; b3 = bp[3];
        }
        double* bs = bsort + (((size_t)(n * 2048 + t)) << 2);
        bs[0] = b0; bs[1] = b1; bs[2] = b2; bs[3] = b3;
        area[(size_t)n * 2048 + t] = fmax(b2 - b0, 0.0) * fmax(b3 - b1, 0.0);
    }
}

// ---------------- K7: pairwise IoU > 0.7 bitmask (32-row tiles, upper-triangle chunks only) ----------------
__global__ __launch_bounds__(256) void k_iou2(const double* __restrict__ bsort,
                                              const double* __restrict__ area,
                                              unsigned long long* __restrict__ mat)
{
    int blk = blockIdx.x; int n = blk >> 6; int rt = blk & 63;
    int tid = threadIdx.x;
    int r = tid >> 3, g = tid & 7;
    int i = rt * 32 + r;
    const double* bp = bsort + ((size_t)n * 2048 + i) * 4;
    double bx0 = bp[0], bx1_ = bp[1], bx2_ = bp[2], bx3 = bp[3];
    double ai = area[(size_t)n * 2048 + i];
    __shared__ double cbx[512][4];
    __shared__ double ca[512];
    for (int cc = 0; cc < 4; cc++) {
        if ((cc + 1) * 512 <= rt * 32) continue;   // strictly-lower-triangle: never read before decided
        __syncthreads();
        for (int idx = tid; idx < 512; idx += 256) {
            const double* sp = bsort + ((size_t)n * 2048 + cc * 512 + idx) * 4;
            cbx[idx][0] = sp[0]; cbx[idx][1] = sp[1]; cbx[idx][2] = sp[2]; cbx[idx][3] = sp[3];
            ca[idx] = area[(size_t)n * 2048 + cc * 512 + idx];
        }
        __syncthreads();
        unsigned long long wd = 0ull;
        for (int jb = 0; jb < 64; jb++) {
            int jr = (jb + g * 9) & 63;            // rotate per-word order: breaks 8-way bank conflict
            int jj = g * 64 + jr;
            double ix1 = fmax(bx0, cbx[jj][0]);
            double iy1 = fmax(bx1_, cbx[jj][1]);
            double ix2 = fmin(bx2_, cbx[jj][2]);
            double iy2 = fmin(bx3, cbx[jj][3]);
            double inter = fmax(ix2 - ix1, 0.0) * fmax(iy2 - iy1, 0.0);
            double den = fmax(ai + ca[jj] - inter, 1e-9);
            double iou = inter / den;
            if (iou > 0.7) wd |= (1ull << jr);
        }
        mat[((size_t)n * 2048 + i) * 32 + cc * 8 + g] = wd;
    }
}

// ---------------- K8: chunked NMS — LDS-prefetched rows + readlane scalar recurrence ----------------
__global__ __launch_bounds__(256) void k_nms2(const unsigned long long* __restrict__ skeys,
                                              const double* __restrict__ bsort,
                                              const unsigned long long* __restrict__ mat,
                                              float* __restrict__ out)
{
    int n = blockIdx.x; int tid = threadIdx.x;
    int lane = tid & 63;
    __shared__ unsigned long long rb[2][64][33];
    __shared__ unsigned long long sup_lds[32];
    __shared__ unsigned long long vb[32];
    __shared__ unsigned long long kbw[32];
    float* dout = out + n * (POST_NMS * 5);
    for (int t = tid; t < POST_NMS * 5; t += 256) dout[t] = 0.f;
    if (tid < 32) sup_lds[tid] = 0ull;
    if (tid < 64) {
        for (int i0 = 0; i0 < 2048; i0 += 64) {
            int i = i0 + lane;
            unsigned long long k = (i < PRE_NMS) ? skeys[(size_t)n * PRE_NMS + i] : ~0ull;
            unsigned long long m = __ballot(k != ~0ull);
            if (lane == 0) vb[i0 >> 6] = m;
        }
    }
    int r = tid >> 2, w0 = (tid & 3) * 8;
    {   // prefetch chunk 0
        const unsigned long long* src = mat + ((size_t)n * 2048 + r) * 32 + w0;
        ulonglong2 a = *(const ulonglong2*)(src);
        ulonglong2 b = *(const ulonglong2*)(src + 2);
        ulonglong2 c2 = *(const ulonglong2*)(src + 4);
        ulonglong2 d = *(const ulonglong2*)(src + 6);
        unsigned long long* dst = &rb[0][r][w0];
        dst[0] = a.x; dst[1] = a.y; dst[2] = b.x; dst[3] = b.y;
        dst[4] = c2.x; dst[5] = c2.y; dst[6] = d.x; dst[7] = d.y;
    }
    __syncthreads();
    for (int c = 0; c < 32; c++) {
        int cur = c & 1, nxt = cur ^ 1;
        ulonglong2 pa, pb, pc, pd;
        bool pf = (c + 1 < 32);
        if (pf) {   // issue next-chunk loads (land after wave-0's serial work)
            const unsigned long long* src = mat + ((size_t)n * 2048 + (c + 1) * 64 + r) * 32 + w0;
            pa = *(const ulonglong2*)(src);
            pb = *(const ulonglong2*)(src + 2);
            pc = *(const ulonglong2*)(src + 4);
            pd = *(const ulonglong2*)(src + 6);
        }
        if (tid < 64) {
            unsigned long long M = rb[cur][lane][c];   // diagonal word of row `lane`
            unsigned long long supw = sup_lds[c];
            unsigned long long vbw = vb[c];
            unsigned long long km = 0ull;
#pragma unroll
            for (int ii = 0; ii < 64; ii++) {
                unsigned long long bit = 1ull << ii;
                if ((vbw & bit) && !(supw & bit)) {
                    km |= bit;
                    supw |= rl64(M, ii);
                }
            }
            if (lane == 0) kbw[c] = km;
            if (lane < 32) {
                unsigned long long acc = 0ull;
                unsigned long long tm = km;
                while (tm) {
                    int ii = __ffsll((long long)tm) - 1;
                    tm &= tm - 1;
                    acc |= rb[cur][ii][lane];
                }
                sup_lds[lane] |= acc;
            }
        }
        if (pf) {
            unsigned long long* dst = &rb[nxt][r][w0];
            dst[0] = pa.x; dst[1] = pa.y; dst[2] = pb.x; dst[3] = pb.y;
            dst[4] = pc.x; dst[5] = pc.y; dst[6] = pd.x; dst[7] = pd.y;
        }
        __syncthreads();
    }
    if (tid < 64) {
        int running = 0;
        for (int i0 = 0; i0 < 2048; i0 += 64) {
            int i = i0 + lane;
            bool kp = (i < PRE_NMS) && ((kbw[i >> 6] >> (i & 63)) & 1ull);
            unsigned long long m = __ballot(kp);
            if (kp) {
                int rk = running + __popcll(m & ((1ull << lane) - 1ull));
                if (rk < POST_NMS) {
                    const double* bp2 = bsort + ((size_t)n * 2048 + i) * 4;
                    unsigned long long k = skeys[(size_t)n * PRE_NMS + i];
                    double s = __longlong_as_double((long long)~k);
                    float* o = dout + rk * 5;
                    o[0] = (float)bp2[0]; o[1] = (float)bp2[1];
                    o[2] = (float)bp2[2]; o[3] = (float)bp2[3];
                    o[4] = (float)s;
                }
            }
            running += __popcll(m);
        }
    }
}

extern "C" void kernel_launch(void* const* d_in, const int* in_sizes, int n_in,
                              void* d_out, int out_size, void* d_ws, size_t ws_size,
                              hipStream_t stream) {
    (void)in_sizes; (void)n_in; (void)out_size; (void)ws_size;
    const float* feat   = (const float*)d_in[0];
    const float* conv_w = (const float*)d_in[1];
    const float* conv_b = (const float*)d_in[2];
    const float* det_w  = (const float*)d_in[3];
    const float* det_b  = (const float*)d_in[4];
    const float* reg_w  = (const float*)d_in[5];
    const float* reg_b  = (const float*)d_in[6];
    float* out = (float*)d_out;

    char* w = (char*)d_ws;
    double* E64 = (double*)w;                         w += (size_t)2304 * 16 * 8;
    double* EB64 = (double*)w;                        w += 128;
    float* E32 = (float*)w;                           w += (size_t)2304 * 16 * 4;
    float* EB32 = (float*)w;                          w += 64;
    float* PL = (float*)w;                            w += (size_t)60 * 65536 * 4;
    float* SCORE = (float*)w;                         w += (size_t)N_IMG * NPROP * 4;
    uint32_t* KEY32 = (uint32_t*)w;                   w += (size_t)N_IMG * NPROP * 4;
    uint32_t* POSSLOT = (uint32_t*)w;                 w += (size_t)N_IMG * 16384 * 4;
    uint32_t* POSLIST = (uint32_t*)w;                 w += (size_t)N_IMG * POS_CAP * 4;
    uint32_t* PROPLIST = (uint32_t*)w;                w += (size_t)N_IMG * CAND_CAP * 4;
    uint32_t* COUNTS = (uint32_t*)w;                  w += 1024;
    double* L64 = (double*)w;                         w += (size_t)N_IMG * POS_CAP * 16 * 8;
    unsigned long long* CKEY = (unsigned long long*)w; w += (size_t)N_IMG * CAND_CAP * 8;
    uint32_t* CPIDX = (uint32_t*)w;                   w += (size_t)N_IMG * CAND_CAP * 4;
    double* CBOXJ = (double*)w;                       w += (size_t)N_IMG * CAND_CAP * 4 * 8;
    unsigned long long* SKEY = (unsigned long long*)w; w += (size_t)N_IMG * PRE_NMS * 8;
    double* BSORT = (double*)w;                       w += (size_t)N_IMG * 2048 * 4 * 8;
    double* AREA = (double*)w;                        w += (size_t)N_IMG * 2048 * 8;
    unsigned long long* MAT = (unsigned long long*)w; w += (size_t)N_IMG * 2048 * 32 * 8;

    k_effw64<<<dim3(145), dim3(256), 0, stream>>>(conv_w, conv_b, det_w, det_b, reg_w, reg_b, E64, E32, EB64, EB32);
    k_screen<<<dim3(512), dim3(256), 0, stream>>>(feat, E32, PL);
    k_decode<<<dim3(256), dim3(256), 0, stream>>>(PL, EB32, SCORE, KEY32, POSSLOT, COUNTS);
    k_thresh<<<dim3(N_IMG), dim3(1024), 0, stream>>>(KEY32, SCORE, COUNTS, POSSLOT, POSLIST, PROPLIST);
    k_refineL<<<dim3(N_IMG * (POS_CAP / 16)), dim3(256), 0, stream>>>(feat, E64, EB64, POSLIST, COUNTS, L64);
    k_refineDecode<<<dim3(N_IMG * CAND_CAP / 256), dim3(256), 0, stream>>>(L64, PROPLIST, POSSLOT, COUNTS, CKEY, CPIDX, CBOXJ);
    k_sort2000<<<dim3(N_IMG), dim3(256), 0, stream>>>(CKEY, CPIDX, CBOXJ, SKEY, BSORT, AREA);
    k_iou2<<<dim3(N_IMG * 64), dim3(256), 0, stream>>>(BSORT, AREA, MAT);
    k_nms2<<<dim3(N_IMG), dim3(256), 0, stream>>>(SKEY, BSORT, MAT, out);
}

// Round 6
// 954.911 us; speedup vs baseline: 3.7650x; 1.2749x over previous
//
#include <hip/hip_runtime.h>
#include <hip/hip_bf16.h>
#include <hip/hip_fp16.h>
#include <stdint.h>
#include <math.h>

#define N_IMG 4
#define CIN 256
#define HFD 128
#define WFD 128
#define HW (HFD*WFD)        // 16384
#define NA 3
#define NPROP (NA*HW)       // 49152
#define PRE_NMS 2000
#define POST_NMS 300
#define CAND_CAP 8192
#define POS_CAP 3072
#define MARGIN 2e-3f

__device__ __forceinline__ unsigned long long rl64(unsigned long long v, int i) {
    unsigned int lo = (unsigned int)__builtin_amdgcn_readlane((int)(unsigned int)v, i);
    unsigned int hi = (unsigned int)__builtin_amdgcn_readlane((int)(unsigned int)(v >> 32), i);
    return ((unsigned long long)hi << 32) | (unsigned long long)lo;
}

// ---------------- K0: effective weights (fp64 + fp32 copies) ----------------
__global__ __launch_bounds__(256) void k_effw64(const float* __restrict__ cw, const float* __restrict__ cb,
                                                const float* __restrict__ dw_, const float* __restrict__ db_,
                                                const float* __restrict__ rw_, const float* __restrict__ rb_,
                                                double* __restrict__ E64, float* __restrict__ E32,
                                                double* __restrict__ EB64, float* __restrict__ EB32)
{
    int out = blockIdx.x * 256 + threadIdx.x;
    if (out < 36864) {
        int k2 = out >> 4, c = out & 15;
        if (c == 15) { E64[out] = 0.0; E32[out] = 0.f; return; }
        const float* hw = (c < 3) ? (dw_ + c * 256) : (rw_ + (c - 3) * 256);
        double s = 0.0;
#pragma unroll 4
        for (int co = 0; co < 256; co++) s += (double)hw[co] * (double)cw[co * 2304 + k2];
        E64[out] = s; E32[out] = (float)s;
    } else if (out < 36864 + 16) {
        int c = out - 36864;
        double s = 0.0; double hb = 0.0;
        if (c < 15) {
            const float* hw = (c < 3) ? (dw_ + c * 256) : (rw_ + (c - 3) * 256);
            for (int co = 0; co < 256; co++) s += (double)hw[co] * (double)cb[co];
            hb = (double)((c < 3) ? db_[c] : rb_[c - 3]);
        }
        EB64[c] = s + hb; EB32[c] = (float)(s + hb);
    }
}

// ---------------- K1: direct 15-output 3x3 conv (screen), fp32, ci-chunked ----------------
__global__ __launch_bounds__(256) void k_screen(const float* __restrict__ feat,
                                                const float* __restrict__ E,
                                                float* __restrict__ PL)
{
    __shared__ float in_t[8][6][132];
    __shared__ float wl[8][9][16];
    int b = blockIdx.x;
    int chunk = b & 3; int htile = (b >> 2) & 31; int n = b >> 7;
    int h0 = htile * 4;
    int tid = threadIdx.x;
    int q = tid & 63, hl = tid >> 6;
    int w0 = q * 2;
    float acc[15][2];
#pragma unroll
    for (int c = 0; c < 15; c++) { acc[c][0] = 0.f; acc[c][1] = 0.f; }

    for (int sl = 0; sl < 8; sl++) {
        int ci0 = chunk * 64 + sl * 8;
        for (int idx = tid; idx < 8 * 780; idx += 256) {
            int ci = idx / 780; int r2 = idx % 780; int dh = r2 / 130; int dw = r2 % 130;
            int gh = h0 - 1 + dh, gw = dw - 1;
            float v = 0.f;
            if (gh >= 0 && gh < HFD && gw >= 0 && gw < WFD)
                v = feat[(((n << 8) + ci0 + ci) << 14) + (gh << 7) + gw];
            in_t[ci][dh][dw] = v;
        }
        for (int idx = tid; idx < 8 * 144; idx += 256) {
            int ci = idx / 144; int rem = idx % 144;
            wl[ci][rem / 16][rem & 15] = E[(ci0 + ci) * 144 + rem];
        }
        __syncthreads();
        for (int ci = 0; ci < 8; ci++) {
#pragma unroll
            for (int r = 0; r < 3; r++) {
                float2 g0 = *(const float2*)&in_t[ci][hl + r][w0];
                float2 g1 = *(const float2*)&in_t[ci][hl + r][w0 + 2];
                float f[4] = {g0.x, g0.y, g1.x, g1.y};
#pragma unroll
                for (int s = 0; s < 3; s++) {
                    const float4* wp = (const float4*)&wl[ci][r * 3 + s][0];
                    float w16[16];
                    *(float4*)&w16[0] = wp[0]; *(float4*)&w16[4] = wp[1];
                    *(float4*)&w16[8] = wp[2]; *(float4*)&w16[12] = wp[3];
                    float pa = f[s], pb = f[s + 1];
#pragma unroll
                    for (int c = 0; c < 15; c++) {
                        acc[c][0] = fmaf(w16[c], pa, acc[c][0]);
                        acc[c][1] = fmaf(w16[c], pb, acc[c][1]);
                    }
                }
            }
        }
        __syncthreads();
    }
    int gpos = (n << 14) + ((h0 + hl) << 7) + w0;
#pragma unroll
    for (int c = 0; c < 15; c++) {
        PL[((chunk * 15 + c) << 16) + gpos] = acc[c][0];
        PL[((chunk * 15 + c) << 16) + gpos + 1] = acc[c][1];
    }
}

// ---------------- K2: combine partials + fp32 decode -> score32/key32 ----------------
__global__ __launch_bounds__(256) void k_decode(const float* __restrict__ PL, const float* __restrict__ EB32,
                                                float* __restrict__ score32, uint32_t* __restrict__ key32,
                                                uint32_t* __restrict__ posSlot, uint32_t* __restrict__ counts)
{
    int p = blockIdx.x * 256 + threadIdx.x;
    if (p < 8) counts[p] = 0u;
    posSlot[p] = 0xFFFFFFFFu;
    int n = p >> 14, pos = p & 16383;
    float L[15];
#pragma unroll
    for (int c = 0; c < 15; c++)
        L[c] = ((PL[((c) << 16) + p] + PL[((15 + c) << 16) + p]) +
                (PL[((30 + c) << 16) + p] + PL[((45 + c) << 16) + p])) + EB32[c];
#pragma unroll
    for (int a = 0; a < 3; a++) {
        float logit = L[a];
        float score = 1.f / (1.f + expf(-logit));
        float dx  = L[3 + a];
        float dy  = L[6 + a];
        float dwv = L[9 + a];
        float dhv = L[12 + a];
        int i = a * HW + pos;
        int loc = i / 3, aa = i % 3;
        int hh = loc >> 7, wwi = loc & 127;
        float sx = (float)(wwi * 8), sy = (float)(hh * 8);
        float bx1 = (aa == 0) ? -91.f : (aa == 1 ? -64.f : -45.f);
        float by1 = (aa == 0) ? -45.f : (aa == 1 ? -64.f : -91.f);
        float x1 = sx + bx1, y1 = sy + by1, x2 = sx - bx1, y2 = sy - by1;
        float aw = x2 - x1, ahh = y2 - y1;
        float acx = y1 + aw * 0.5f;   // (sic)
        float acy = x1 + ahh * 0.5f;  // (sic)
        float px = acx + dx * aw, py = acy + dy * ahh;
        float pw = aw * expf(dwv), ph = ahh * expf(dhv);
        float c1 = px - pw * 0.5f, c2 = py - ph * 0.5f, c3 = px + pw * 0.5f, c4 = py + ph * 0.5f;
        c1 = fminf(fmaxf(c1, 0.f), 1024.f);
        c2 = fminf(fmaxf(c2, 0.f), 1024.f);
        c3 = fminf(fmaxf(c3, 0.f), 1024.f);
        c4 = fminf(fmaxf(c4, 0.f), 1024.f);
        bool valid = (score > 0.3f + 5e-4f) && (c3 - c1 > 0.1f) && (c4 - c2 > 0.1f);
        score32[(size_t)n * NPROP + i] = score;
        key32[(size_t)n * NPROP + i] = valid ? ~__float_as_uint(score) : 0xFFFFFFFFu;
    }
}

// ---------------- K3: per-image 2000th-key radix select + candidate compaction ----------------
__global__ __launch_bounds__(1024) void k_thresh(const uint32_t* __restrict__ key32,
                                                 const float* __restrict__ score32,
                                                 uint32_t* __restrict__ counts, uint32_t* __restrict__ posSlot,
                                                 uint32_t* __restrict__ PosList, uint32_t* __restrict__ PropList)
{
    int n = blockIdx.x; int tid = threadIdx.x;
    const uint32_t* K = key32 + (size_t)n * NPROP;
    __shared__ uint32_t hist[2048];
    __shared__ uint32_t psum[256];
    __shared__ uint32_t s_prefix;
    __shared__ int s_need;
    __shared__ float s_smargin;
    if (tid == 0) { s_prefix = 0u; s_need = PRE_NMS; }
    const int shifts[3] = {21, 10, 0};
    const uint32_t hmask[3] = {0u, 0xFFE00000u, 0xFFFFFC00u};
    const uint32_t bmask[3] = {2047u, 2047u, 1023u};
    for (int ps = 0; ps < 3; ps++) {
        for (int idx = tid; idx < 2048; idx += 1024) hist[idx] = 0u;
        __syncthreads();
        uint32_t pref = s_prefix;
        for (int i = tid; i < NPROP; i += 1024) {
            uint32_t k = K[i];
            if ((k & hmask[ps]) == pref) atomicAdd(&hist[(k >> shifts[ps]) & bmask[ps]], 1u);
        }
        __syncthreads();
        if (tid < 256) { uint32_t s = 0; for (int q = 0; q < 8; q++) s += hist[tid * 8 + q]; psum[tid] = s; }
        __syncthreads();
        if (tid == 0) {
            int need = s_need; uint32_t cum = 0; int g = 255;
            for (int t = 0; t < 256; t++) { uint32_t c = psum[t]; if (cum + c >= (uint32_t)need) { g = t; break; } cum += c; }
            int bsel = g * 8 + 7;
            for (int t = g * 8; t < g * 8 + 8; t++) { uint32_t c = hist[t]; if (cum + c >= (uint32_t)need) { bsel = t; break; } cum += c; }
            s_need = need - (int)cum;
            s_prefix = pref | ((uint32_t)bsel << shifts[ps]);
        }
        __syncthreads();
    }
    if (tid == 0) {
        uint32_t kth = s_prefix;
        s_smargin = (kth == 0xFFFFFFFFu) ? (0.3f - MARGIN) : (__uint_as_float(~kth) - MARGIN);
    }
    __syncthreads();
    float sm = s_smargin;
    const float* S = score32 + (size_t)n * NPROP;
    for (int i = tid; i < NPROP; i += 1024) {
        if (S[i] >= sm) {
            uint32_t j = atomicAdd(&counts[n], 1u);
            if (j < (uint32_t)CAND_CAP) PropList[n * CAND_CAP + j] = (uint32_t)i;
            int pos = i & 16383;
            if (atomicCAS(&posSlot[n * 16384 + pos], 0xFFFFFFFFu, 0xFFFFFFFEu) == 0xFFFFFFFFu) {
                uint32_t s = atomicAdd(&counts[4 + n], 1u);
                if (s < (uint32_t)POS_CAP) { posSlot[n * 16384 + pos] = s; PosList[n * POS_CAP + s] = (uint32_t)pos; }
            }
        }
    }
}

// ---------------- K4: fp64 fused logits, 4-way channel split + 4-channel ILP batches ----------------
// grid = N * (POS_CAP/16) * 4 quarters; block 256 = 16 positions x 16 lanes (lane = logit)
__global__ __launch_bounds__(256) void k_refineL4(const float* __restrict__ feat,
                                                  const double* __restrict__ E64,
                                                  const uint32_t* __restrict__ PosList,
                                                  const uint32_t* __restrict__ counts,
                                                  double* __restrict__ PART)
{
    int blk = blockIdx.x;
    int q = blk & 3;
    int t = (blk >> 2) % (POS_CAP / 16);
    int n = (blk >> 2) / (POS_CAP / 16);
    uint32_t pc = counts[4 + n]; if (pc > (uint32_t)POS_CAP) pc = POS_CAP;
    int tid = threadIdx.x;
    int g = tid >> 4, c = tid & 15;
    int slot = t * 16 + g;
    if (slot >= (int)pc || c >= 15) return;
    uint32_t pos = PosList[n * POS_CAP + slot];
    int h = (int)(pos >> 7), w = (int)(pos & 127u);
    const float* fb = feat + ((size_t)n << 22) + (h << 7) + w;
    bool hv0 = (h - 1 >= 0), hv2 = (h + 1 < HFD);
    bool wv0 = (w - 1 >= 0), wv2 = (w + 1 < WFD);
    double a0 = 0.0, a1 = 0.0, a2 = 0.0, a3 = 0.0;
    int cjb = q * 64;
    for (int u = 0; u < 64; u += 4) {
        float v[4][9];
#pragma unroll
        for (int x = 0; x < 4; x++) {
            const float* base = fb + ((size_t)(cjb + u + x) << 14);
            v[x][0] = (hv0 && wv0) ? base[-129] : 0.f;
            v[x][1] = hv0 ? base[-128] : 0.f;
            v[x][2] = (hv0 && wv2) ? base[-127] : 0.f;
            v[x][3] = wv0 ? base[-1] : 0.f;
            v[x][4] = base[0];
            v[x][5] = wv2 ? base[1] : 0.f;
            v[x][6] = (hv2 && wv0) ? base[127] : 0.f;
            v[x][7] = hv2 ? base[128] : 0.f;
            v[x][8] = (hv2 && wv2) ? base[129] : 0.f;
        }
        const double* Ek0 = E64 + (size_t)((cjb + u) * 9) * 16 + c;
#pragma unroll
        for (int tap = 0; tap < 9; tap++) {
            a0 += Ek0[(0 * 9 + tap) * 16] * (double)v[0][tap];
            a1 += Ek0[(1 * 9 + tap) * 16] * (double)v[1][tap];
            a2 += Ek0[(2 * 9 + tap) * 16] * (double)v[2][tap];
            a3 += Ek0[(3 * 9 + tap) * 16] * (double)v[3][tap];
        }
    }
    PART[((((size_t)(n * POS_CAP + slot)) << 2) + q) * 16 + c] = (a0 + a1) + (a2 + a3);
}

// ---------------- K4b: combine 4 channel-quarter partials + bias ----------------
__global__ __launch_bounds__(256) void k_combineL(const double* __restrict__ PART,
                                                  const double* __restrict__ EB64,
                                                  double* __restrict__ L64)
{
    int idx = blockIdx.x * 256 + threadIdx.x;  // N*POS_CAP*16
    int c = idx & 15;
    size_t sl = (size_t)(idx >> 4);
    const double* p = PART + (sl << 6) + c;
    L64[idx] = ((p[0] + p[16]) + (p[32] + p[48])) + EB64[c];
}

// ---------------- K5: fp64 decode for candidates ----------------
__global__ __launch_bounds__(256) void k_refineDecode(const double* __restrict__ L64,
                                                      const uint32_t* __restrict__ PropList,
                                                      const uint32_t* __restrict__ posSlot,
                                                      const uint32_t* __restrict__ counts,
                                                      unsigned long long* __restrict__ ckey,
                                                      uint32_t* __restrict__ cpidx,
                                                      double* __restrict__ cboxJ)
{
    int jj = blockIdx.x * 256 + threadIdx.x;
    int n = jj >> 13, j = jj & 8191;
    uint32_t cnt = counts[n]; if (cnt > (uint32_t)CAND_CAP) cnt = CAND_CAP;
    bool pad = (j >= (int)cnt);
    uint32_t i = 0, slot = 0;
    if (!pad) {
        i = PropList[n * CAND_CAP + j];
        slot = posSlot[n * 16384 + (i & 16383)];
        if (slot >= (uint32_t)POS_CAP) pad = true;
    }
    if (pad) {
        ckey[n * CAND_CAP + j] = ~0ull;
        cpidx[n * CAND_CAP + j] = 0xFFFFFFFFu;
        return;
    }
    const double* Lp = L64 + (((size_t)(n * POS_CAP + (int)slot)) << 4);
    int a = (int)(i >> 14);
    double logit = Lp[a];
    double score = 1.0 / (1.0 + exp(-logit));
    double dx  = Lp[3 + a];
    double dy  = Lp[6 + a];
    double dwv = Lp[9 + a];
    double dhv = Lp[12 + a];
    int loc = (int)i / 3, aa = (int)i % 3;
    int hh = loc >> 7, wwi = loc & 127;
    double sx = (double)(wwi * 8), sy = (double)(hh * 8);
    double bx1 = (aa == 0) ? -91.0 : (aa == 1 ? -64.0 : -45.0);
    double by1 = (aa == 0) ? -45.0 : (aa == 1 ? -64.0 : -91.0);
    double x1 = sx + bx1, y1 = sy + by1, x2 = sx - bx1, y2 = sy - by1;
    double aw = x2 - x1, ahh = y2 - y1;
    double acx = y1 + aw * 0.5;   // (sic)
    double acy = x1 + ahh * 0.5;  // (sic)
    double px = acx + dx * aw, py = acy + dy * ahh;
    double pw = aw * exp(dwv), ph = ahh * exp(dhv);
    double c1 = px - pw * 0.5, c2 = py - ph * 0.5, c3 = px + pw * 0.5, c4 = py + ph * 0.5;
    c1 = fmin(fmax(c1, 0.0), 1024.0);
    c2 = fmin(fmax(c2, 0.0), 1024.0);
    c3 = fmin(fmax(c3, 0.0), 1024.0);
    c4 = fmin(fmax(c4, 0.0), 1024.0);
    bool valid = (score > 0.3) && (c3 - c1 > 0.0) && (c4 - c2 > 0.0);
    ckey[n * CAND_CAP + j] = valid ? ~((unsigned long long)__double_as_longlong(score)) : ~0ull;
    cpidx[n * CAND_CAP + j] = i;
    double* bp = cboxJ + (((size_t)(n * CAND_CAP + j)) << 2);
    bp[0] = c1; bp[1] = c2; bp[2] = c3; bp[3] = c4;
}

// ---------------- K6: exact top-2000 (radix over candidates + bitonic, idx tiebreak) ----------------
__global__ __launch_bounds__(256) void k_sort2000(const unsigned long long* __restrict__ ckey,
                                                  const uint32_t* __restrict__ cpidx,
                                                  const double* __restrict__ cboxJ,
                                                  unsigned long long* __restrict__ skeys,
                                                  double* __restrict__ bsort,
                                                  double* __restrict__ area)
{
    int n = blockIdx.x; int tid = threadIdx.x;
    const unsigned long long* K = ckey + (size_t)n * CAND_CAP;
    __shared__ uint32_t hist[2048];
    __shared__ uint32_t psum[256];
    __shared__ unsigned long long selk[2048];
    __shared__ uint32_t selp[2048];
    __shared__ uint32_t selj[2048];
    __shared__ unsigned long long s_prefix;
    __shared__ int s_need;
    __shared__ uint32_t s_cnt;
    if (tid == 0) { s_prefix = 0ull; s_need = PRE_NMS; s_cnt = 0u; }
    for (int L = 0; L < 4; L++) {
        int sh = 53 - 11 * L;
        for (int idx = tid; idx < 2048; idx += 256) hist[idx] = 0u;
        __syncthreads();
        unsigned long long pref = s_prefix;
        for (int i = tid; i < CAND_CAP; i += 256) {
            unsigned long long k = K[i];
            bool in = (L == 0) || ((k >> (sh + 11)) == pref);
            if (in) atomicAdd(&hist[(uint32_t)((k >> sh) & 2047ull)], 1u);
        }
        __syncthreads();
        if (tid < 256) { uint32_t s = 0; for (int q = 0; q < 8; q++) s += hist[tid * 8 + q]; psum[tid] = s; }
        __syncthreads();
        if (tid == 0) {
            int need = s_need; uint32_t cum = 0; int g = 255;
            for (int t = 0; t < 256; t++) { uint32_t c = psum[t]; if (cum + c >= (uint32_t)need) { g = t; break; } cum += c; }
            int bsel = g * 8 + 7;
            for (int t = g * 8; t < g * 8 + 8; t++) { uint32_t c = hist[t]; if (cum + c >= (uint32_t)need) { bsel = t; break; } cum += c; }
            s_need = need - (int)cum;
            s_prefix = (pref << 11) | (unsigned long long)bsel;
        }
        __syncthreads();
    }
    unsigned long long pref44 = s_prefix;
    for (int idx = tid; idx < 2048; idx += 256) { selk[idx] = ~0ull; selp[idx] = 0xFFFFFFFFu; selj[idx] = 0xFFFFFFFFu; }
    __syncthreads();
    for (int i = tid; i < CAND_CAP; i += 256) {
        unsigned long long k = K[i];
        if (k != ~0ull && (k >> 20) <= pref44) {
            uint32_t p2 = atomicAdd(&s_cnt, 1u);
            if (p2 < 2048u) { selk[p2] = k; selp[p2] = cpidx[(size_t)n * CAND_CAP + i]; selj[p2] = (uint32_t)i; }
        }
    }
    __syncthreads();
    for (unsigned k2 = 2; k2 <= 2048; k2 <<= 1) {
        for (unsigned jx = k2 >> 1; jx > 0; jx >>= 1) {
            for (int t = tid; t < 2048; t += 256) {
                unsigned ixj = (unsigned)t ^ jx;
                if (ixj > (unsigned)t) {
                    bool up = ((t & k2) == 0);
                    unsigned long long ka = selk[t], kb = selk[ixj];
                    uint32_t pa = selp[t], pb = selp[ixj];
                    uint32_t ja = selj[t], jb2 = selj[ixj];
                    bool agt = (ka > kb) || (ka == kb && pa > pb);
                    if (up ? agt : !agt) {
                        selk[t] = kb; selk[ixj] = ka;
                        selp[t] = pb; selp[ixj] = pa;
                        selj[t] = jb2; selj[ixj] = ja;
                    }
                }
            }
            __syncthreads();
        }
    }
    for (int t = tid; t < 2048; t += 256) {
        bool valid = (t < PRE_NMS) && (selk[t] != ~0ull);
        if (t < PRE_NMS) skeys[(size_t)n * PRE_NMS + t] = valid ? selk[t] : ~0ull;
        double b0 = 0, b1 = 0, b2 = 0, b3 = 0;
        if (valid) {
            const double* bp = cboxJ + (((size_t)(n * CAND_CAP + (int)selj[t])) << 2);
            b0 = bp[0]; b1 = bp[1]; b2 = bp[2]; b3 = bp[3];
        }
        double* bs = bsort + (((size_t)(n * 2048 + t)) << 2);
        bs[0] = b0; bs[1] = b1; bs[2] = b2; bs[3] = b3;
        area[(size_t)n * 2048 + t] = fmax(b2 - b0, 0.0) * fmax(b3 - b1, 0.0);
    }
}

// ---------------- K7: pairwise IoU > 0.7 bitmask (32-row tiles, upper-triangle chunks only) ----------------
__global__ __launch_bounds__(256) void k_iou2(const double* __restrict__ bsort,
                                              const double* __restrict__ area,
                                              unsigned long long* __restrict__ mat)
{
    int blk = blockIdx.x; int n = blk >> 6; int rt = blk & 63;
    int tid = threadIdx.x;
    int r = tid >> 3, g = tid & 7;
    int i = rt * 32 + r;
    const double* bp = bsort + ((size_t)n * 2048 + i) * 4;
    double bx0 = bp[0], bx1_ = bp[1], bx2_ = bp[2], bx3 = bp[3];
    double ai = area[(size_t)n * 2048 + i];
    __shared__ double cbx[512][4];
    __shared__ double ca[512];
    for (int cc = 0; cc < 4; cc++) {
        if ((cc + 1) * 512 <= rt * 32) continue;
        __syncthreads();
        for (int idx = tid; idx < 512; idx += 256) {
            const double* sp = bsort + ((size_t)n * 2048 + cc * 512 + idx) * 4;
            cbx[idx][0] = sp[0]; cbx[idx][1] = sp[1]; cbx[idx][2] = sp[2]; cbx[idx][3] = sp[3];
            ca[idx] = area[(size_t)n * 2048 + cc * 512 + idx];
        }
        __syncthreads();
        unsigned long long wd = 0ull;
        for (int jb = 0; jb < 64; jb++) {
            int jr = (jb + g * 9) & 63;
            int jj = g * 64 + jr;
            double ix1 = fmax(bx0, cbx[jj][0]);
            double iy1 = fmax(bx1_, cbx[jj][1]);
            double ix2 = fmin(bx2_, cbx[jj][2]);
            double iy2 = fmin(bx3, cbx[jj][3]);
            double inter = fmax(ix2 - ix1, 0.0) * fmax(iy2 - iy1, 0.0);
            double den = fmax(ai + ca[jj] - inter, 1e-9);
            double iou = inter / den;
            if (iou > 0.7) wd |= (1ull << jr);
        }
        mat[((size_t)n * 2048 + i) * 32 + cc * 8 + g] = wd;
    }
}

// ---------------- K8: chunked NMS — LDS-prefetched rows + readlane scalar recurrence ----------------
__global__ __launch_bounds__(256) void k_nms2(const unsigned long long* __restrict__ skeys,
                                              const double* __restrict__ bsort,
                                              const unsigned long long* __restrict__ mat,
                                              float* __restrict__ out)
{
    int n = blockIdx.x; int tid = threadIdx.x;
    int lane = tid & 63;
    __shared__ unsigned long long rb[2][64][33];
    __shared__ unsigned long long sup_lds[32];
    __shared__ unsigned long long vb[32];
    __shared__ unsigned long long kbw[32];
    float* dout = out + n * (POST_NMS * 5);
    for (int t = tid; t < POST_NMS * 5; t += 256) dout[t] = 0.f;
    if (tid < 32) sup_lds[tid] = 0ull;
    if (tid < 64) {
        for (int i0 = 0; i0 < 2048; i0 += 64) {
            int i = i0 + lane;
            unsigned long long k = (i < PRE_NMS) ? skeys[(size_t)n * PRE_NMS + i] : ~0ull;
            unsigned long long m = __ballot(k != ~0ull);
            if (lane == 0) vb[i0 >> 6] = m;
        }
    }
    int r = tid >> 2, w0 = (tid & 3) * 8;
    {
        const unsigned long long* src = mat + ((size_t)n * 2048 + r) * 32 + w0;
        ulonglong2 a = *(const ulonglong2*)(src);
        ulonglong2 b = *(const ulonglong2*)(src + 2);
        ulonglong2 c2 = *(const ulonglong2*)(src + 4);
        ulonglong2 d = *(const ulonglong2*)(src + 6);
        unsigned long long* dst = &rb[0][r][w0];
        dst[0] = a.x; dst[1] = a.y; dst[2] = b.x; dst[3] = b.y;
        dst[4] = c2.x; dst[5] = c2.y; dst[6] = d.x; dst[7] = d.y;
    }
    __syncthreads();
    for (int c = 0; c < 32; c++) {
        int cur = c & 1, nxt = cur ^ 1;
        ulonglong2 pa, pb, pc, pd;
        bool pf = (c + 1 < 32);
        if (pf) {
            const unsigned long long* src = mat + ((size_t)n * 2048 + (c + 1) * 64 + r) * 32 + w0;
            pa = *(const ulonglong2*)(src);
            pb = *(const ulonglong2*)(src + 2);
            pc = *(const ulonglong2*)(src + 4);
            pd = *(const ulonglong2*)(src + 6);
        }
        if (tid < 64) {
            unsigned long long M = rb[cur][lane][c];
            unsigned long long supw = sup_lds[c];
            unsigned long long vbw = vb[c];
            unsigned long long km = 0ull;
#pragma unroll
            for (int ii = 0; ii < 64; ii++) {
                unsigned long long bit = 1ull << ii;
                if ((vbw & bit) && !(supw & bit)) {
                    km |= bit;
                    supw |= rl64(M, ii);
                }
            }
            if (lane == 0) kbw[c] = km;
            if (lane < 32) {
                unsigned long long acc = 0ull;
                unsigned long long tm = km;
                while (tm) {
                    int ii = __ffsll((long long)tm) - 1;
                    tm &= tm - 1;
                    acc |= rb[cur][ii][lane];
                }
                sup_lds[lane] |= acc;
            }
        }
        if (pf) {
            unsigned long long* dst = &rb[nxt][r][w0];
            dst[0] = pa.x; dst[1] = pa.y; dst[2] = pb.x; dst[3] = pb.y;
            dst[4] = pc.x; dst[5] = pc.y; dst[6] = pd.x; dst[7] = pd.y;
        }
        __syncthreads();
    }
    if (tid < 64) {
        int running = 0;
        for (int i0 = 0; i0 < 2048; i0 += 64) {
            int i = i0 + lane;
            bool kp = (i < PRE_NMS) && ((kbw[i >> 6] >> (i & 63)) & 1ull);
            unsigned long long m = __ballot(kp);
            if (kp) {
                int rk = running + __popcll(m & ((1ull << lane) - 1ull));
                if (rk < POST_NMS) {
                    const double* bp2 = bsort + ((size_t)n * 2048 + i) * 4;
                    unsigned long long k = skeys[(size_t)n * PRE_NMS + i];
                    double s = __longlong_as_double((long long)~k);
                    float* o = dout + rk * 5;
                    o[0] = (float)bp2[0]; o[1] = (float)bp2[1];
                    o[2] = (float)bp2[2]; o[3] = (float)bp2[3];
                    o[4] = (float)s;
                }
            }
            running += __popcll(m);
        }
    }
}

extern "C" void kernel_launch(void* const* d_in, const int* in_sizes, int n_in,
                              void* d_out, int out_size, void* d_ws, size_t ws_size,
                              hipStream_t stream) {
    (void)in_sizes; (void)n_in; (void)out_size; (void)ws_size;
    const float* feat   = (const float*)d_in[0];
    const float* conv_w = (const float*)d_in[1];
    const float* conv_b = (const float*)d_in[2];
    const float* det_w  = (const float*)d_in[3];
    const float* det_b  = (const float*)d_in[4];
    const float* reg_w  = (const float*)d_in[5];
    const float* reg_b  = (const float*)d_in[6];
    float* out = (float*)d_out;

    char* w = (char*)d_ws;
    double* E64 = (double*)w;                         w += (size_t)2304 * 16 * 8;
    double* EB64 = (double*)w;                        w += 128;
    float* E32 = (float*)w;                           w += (size_t)2304 * 16 * 4;
    float* EB32 = (float*)w;                          w += 64;
    float* PL = (float*)w;                            w += (size_t)60 * 65536 * 4;
    float* SCORE = (float*)w;                         w += (size_t)N_IMG * NPROP * 4;
    uint32_t* KEY32 = (uint32_t*)w;                   w += (size_t)N_IMG * NPROP * 4;
    uint32_t* POSSLOT = (uint32_t*)w;                 w += (size_t)N_IMG * 16384 * 4;
    uint32_t* POSLIST = (uint32_t*)w;                 w += (size_t)N_IMG * POS_CAP * 4;
    uint32_t* PROPLIST = (uint32_t*)w;                w += (size_t)N_IMG * CAND_CAP * 4;
    uint32_t* COUNTS = (uint32_t*)w;                  w += 1024;
    double* PART = (double*)w;                        w += (size_t)N_IMG * POS_CAP * 4 * 16 * 8; // 6.3 MB
    double* L64 = (double*)w;                         w += (size_t)N_IMG * POS_CAP * 16 * 8;
    unsigned long long* CKEY = (unsigned long long*)w; w += (size_t)N_IMG * CAND_CAP * 8;
    uint32_t* CPIDX = (uint32_t*)w;                   w += (size_t)N_IMG * CAND_CAP * 4;
    double* CBOXJ = (double*)w;                       w += (size_t)N_IMG * CAND_CAP * 4 * 8;
    unsigned long long* SKEY = (unsigned long long*)w; w += (size_t)N_IMG * PRE_NMS * 8;
    double* BSORT = (double*)w;                       w += (size_t)N_IMG * 2048 * 4 * 8;
    double* AREA = (double*)w;                        w += (size_t)N_IMG * 2048 * 8;
    unsigned long long* MAT = (unsigned long long*)w; w += (size_t)N_IMG * 2048 * 32 * 8;

    k_effw64<<<dim3(145), dim3(256), 0, stream>>>(conv_w, conv_b, det_w, det_b, reg_w, reg_b, E64, E32, EB64, EB32);
    k_screen<<<dim3(512), dim3(256), 0, stream>>>(feat, E32, PL);
    k_decode<<<dim3(256), dim3(256), 0, stream>>>(PL, EB32, SCORE, KEY32, POSSLOT, COUNTS);
    k_thresh<<<dim3(N_IMG), dim3(1024), 0, stream>>>(KEY32, SCORE, COUNTS, POSSLOT, POSLIST, PROPLIST);
    k_refineL4<<<dim3(N_IMG * (POS_CAP / 16) * 4), dim3(256), 0, stream>>>(feat, E64, POSLIST, COUNTS, PART);
    k_combineL<<<dim3(N_IMG * POS_CAP * 16 / 256), dim3(256), 0, stream>>>(PART, EB64, L64);
    k_refineDecode<<<dim3(N_IMG * CAND_CAP / 256), dim3(256), 0, stream>>>(L64, PROPLIST, POSSLOT, COUNTS, CKEY, CPIDX, CBOXJ);
    k_sort2000<<<dim3(N_IMG), dim3(256), 0, stream>>>(CKEY, CPIDX, CBOXJ, SKEY, BSORT, AREA);
    k_iou2<<<dim3(N_IMG * 64), dim3(256), 0, stream>>>(BSORT, AREA, MAT);
    k_nms2<<<dim3(N_IMG), dim3(256), 0, stream>>>(SKEY, BSORT, MAT, out);
}

// Round 7
// 598.904 us; speedup vs baseline: 6.0031x; 1.5944x over previous
//
#include <hip/hip_runtime.h>
#include <hip/hip_bf16.h>
#include <hip/hip_fp16.h>
#include <stdint.h>
#include <math.h>

#define N_IMG 4
#define CIN 256
#define HFD 128
#define WFD 128
#define HW (HFD*WFD)        // 16384
#define NA 3
#define NPROP (NA*HW)       // 49152
#define PRE_NMS 2000
#define POST_NMS 300

__device__ __forceinline__ unsigned long long rl64(unsigned long long v, int i) {
    unsigned int lo = (unsigned int)__builtin_amdgcn_readlane((int)(unsigned int)v, i);
    unsigned int hi = (unsigned int)__builtin_amdgcn_readlane((int)(unsigned int)(v >> 32), i);
    return ((unsigned long long)hi << 32) | (unsigned long long)lo;
}

// ---------------- K0: effective fp64 weights E64[(ci*9+rs)*16 + c] (c=15 pad), bias EB64 ----------------
__global__ __launch_bounds__(256) void k_effw64(const float* __restrict__ cw, const float* __restrict__ cb,
                                                const float* __restrict__ dw_, const float* __restrict__ db_,
                                                const float* __restrict__ rw_, const float* __restrict__ rb_,
                                                double* __restrict__ E64, double* __restrict__ EB64)
{
    int out = blockIdx.x * 256 + threadIdx.x;
    if (out < 36864) {
        int k2 = out >> 4, c = out & 15;
        if (c == 15) { E64[out] = 0.0; return; }
        const float* hw = (c < 3) ? (dw_ + c * 256) : (rw_ + (c - 3) * 256);
        double s = 0.0;
#pragma unroll 4
        for (int co = 0; co < 256; co++) s += (double)hw[co] * (double)cw[co * 2304 + k2];
        E64[out] = s;
    } else if (out < 36864 + 16) {
        int c = out - 36864;
        double s = 0.0; double hb = 0.0;
        if (c < 15) {
            const float* hw = (c < 3) ? (dw_ + c * 256) : (rw_ + (c - 3) * 256);
            for (int co = 0; co < 256; co++) s += (double)hw[co] * (double)cb[co];
            hb = (double)((c < 3) ? db_[c] : rb_[c - 3]);
        }
        EB64[c] = s + hb;
    }
}

// ---------------- K1: dense fused 15-output 3x3 conv, fp64 accumulate, 4-way ci-split ----------------
// grid 512 = 4 img x 32 htiles(4 rows) x 4 chunks(64 ci); block 256: q=tid&63 -> 2 px, hl=tid>>6
__global__ __launch_bounds__(256) void k_conv64(const float* __restrict__ feat,
                                                const double* __restrict__ E64,
                                                double* __restrict__ PART)
{
    __shared__ float in_t[8][6][132];
    __shared__ double wl[8][9][16];
    int b = blockIdx.x;
    int chunk = b & 3; int htile = (b >> 2) & 31; int n = b >> 7;
    int h0 = htile * 4;
    int tid = threadIdx.x;
    int q = tid & 63, hl = tid >> 6;
    int w0 = q * 2;
    double acc[15][2];
#pragma unroll
    for (int c = 0; c < 15; c++) { acc[c][0] = 0.0; acc[c][1] = 0.0; }

    for (int sl = 0; sl < 8; sl++) {
        int ci0 = chunk * 64 + sl * 8;
        for (int idx = tid; idx < 8 * 780; idx += 256) {
            int ci = idx / 780; int r2 = idx % 780; int dh = r2 / 130; int dw = r2 % 130;
            int gh = h0 - 1 + dh, gw = dw - 1;
            float v = 0.f;
            if (gh >= 0 && gh < HFD && gw >= 0 && gw < WFD)
                v = feat[(((n << 8) + ci0 + ci) << 14) + (gh << 7) + gw];
            in_t[ci][dh][dw] = v;
        }
        for (int idx = tid; idx < 1152; idx += 256) {
            ((double*)wl)[idx] = E64[(size_t)ci0 * 144 + idx];
        }
        __syncthreads();
        for (int ci = 0; ci < 8; ci++) {
#pragma unroll
            for (int r = 0; r < 3; r++) {
                float2 g0 = *(const float2*)&in_t[ci][hl + r][w0];
                float2 g1 = *(const float2*)&in_t[ci][hl + r][w0 + 2];
                float f[4] = {g0.x, g0.y, g1.x, g1.y};
#pragma unroll
                for (int s = 0; s < 3; s++) {
                    const double* wp = &wl[ci][r * 3 + s][0];
                    double pa = (double)f[s], pb = (double)f[s + 1];
#pragma unroll
                    for (int c = 0; c < 15; c++) {
                        double wv = wp[c];
                        acc[c][0] += wv * pa;
                        acc[c][1] += wv * pb;
                    }
                }
            }
        }
        __syncthreads();
    }
    int gpos = (n << 14) + ((h0 + hl) << 7) + w0;
    double* dst = PART + ((size_t)chunk << 20) + (size_t)gpos * 16;
#pragma unroll
    for (int c = 0; c < 15; c++) {
        dst[c] = acc[c][0];
        dst[16 + c] = acc[c][1];
    }
}

// ---------------- K2: combine 4 chunk partials + bias (fixed order) ----------------
__global__ __launch_bounds__(256) void k_combine64(const double* __restrict__ PART,
                                                   const double* __restrict__ EB64,
                                                   double* __restrict__ LALL)
{
    int idx = blockIdx.x * 256 + threadIdx.x;  // < 1<<20
    double v = ((PART[idx] + PART[(1u << 20) + idx]) + (PART[(2u << 20) + idx] + PART[(3u << 20) + idx]))
               + EB64[idx & 15];
    LALL[idx] = v;
}

// ---------------- K3: fp64 decode for ALL props -> key64 + boxes ----------------
__global__ __launch_bounds__(256) void k_decode64(const double* __restrict__ LALL,
                                                  unsigned long long* __restrict__ KEY64,
                                                  double* __restrict__ BOX64)
{
    int p = blockIdx.x * 256 + threadIdx.x;   // 65536
    int n = p >> 14, pos = p & 16383;
    const double* Lp = LALL + (size_t)p * 16;
#pragma unroll
    for (int a = 0; a < 3; a++) {
        double logit = Lp[a];
        double score = 1.0 / (1.0 + exp(-logit));
        double dx  = Lp[3 + a];
        double dy  = Lp[6 + a];
        double dwv = Lp[9 + a];
        double dhv = Lp[12 + a];
        int i = a * HW + pos;
        int loc = i / 3, aa = i % 3;
        int hh = loc >> 7, wwi = loc & 127;
        double sx = (double)(wwi * 8), sy = (double)(hh * 8);
        double bx1 = (aa == 0) ? -91.0 : (aa == 1 ? -64.0 : -45.0);
        double by1 = (aa == 0) ? -45.0 : (aa == 1 ? -64.0 : -91.0);
        double x1 = sx + bx1, y1 = sy + by1, x2 = sx - bx1, y2 = sy - by1;
        double aw = x2 - x1, ahh = y2 - y1;
        double acx = y1 + aw * 0.5;   // (sic) swap, faithful to reference
        double acy = x1 + ahh * 0.5;  // (sic)
        double px = acx + dx * aw, py = acy + dy * ahh;
        double pw = aw * exp(dwv), ph = ahh * exp(dhv);
        double c1 = px - pw * 0.5, c2 = py - ph * 0.5, c3 = px + pw * 0.5, c4 = py + ph * 0.5;
        c1 = fmin(fmax(c1, 0.0), 1024.0);
        c2 = fmin(fmax(c2, 0.0), 1024.0);
        c3 = fmin(fmax(c3, 0.0), 1024.0);
        c4 = fmin(fmax(c4, 0.0), 1024.0);
        bool valid = (score > 0.3) && (c3 - c1 > 0.0) && (c4 - c2 > 0.0);
        KEY64[(size_t)n * NPROP + i] = valid ? ~((unsigned long long)__double_as_longlong(score)) : ~0ull;
        double* bp = BOX64 + ((size_t)n * NPROP + i) * 4;
        bp[0] = c1; bp[1] = c2; bp[2] = c3; bp[3] = c4;
    }
}

// ---------------- K4: exact top-2000 per image (64-bit radix select + bitonic, idx tiebreak) ----------------
__global__ __launch_bounds__(1024) void k_select64(const unsigned long long* __restrict__ KEY64,
                                                   const double* __restrict__ BOX64,
                                                   unsigned long long* __restrict__ skeys,
                                                   double* __restrict__ bsort,
                                                   double* __restrict__ area)
{
    int n = blockIdx.x; int tid = threadIdx.x;
    const unsigned long long* K = KEY64 + (size_t)n * NPROP;
    __shared__ uint32_t hist[2048];
    __shared__ uint32_t psum[256];
    __shared__ unsigned long long selk[2048];
    __shared__ uint32_t seli[2048];
    __shared__ unsigned long long s_prefix;
    __shared__ int s_need;
    __shared__ uint32_t s_cnt;
    if (tid == 0) { s_prefix = 0ull; s_need = PRE_NMS; s_cnt = 0u; }
    for (int L = 0; L < 4; L++) {
        int sh = 53 - 11 * L;
        for (int idx = tid; idx < 2048; idx += 1024) hist[idx] = 0u;
        __syncthreads();
        unsigned long long pref = s_prefix;
        for (int i = tid; i < NPROP; i += 1024) {
            unsigned long long k = K[i];
            bool in = (L == 0) || ((k >> (sh + 11)) == pref);
            if (in) atomicAdd(&hist[(uint32_t)((k >> sh) & 2047ull)], 1u);
        }
        __syncthreads();
        if (tid < 256) { uint32_t s = 0; for (int qq = 0; qq < 8; qq++) s += hist[tid * 8 + qq]; psum[tid] = s; }
        __syncthreads();
        if (tid == 0) {
            int need = s_need; uint32_t cum = 0; int g = 255;
            for (int t = 0; t < 256; t++) { uint32_t c = psum[t]; if (cum + c >= (uint32_t)need) { g = t; break; } cum += c; }
            int bsel = g * 8 + 7;
            for (int t = g * 8; t < g * 8 + 8; t++) { uint32_t c = hist[t]; if (cum + c >= (uint32_t)need) { bsel = t; break; } cum += c; }
            s_need = need - (int)cum;
            s_prefix = (pref << 11) | (unsigned long long)bsel;
        }
        __syncthreads();
    }
    unsigned long long pref44 = s_prefix;
    for (int idx = tid; idx < 2048; idx += 1024) { selk[idx] = ~0ull; seli[idx] = 0xFFFFFFFFu; }
    __syncthreads();
    for (int i = tid; i < NPROP; i += 1024) {
        unsigned long long k = K[i];
        if (k != ~0ull && (k >> 20) <= pref44) {
            uint32_t p2 = atomicAdd(&s_cnt, 1u);
            if (p2 < 2048u) { selk[p2] = k; seli[p2] = (uint32_t)i; }
        }
    }
    __syncthreads();
    for (unsigned k2 = 2; k2 <= 2048; k2 <<= 1) {
        for (unsigned jx = k2 >> 1; jx > 0; jx >>= 1) {
            for (int t = tid; t < 2048; t += 1024) {
                unsigned ixj = (unsigned)t ^ jx;
                if (ixj > (unsigned)t) {
                    bool up = ((t & k2) == 0);
                    unsigned long long ka = selk[t], kb = selk[ixj];
                    uint32_t ia = seli[t], ib = seli[ixj];
                    bool agt = (ka > kb) || (ka == kb && ia > ib);
                    if (up ? agt : !agt) {
                        selk[t] = kb; selk[ixj] = ka;
                        seli[t] = ib; seli[ixj] = ia;
                    }
                }
            }
            __syncthreads();
        }
    }
    for (int t = tid; t < 2048; t += 1024) {
        bool valid = (t < PRE_NMS) && (selk[t] != ~0ull);
        if (t < PRE_NMS) skeys[(size_t)n * PRE_NMS + t] = valid ? selk[t] : ~0ull;
        double b0 = 0, b1 = 0, b2 = 0, b3 = 0;
        if (valid) {
            const double* bp = BOX64 + ((size_t)n * NPROP + seli[t]) * 4;
            b0 = bp[0]; b1 = bp[1]; b2 = bp[2]; b3 = bp[3];
        }
        double* bs = bsort + (((size_t)(n * 2048 + t)) << 2);
        bs[0] = b0; bs[1] = b1; bs[2] = b2; bs[3] = b3;
        area[(size_t)n * 2048 + t] = fmax(b2 - b0, 0.0) * fmax(b3 - b1, 0.0);
    }
}

// ---------------- K5: pairwise IoU > 0.7 bitmask (32-row tiles, upper-triangle chunks only) ----------------
__global__ __launch_bounds__(256) void k_iou2(const double* __restrict__ bsort,
                                              const double* __restrict__ area,
                                              unsigned long long* __restrict__ mat)
{
    int blk = blockIdx.x; int n = blk >> 6; int rt = blk & 63;
    int tid = threadIdx.x;
    int r = tid >> 3, g = tid & 7;
    int i = rt * 32 + r;
    const double* bp = bsort + ((size_t)n * 2048 + i) * 4;
    double bx0 = bp[0], bx1_ = bp[1], bx2_ = bp[2], bx3 = bp[3];
    double ai = area[(size_t)n * 2048 + i];
    __shared__ double cbx[512][4];
    __shared__ double ca[512];
    for (int cc = 0; cc < 4; cc++) {
        if ((cc + 1) * 512 <= rt * 32) continue;
        __syncthreads();
        for (int idx = tid; idx < 512; idx += 256) {
            const double* sp = bsort + ((size_t)n * 2048 + cc * 512 + idx) * 4;
            cbx[idx][0] = sp[0]; cbx[idx][1] = sp[1]; cbx[idx][2] = sp[2]; cbx[idx][3] = sp[3];
            ca[idx] = area[(size_t)n * 2048 + cc * 512 + idx];
        }
        __syncthreads();
        unsigned long long wd = 0ull;
        for (int jb = 0; jb < 64; jb++) {
            int jr = (jb + g * 9) & 63;
            int jj = g * 64 + jr;
            double ix1 = fmax(bx0, cbx[jj][0]);
            double iy1 = fmax(bx1_, cbx[jj][1]);
            double ix2 = fmin(bx2_, cbx[jj][2]);
            double iy2 = fmin(bx3, cbx[jj][3]);
            double inter = fmax(ix2 - ix1, 0.0) * fmax(iy2 - iy1, 0.0);
            double den = fmax(ai + ca[jj] - inter, 1e-9);
            double iou = inter / den;
            if (iou > 0.7) wd |= (1ull << jr);
        }
        mat[((size_t)n * 2048 + i) * 32 + cc * 8 + g] = wd;
    }
}

// ---------------- K6: chunked NMS — LDS-prefetched rows + readlane scalar recurrence ----------------
__global__ __launch_bounds__(256) void k_nms2(const unsigned long long* __restrict__ skeys,
                                              const double* __restrict__ bsort,
                                              const unsigned long long* __restrict__ mat,
                                              float* __restrict__ out)
{
    int n = blockIdx.x; int tid = threadIdx.x;
    int lane = tid & 63;
    __shared__ unsigned long long rb[2][64][33];
    __shared__ unsigned long long sup_lds[32];
    __shared__ unsigned long long vb[32];
    __shared__ unsigned long long kbw[32];
    float* dout = out + n * (POST_NMS * 5);
    for (int t = tid; t < POST_NMS * 5; t += 256) dout[t] = 0.f;
    if (tid < 32) sup_lds[tid] = 0ull;
    if (tid < 64) {
        for (int i0 = 0; i0 < 2048; i0 += 64) {
            int i = i0 + lane;
            unsigned long long k = (i < PRE_NMS) ? skeys[(size_t)n * PRE_NMS + i] : ~0ull;
            unsigned long long m = __ballot(k != ~0ull);
            if (lane == 0) vb[i0 >> 6] = m;
        }
    }
    int r = tid >> 2, w0 = (tid & 3) * 8;
    {
        const unsigned long long* src = mat + ((size_t)n * 2048 + r) * 32 + w0;
        ulonglong2 a = *(const ulonglong2*)(src);
        ulonglong2 b = *(const ulonglong2*)(src + 2);
        ulonglong2 c2 = *(const ulonglong2*)(src + 4);
        ulonglong2 d = *(const ulonglong2*)(src + 6);
        unsigned long long* dst = &rb[0][r][w0];
        dst[0] = a.x; dst[1] = a.y; dst[2] = b.x; dst[3] = b.y;
        dst[4] = c2.x; dst[5] = c2.y; dst[6] = d.x; dst[7] = d.y;
    }
    __syncthreads();
    for (int c = 0; c < 32; c++) {
        int cur = c & 1, nxt = cur ^ 1;
        ulonglong2 pa, pb, pc, pd;
        bool pf = (c + 1 < 32);
        if (pf) {
            const unsigned long long* src = mat + ((size_t)n * 2048 + (c + 1) * 64 + r) * 32 + w0;
            pa = *(const ulonglong2*)(src);
            pb = *(const ulonglong2*)(src + 2);
            pc = *(const ulonglong2*)(src + 4);
            pd = *(const ulonglong2*)(src + 6);
        }
        if (tid < 64) {
            unsigned long long M = rb[cur][lane][c];
            unsigned long long supw = sup_lds[c];
            unsigned long long vbw = vb[c];
            unsigned long long km = 0ull;
#pragma unroll
            for (int ii = 0; ii < 64; ii++) {
                unsigned long long bit = 1ull << ii;
                if ((vbw & bit) && !(supw & bit)) {
                    km |= bit;
                    supw |= rl64(M, ii);
                }
            }
            if (lane == 0) kbw[c] = km;
            if (lane < 32) {
                unsigned long long acc = 0ull;
                unsigned long long tm = km;
                while (tm) {
                    int ii = __ffsll((long long)tm) - 1;
                    tm &= tm - 1;
                    acc |= rb[cur][ii][lane];
                }
                sup_lds[lane] |= acc;
            }
        }
        if (pf) {
            unsigned long long* dst = &rb[nxt][r][w0];
            dst[0] = pa.x; dst[1] = pa.y; dst[2] = pb.x; dst[3] = pb.y;
            dst[4] = pc.x; dst[5] = pc.y; dst[6] = pd.x; dst[7] = pd.y;
        }
        __syncthreads();
    }
    if (tid < 64) {
        int running = 0;
        for (int i0 = 0; i0 < 2048; i0 += 64) {
            int i = i0 + lane;
            bool kp = (i < PRE_NMS) && ((kbw[i >> 6] >> (i & 63)) & 1ull);
            unsigned long long m = __ballot(kp);
            if (kp) {
                int rk = running + __popcll(m & ((1ull << lane) - 1ull));
                if (rk < POST_NMS) {
                    const double* bp2 = bsort + ((size_t)n * 2048 + i) * 4;
                    unsigned long long k = skeys[(size_t)n * PRE_NMS + i];
                    double s = __longlong_as_double((long long)~k);
                    float* o = dout + rk * 5;
                    o[0] = (float)bp2[0]; o[1] = (float)bp2[1];
                    o[2] = (float)bp2[2]; o[3] = (float)bp2[3];
                    o[4] = (float)s;
                }
            }
            running += __popcll(m);
        }
    }
}

extern "C" void kernel_launch(void* const* d_in, const int* in_sizes, int n_in,
                              void* d_out, int out_size, void* d_ws, size_t ws_size,
                              hipStream_t stream) {
    (void)in_sizes; (void)n_in; (void)out_size; (void)ws_size;
    const float* feat   = (const float*)d_in[0];
    const float* conv_w = (const float*)d_in[1];
    const float* conv_b = (const float*)d_in[2];
    const float* det_w  = (const float*)d_in[3];
    const float* det_b  = (const float*)d_in[4];
    const float* reg_w  = (const float*)d_in[5];
    const float* reg_b  = (const float*)d_in[6];
    float* out = (float*)d_out;

    char* w = (char*)d_ws;
    double* E64 = (double*)w;                          w += (size_t)2304 * 16 * 8;              // 295 KB
    double* EB64 = (double*)w;                         w += 128;
    double* PART = (double*)w;                         w += (size_t)4 << 23;                    // 4 x (1<<20) doubles = 33.6 MB
    double* LALL = (double*)w;                         w += (size_t)1 << 23;                    // 8.4 MB
    unsigned long long* KEY64 = (unsigned long long*)w; w += (size_t)N_IMG * NPROP * 8;         // 1.6 MB
    double* BOX64 = (double*)w;                        w += (size_t)N_IMG * NPROP * 4 * 8;      // 6.3 MB
    unsigned long long* SKEY = (unsigned long long*)w; w += (size_t)N_IMG * PRE_NMS * 8;
    double* BSORT = (double*)w;                        w += (size_t)N_IMG * 2048 * 4 * 8;
    double* AREA = (double*)w;                         w += (size_t)N_IMG * 2048 * 8;
    unsigned long long* MAT = (unsigned long long*)w;  w += (size_t)N_IMG * 2048 * 32 * 8;      // 2 MB

    k_effw64<<<dim3(145), dim3(256), 0, stream>>>(conv_w, conv_b, det_w, det_b, reg_w, reg_b, E64, EB64);
    k_conv64<<<dim3(512), dim3(256), 0, stream>>>(feat, E64, PART);
    k_combine64<<<dim3(4096), dim3(256), 0, stream>>>(PART, EB64, LALL);
    k_decode64<<<dim3(256), dim3(256), 0, stream>>>(LALL, KEY64, BOX64);
    k_select64<<<dim3(N_IMG), dim3(1024), 0, stream>>>(KEY64, BOX64, SKEY, BSORT, AREA);
    k_iou2<<<dim3(N_IMG * 64), dim3(256), 0, stream>>>(BSORT, AREA, MAT);
    k_nms2<<<dim3(N_IMG), dim3(256), 0, stream>>>(SKEY, BSORT, MAT, out);
}

// Round 8
// 565.675 us; speedup vs baseline: 6.3557x; 1.0587x over previous
//
#include <hip/hip_runtime.h>
#include <hip/hip_bf16.h>
#include <hip/hip_fp16.h>
#include <stdint.h>
#include <math.h>

#define N_IMG 4
#define CIN 256
#define HFD 128
#define WFD 128
#define HW (HFD*WFD)        // 16384
#define NA 3
#define NPROP (NA*HW)       // 49152
#define PRE_NMS 2000
#define POST_NMS 300

__device__ __forceinline__ unsigned long long rl64(unsigned long long v, int i) {
    unsigned int lo = (unsigned int)__builtin_amdgcn_readlane((int)(unsigned int)v, i);
    unsigned int hi = (unsigned int)__builtin_amdgcn_readlane((int)(unsigned int)(v >> 32), i);
    return ((unsigned long long)hi << 32) | (unsigned long long)lo;
}

// PART layout: [chunk][c][p] with chunk stride 1<<20 doubles, c stride 65536, p = (n<<14)+pos
__device__ __forceinline__ double sum8(const double* __restrict__ PART, size_t cp) {
    const size_t S = (size_t)1 << 20;
    double a = PART[cp] + PART[cp + S];
    double b = PART[cp + 2 * S] + PART[cp + 3 * S];
    double c = PART[cp + 4 * S] + PART[cp + 5 * S];
    double d = PART[cp + 6 * S] + PART[cp + 7 * S];
    return (a + b) + (c + d);
}

__device__ __forceinline__ void decode_box(int i, double dx, double dy, double dwv, double dhv,
                                           double& c1o, double& c2o, double& c3o, double& c4o) {
    int loc = i / 3, aa = i % 3;
    int hh = loc >> 7, wwi = loc & 127;
    double sx = (double)(wwi * 8), sy = (double)(hh * 8);
    double bx1 = (aa == 0) ? -91.0 : (aa == 1 ? -64.0 : -45.0);
    double by1 = (aa == 0) ? -45.0 : (aa == 1 ? -64.0 : -91.0);
    double x1 = sx + bx1, y1 = sy + by1, x2 = sx - bx1, y2 = sy - by1;
    double aw = x2 - x1, ahh = y2 - y1;
    double acx = y1 + aw * 0.5;   // (sic) swap, faithful to reference
    double acy = x1 + ahh * 0.5;  // (sic)
    double px = acx + dx * aw, py = acy + dy * ahh;
    double pw = aw * exp(dwv), ph = ahh * exp(dhv);
    double c1 = px - pw * 0.5, c2 = py - ph * 0.5, c3 = px + pw * 0.5, c4 = py + ph * 0.5;
    c1o = fmin(fmax(c1, 0.0), 1024.0);
    c2o = fmin(fmax(c2, 0.0), 1024.0);
    c3o = fmin(fmax(c3, 0.0), 1024.0);
    c4o = fmin(fmax(c4, 0.0), 1024.0);
}

// ---------------- K0: effective fp64 weights, LDS-staged ----------------
// blocks 0..143: 256 outs each (16 k2 x 16 c); block 144: EB64
__global__ __launch_bounds__(256) void k_effw64(const float* __restrict__ cw, const float* __restrict__ cb,
                                                const float* __restrict__ dw_, const float* __restrict__ db_,
                                                const float* __restrict__ rw_, const float* __restrict__ rb_,
                                                double* __restrict__ E64, double* __restrict__ EB64)
{
    int b = blockIdx.x;
    int tid = threadIdx.x;
    if (b < 144) {
        __shared__ float hwl[15][260];
        __shared__ float wt[256][16];
        int k0 = b * 16;
        for (int idx = tid; idx < 15 * 256; idx += 256) {
            int c = idx >> 8, co = idx & 255;
            hwl[c][co] = (c < 3) ? dw_[c * 256 + co] : rw_[(c - 3) * 256 + co];
        }
        for (int idx = tid; idx < 4096; idx += 256) {
            int co = idx >> 4, kk = idx & 15;
            wt[co][kk] = cw[co * 2304 + k0 + kk];
        }
        __syncthreads();
        int kk = tid >> 4, c = tid & 15;
        double s = 0.0;
        if (c < 15) {
#pragma unroll 4
            for (int co = 0; co < 256; co++) s += (double)hwl[c][co] * (double)wt[co][kk];
        }
        E64[(k0 + kk) * 16 + c] = s;
    } else {
        if (tid < 16) {
            int c = tid;
            double s = 0.0; double hb = 0.0;
            if (c < 15) {
                const float* hw = (c < 3) ? (dw_ + c * 256) : (rw_ + (c - 3) * 256);
                for (int co = 0; co < 256; co++) s += (double)hw[co] * (double)cb[co];
                hb = (double)((c < 3) ? db_[c] : rb_[c - 3]);
            }
            EB64[c] = s + hb;
        }
    }
}

// ---------------- K1: dense fused 15-output 3x3 conv, fp64 acc, 8-way ci-split ----------------
// grid 1024 = 4 img x 32 htiles(4 rows) x 8 chunks(32 ci); block 256: q=tid&63 -> 2 px, hl=tid>>6
__global__ __launch_bounds__(256, 4) void k_conv64(const float* __restrict__ feat,
                                                   const double* __restrict__ E64,
                                                   double* __restrict__ PART)
{
    __shared__ float in_t[8][6][132];
    __shared__ double wl[8][9][16];
    int b = blockIdx.x;
    int chunk = b & 7; int htile = (b >> 3) & 31; int n = b >> 8;
    int h0 = htile * 4;
    int tid = threadIdx.x;
    int q = tid & 63, hl = tid >> 6;
    int w0 = q * 2;
    double acc[15][2];
#pragma unroll
    for (int c = 0; c < 15; c++) { acc[c][0] = 0.0; acc[c][1] = 0.0; }

    for (int sl = 0; sl < 4; sl++) {
        int ci0 = (chunk << 5) + sl * 8;
        for (int idx = tid; idx < 8 * 780; idx += 256) {
            int ci = idx / 780; int r2 = idx % 780; int dh = r2 / 130; int dw = r2 % 130;
            int gh = h0 - 1 + dh, gw = dw - 1;
            float v = 0.f;
            if (gh >= 0 && gh < HFD && gw >= 0 && gw < WFD)
                v = feat[(((n << 8) + ci0 + ci) << 14) + (gh << 7) + gw];
            in_t[ci][dh][dw] = v;
        }
        for (int idx = tid; idx < 1152; idx += 256) {
            ((double*)wl)[idx] = E64[(size_t)ci0 * 144 + idx];
        }
        __syncthreads();
        for (int ci = 0; ci < 8; ci++) {
#pragma unroll
            for (int r = 0; r < 3; r++) {
                float2 g0 = *(const float2*)&in_t[ci][hl + r][w0];
                float2 g1 = *(const float2*)&in_t[ci][hl + r][w0 + 2];
                float f[4] = {g0.x, g0.y, g1.x, g1.y};
#pragma unroll
                for (int s = 0; s < 3; s++) {
                    const double* wp = &wl[ci][r * 3 + s][0];
                    double pa = (double)f[s], pb = (double)f[s + 1];
#pragma unroll
                    for (int cp = 0; cp < 7; cp++) {
                        double2 wv = *(const double2*)(wp + 2 * cp);
                        acc[2 * cp][0] += wv.x * pa; acc[2 * cp][1] += wv.x * pb;
                        acc[2 * cp + 1][0] += wv.y * pa; acc[2 * cp + 1][1] += wv.y * pb;
                    }
                    double w14 = wp[14];
                    acc[14][0] += w14 * pa; acc[14][1] += w14 * pb;
                }
            }
        }
        __syncthreads();
    }
    int gpos = (n << 14) + ((h0 + hl) << 7) + w0;
    double* base = PART + ((size_t)chunk << 20) + gpos;
#pragma unroll
    for (int c = 0; c < 15; c++) {
        double2 st; st.x = acc[c][0]; st.y = acc[c][1];
        *(double2*)(base + (size_t)c * 65536) = st;
    }
}

// ---------------- K2: fused combine + fp64 decode -> KEY64 (no box store) ----------------
__global__ __launch_bounds__(256) void k_findecode(const double* __restrict__ PART,
                                                   const double* __restrict__ EB64,
                                                   unsigned long long* __restrict__ KEY64)
{
    int p = blockIdx.x * 256 + threadIdx.x;   // 65536
    int n = p >> 14, pos = p & 16383;
    double L[15];
#pragma unroll
    for (int c = 0; c < 15; c++)
        L[c] = sum8(PART, (size_t)c * 65536 + p) + EB64[c];
#pragma unroll
    for (int a = 0; a < 3; a++) {
        double logit = L[a];
        double score = 1.0 / (1.0 + exp(-logit));
        int i = a * HW + pos;
        double c1, c2, c3, c4;
        decode_box(i, L[3 + a], L[6 + a], L[9 + a], L[12 + a], c1, c2, c3, c4);
        bool valid = (score > 0.3) && (c3 - c1 > 0.0) && (c4 - c2 > 0.0);
        KEY64[(size_t)n * NPROP + i] = valid ? ~((unsigned long long)__double_as_longlong(score)) : ~0ull;
    }
}

// ---------------- K3: exact top-2000 per image (radix + bitonic); boxes recomputed from PART ----------------
__global__ __launch_bounds__(1024) void k_select64(const unsigned long long* __restrict__ KEY64,
                                                   const double* __restrict__ PART,
                                                   const double* __restrict__ EB64,
                                                   unsigned long long* __restrict__ skeys,
                                                   double* __restrict__ bsort,
                                                   double* __restrict__ area)
{
    int n = blockIdx.x; int tid = threadIdx.x;
    const unsigned long long* K = KEY64 + (size_t)n * NPROP;
    __shared__ uint32_t hist[2048];
    __shared__ uint32_t psum[256];
    __shared__ unsigned long long selk[2048];
    __shared__ uint32_t seli[2048];
    __shared__ unsigned long long s_prefix;
    __shared__ int s_need;
    __shared__ uint32_t s_cnt;
    if (tid == 0) { s_prefix = 0ull; s_need = PRE_NMS; s_cnt = 0u; }
    for (int L = 0; L < 4; L++) {
        int sh = 53 - 11 * L;
        for (int idx = tid; idx < 2048; idx += 1024) hist[idx] = 0u;
        __syncthreads();
        unsigned long long pref = s_prefix;
        for (int i = tid; i < NPROP; i += 1024) {
            unsigned long long k = K[i];
            bool in = (L == 0) || ((k >> (sh + 11)) == pref);
            if (in) atomicAdd(&hist[(uint32_t)((k >> sh) & 2047ull)], 1u);
        }
        __syncthreads();
        if (tid < 256) { uint32_t s = 0; for (int qq = 0; qq < 8; qq++) s += hist[tid * 8 + qq]; psum[tid] = s; }
        __syncthreads();
        if (tid == 0) {
            int need = s_need; uint32_t cum = 0; int g = 255;
            for (int t = 0; t < 256; t++) { uint32_t c = psum[t]; if (cum + c >= (uint32_t)need) { g = t; break; } cum += c; }
            int bsel = g * 8 + 7;
            for (int t = g * 8; t < g * 8 + 8; t++) { uint32_t c = hist[t]; if (cum + c >= (uint32_t)need) { bsel = t; break; } cum += c; }
            s_need = need - (int)cum;
            s_prefix = (pref << 11) | (unsigned long long)bsel;
        }
        __syncthreads();
    }
    unsigned long long pref44 = s_prefix;
    for (int idx = tid; idx < 2048; idx += 1024) { selk[idx] = ~0ull; seli[idx] = 0xFFFFFFFFu; }
    __syncthreads();
    for (int i = tid; i < NPROP; i += 1024) {
        unsigned long long k = K[i];
        if (k != ~0ull && (k >> 20) <= pref44) {
            uint32_t p2 = atomicAdd(&s_cnt, 1u);
            if (p2 < 2048u) { selk[p2] = k; seli[p2] = (uint32_t)i; }
        }
    }
    __syncthreads();
    for (unsigned k2 = 2; k2 <= 2048; k2 <<= 1) {
        for (unsigned jx = k2 >> 1; jx > 0; jx >>= 1) {
            for (int t = tid; t < 2048; t += 1024) {
                unsigned ixj = (unsigned)t ^ jx;
                if (ixj > (unsigned)t) {
                    bool up = ((t & k2) == 0);
                    unsigned long long ka = selk[t], kb = selk[ixj];
                    uint32_t ia = seli[t], ib = seli[ixj];
                    bool agt = (ka > kb) || (ka == kb && ia > ib);
                    if (up ? agt : !agt) {
                        selk[t] = kb; selk[ixj] = ka;
                        seli[t] = ib; seli[ixj] = ia;
                    }
                }
            }
            __syncthreads();
        }
    }
    for (int t = tid; t < 2048; t += 1024) {
        bool valid = (t < PRE_NMS) && (selk[t] != ~0ull);
        if (t < PRE_NMS) skeys[(size_t)n * PRE_NMS + t] = valid ? selk[t] : ~0ull;
        double b0 = 0, b1 = 0, b2 = 0, b3 = 0;
        if (valid) {
            int i = (int)seli[t];
            int a = i >> 14, pos = i & 16383;
            size_t p = ((size_t)n << 14) + pos;
            double dx  = sum8(PART, (size_t)(3 + a)  * 65536 + p) + EB64[3 + a];
            double dy  = sum8(PART, (size_t)(6 + a)  * 65536 + p) + EB64[6 + a];
            double dwv = sum8(PART, (size_t)(9 + a)  * 65536 + p) + EB64[9 + a];
            double dhv = sum8(PART, (size_t)(12 + a) * 65536 + p) + EB64[12 + a];
            decode_box(i, dx, dy, dwv, dhv, b0, b1, b2, b3);
        }
        double* bs = bsort + (((size_t)(n * 2048 + t)) << 2);
        bs[0] = b0; bs[1] = b1; bs[2] = b2; bs[3] = b3;
        area[(size_t)n * 2048 + t] = fmax(b2 - b0, 0.0) * fmax(b3 - b1, 0.0);
    }
}

// ---------------- K4: pairwise IoU > 0.7 bitmask (32-row tiles, upper-triangle chunks only) ----------------
__global__ __launch_bounds__(256) void k_iou2(const double* __restrict__ bsort,
                                              const double* __restrict__ area,
                                              unsigned long long* __restrict__ mat)
{
    int blk = blockIdx.x; int n = blk >> 6; int rt = blk & 63;
    int tid = threadIdx.x;
    int r = tid >> 3, g = tid & 7;
    int i = rt * 32 + r;
    const double* bp = bsort + ((size_t)n * 2048 + i) * 4;
    double bx0 = bp[0], bx1_ = bp[1], bx2_ = bp[2], bx3 = bp[3];
    double ai = area[(size_t)n * 2048 + i];
    __shared__ double cbx[512][4];
    __shared__ double ca[512];
    for (int cc = 0; cc < 4; cc++) {
        if ((cc + 1) * 512 <= rt * 32) continue;
        __syncthreads();
        for (int idx = tid; idx < 512; idx += 256) {
            const double* sp = bsort + ((size_t)n * 2048 + cc * 512 + idx) * 4;
            cbx[idx][0] = sp[0]; cbx[idx][1] = sp[1]; cbx[idx][2] = sp[2]; cbx[idx][3] = sp[3];
            ca[idx] = area[(size_t)n * 2048 + cc * 512 + idx];
        }
        __syncthreads();
        unsigned long long wd = 0ull;
        for (int jb = 0; jb < 64; jb++) {
            int jr = (jb + g * 9) & 63;
            int jj = g * 64 + jr;
            double ix1 = fmax(bx0, cbx[jj][0]);
            double iy1 = fmax(bx1_, cbx[jj][1]);
            double ix2 = fmin(bx2_, cbx[jj][2]);
            double iy2 = fmin(bx3, cbx[jj][3]);
            double inter = fmax(ix2 - ix1, 0.0) * fmax(iy2 - iy1, 0.0);
            double den = fmax(ai + ca[jj] - inter, 1e-9);
            double iou = inter / den;
            if (iou > 0.7) wd |= (1ull << jr);
        }
        mat[((size_t)n * 2048 + i) * 32 + cc * 8 + g] = wd;
    }
}

// ---------------- K5: chunked NMS — LDS-prefetched rows + readlane scalar recurrence ----------------
__global__ __launch_bounds__(256) void k_nms2(const unsigned long long* __restrict__ skeys,
                                              const double* __restrict__ bsort,
                                              const unsigned long long* __restrict__ mat,
                                              float* __restrict__ out)
{
    int n = blockIdx.x; int tid = threadIdx.x;
    int lane = tid & 63;
    __shared__ unsigned long long rb[2][64][33];
    __shared__ unsigned long long sup_lds[32];
    __shared__ unsigned long long vb[32];
    __shared__ unsigned long long kbw[32];
    float* dout = out + n * (POST_NMS * 5);
    for (int t = tid; t < POST_NMS * 5; t += 256) dout[t] = 0.f;
    if (tid < 32) sup_lds[tid] = 0ull;
    if (tid < 64) {
        for (int i0 = 0; i0 < 2048; i0 += 64) {
            int i = i0 + lane;
            unsigned long long k = (i < PRE_NMS) ? skeys[(size_t)n * PRE_NMS + i] : ~0ull;
            unsigned long long m = __ballot(k != ~0ull);
            if (lane == 0) vb[i0 >> 6] = m;
        }
    }
    int r = tid >> 2, w0 = (tid & 3) * 8;
    {
        const unsigned long long* src = mat + ((size_t)n * 2048 + r) * 32 + w0;
        ulonglong2 a = *(const ulonglong2*)(src);
        ulonglong2 b = *(const ulonglong2*)(src + 2);
        ulonglong2 c2 = *(const ulonglong2*)(src + 4);
        ulonglong2 d = *(const ulonglong2*)(src + 6);
        unsigned long long* dst = &rb[0][r][w0];
        dst[0] = a.x; dst[1] = a.y; dst[2] = b.x; dst[3] = b.y;
        dst[4] = c2.x; dst[5] = c2.y; dst[6] = d.x; dst[7] = d.y;
    }
    __syncthreads();
    for (int c = 0; c < 32; c++) {
        int cur = c & 1, nxt = cur ^ 1;
        ulonglong2 pa, pb, pc, pd;
        bool pf = (c + 1 < 32);
        if (pf) {
            const unsigned long long* src = mat + ((size_t)n * 2048 + (c + 1) * 64 + r) * 32 + w0;
            pa = *(const ulonglong2*)(src);
            pb = *(const ulonglong2*)(src + 2);
            pc = *(const ulonglong2*)(src + 4);
            pd = *(const ulonglong2*)(src + 6);
        }
        if (tid < 64) {
            unsigned long long M = rb[cur][lane][c];
            unsigned long long supw = sup_lds[c];
            unsigned long long vbw = vb[c];
            unsigned long long km = 0ull;
#pragma unroll
            for (int ii = 0; ii < 64; ii++) {
                unsigned long long bit = 1ull << ii;
                if ((vbw & bit) && !(supw & bit)) {
                    km |= bit;
                    supw |= rl64(M, ii);
                }
            }
            if (lane == 0) kbw[c] = km;
            if (lane < 32) {
                unsigned long long acc = 0ull;
                unsigned long long tm = km;
                while (tm) {
                    int ii = __ffsll((long long)tm) - 1;
                    tm &= tm - 1;
                    acc |= rb[cur][ii][lane];
                }
                sup_lds[lane] |= acc;
            }
        }
        if (pf) {
            unsigned long long* dst = &rb[nxt][r][w0];
            dst[0] = pa.x; dst[1] = pa.y; dst[2] = pb.x; dst[3] = pb.y;
            dst[4] = pc.x; dst[5] = pc.y; dst[6] = pd.x; dst[7] = pd.y;
        }
        __syncthreads();
    }
    if (tid < 64) {
        int running = 0;
        for (int i0 = 0; i0 < 2048; i0 += 64) {
            int i = i0 + lane;
            bool kp = (i < PRE_NMS) && ((kbw[i >> 6] >> (i & 63)) & 1ull);
            unsigned long long m = __ballot(kp);
            if (kp) {
                int rk = running + __popcll(m & ((1ull << lane) - 1ull));
                if (rk < POST_NMS) {
                    const double* bp2 = bsort + ((size_t)n * 2048 + i) * 4;
                    unsigned long long k = skeys[(size_t)n * PRE_NMS + i];
                    double s = __longlong_as_double((long long)~k);
                    float* o = dout + rk * 5;
                    o[0] = (float)bp2[0]; o[1] = (float)bp2[1];
                    o[2] = (float)bp2[2]; o[3] = (float)bp2[3];
                    o[4] = (float)s;
                }
            }
            running += __popcll(m);
        }
    }
}

extern "C" void kernel_launch(void* const* d_in, const int* in_sizes, int n_in,
                              void* d_out, int out_size, void* d_ws, size_t ws_size,
                              hipStream_t stream) {
    (void)in_sizes; (void)n_in; (void)out_size; (void)ws_size;
    const float* feat   = (const float*)d_in[0];
    const float* conv_w = (const float*)d_in[1];
    const float* conv_b = (const float*)d_in[2];
    const float* det_w  = (const float*)d_in[3];
    const float* det_b  = (const float*)d_in[4];
    const float* reg_w  = (const float*)d_in[5];
    const float* reg_b  = (const float*)d_in[6];
    float* out = (float*)d_out;

    char* w = (char*)d_ws;
    double* E64 = (double*)w;                          w += (size_t)2304 * 16 * 8;              // 295 KB
    double* EB64 = (double*)w;                         w += 128;
    double* PART = (double*)w;                         w += (size_t)8 << 23;                    // 8 x (1<<20) doubles = 67.1 MB
    unsigned long long* KEY64 = (unsigned long long*)w; w += (size_t)N_IMG * NPROP * 8;         // 1.6 MB
    unsigned long long* SKEY = (unsigned long long*)w; w += (size_t)N_IMG * PRE_NMS * 8;
    double* BSORT = (double*)w;                        w += (size_t)N_IMG * 2048 * 4 * 8;
    double* AREA = (double*)w;                         w += (size_t)N_IMG * 2048 * 8;
    unsigned long long* MAT = (unsigned long long*)w;  w += (size_t)N_IMG * 2048 * 32 * 8;      // 2 MB

    k_effw64<<<dim3(145), dim3(256), 0, stream>>>(conv_w, conv_b, det_w, det_b, reg_w, reg_b, E64, EB64);
    k_conv64<<<dim3(1024), dim3(256), 0, stream>>>(feat, E64, PART);
    k_findecode<<<dim3(256), dim3(256), 0, stream>>>(PART, EB64, KEY64);
    k_select64<<<dim3(N_IMG), dim3(1024), 0, stream>>>(KEY64, PART, EB64, SKEY, BSORT, AREA);
    k_iou2<<<dim3(N_IMG * 64), dim3(256), 0, stream>>>(BSORT, AREA, MAT);
    k_nms2<<<dim3(N_IMG), dim3(256), 0, stream>>>(SKEY, BSORT, MAT, out);
}